// Round 11
// baseline (647.170 us; speedup 1.0000x reference)
//
#include <hip/hip_runtime.h>
#include <math.h>

#define N_NODES 50000
#define N_EDGES 500000
#define D 128
#define H 256
#define NE 64
#define TOPK 2
#define NPAIR (N_NODES * TOPK)
#define CAP 3126               // 2 * ceil(100000/64)
#define TILE_R 32
#define BQ 4                   // blocks per expert in k_moe
#define BN_NBLK 128
#define BN_ROWS ((N_NODES + BN_NBLK - 1) / BN_NBLK) // 391

typedef __attribute__((ext_vector_type(8))) short s16x8;
typedef __attribute__((ext_vector_type(4))) float f32x4;

__device__ __forceinline__ unsigned short f2bf(float f) {
    unsigned u = __float_as_uint(f);
    unsigned r = (u + 0x7fffu + ((u >> 16) & 1u)) >> 16;
    return (unsigned short)r;
}
__device__ __forceinline__ float bf2f(unsigned short u) {
    return __uint_as_float(((unsigned)u) << 16);
}

// Compensated f32: TwoProd (mul + fma residual) + branch-free TwoSum.
#define DOT2(s, c, xx, ww) {                      \
    float p_ = (xx) * (ww);                       \
    float e1_ = fmaf((xx), (ww), -p_);            \
    float t_ = (s) + p_;                          \
    float z_ = t_ - (s);                          \
    float e2_ = ((s) - (t_ - z_)) + (p_ - z_);    \
    (s) = t_;                                     \
    (c) += e1_ + e2_; }

#define TSUM(s, c, pp) {                          \
    float p_ = (pp);                              \
    float t_ = (s) + p_;                          \
    float z_ = t_ - (s);                          \
    float e2_ = ((s) - (t_ - z_)) + (p_ - z_);    \
    (s) = t_;                                     \
    (c) += e2_; }

// ---------------- degree count ----------------
__global__ void k_deg(const int* __restrict__ dst, int* __restrict__ deg) {
    int i = blockIdx.x * blockDim.x + threadIdx.x;
    if (i < N_EDGES) atomicAdd(&deg[dst[i]], 1);
}

__global__ void k_invsqrt(const int* __restrict__ deg, float* __restrict__ invs) {
    int i = blockIdx.x * blockDim.x + threadIdx.x;
    if (i < N_NODES) {
        double d = (double)deg[i];
        if (d < 1.0) d = 1.0;
        invs[i] = (float)(1.0 / sqrt(d));
    }
}

// ---------------- exclusive scan of deg -> rowptr ----------------
__global__ __launch_bounds__(1024) void k_scan(const int* __restrict__ deg,
                                               int* __restrict__ rowptr) {
    __shared__ int sh[1024];
    int t = threadIdx.x;
    const int chunk = (N_NODES + 1023) / 1024;   // 49
    int lo = t * chunk;
    int hi = min(lo + chunk, N_NODES);
    int s = 0;
    for (int i = lo; i < hi; i++) s += deg[i];
    sh[t] = s;
    __syncthreads();
    for (int off = 1; off < 1024; off <<= 1) {
        int v = (t >= off) ? sh[t - off] : 0;
        __syncthreads();
        sh[t] += v;
        __syncthreads();
    }
    int run = (t == 0) ? 0 : sh[t - 1];
    for (int i = lo; i < hi; i++) { rowptr[i] = run; run += deg[i]; }
    if (t == 1023) rowptr[N_NODES] = run;
}

// ---------------- scatter edges into CSR ----------------
__global__ void k_scatter(const int* __restrict__ src, const int* __restrict__ dst,
                          const int* __restrict__ rowptr, int* __restrict__ cursor,
                          int* __restrict__ csr) {
    int e = blockIdx.x * blockDim.x + threadIdx.x;
    if (e >= N_EDGES) return;
    int d = dst[e];
    int pos = atomicAdd(&cursor[d], 1);
    csr[rowptr[d] + pos] = src[e];
}

// ---------------- per-node gather (compensated f32, order-independent ~1e-12) ----
__global__ __launch_bounds__(256) void k_gather(const float* __restrict__ feats,
                                                const int* __restrict__ rowptr,
                                                const int* __restrict__ csr,
                                                const float* __restrict__ invs,
                                                float* __restrict__ agg) {
    int node = blockIdx.x * 4 + (threadIdx.x >> 6);
    if (node >= N_NODES) return;
    int lane = threadIdx.x & 63;
    int beg = rowptr[node], end = rowptr[node + 1];
    float wd = invs[node];
    float sx = 0.f, cx = 0.f, sy = 0.f, cy = 0.f;
    for (int i = beg; i < end; i++) {
        int s = csr[i];
        float nrm = invs[s] * wd;
        float2 f = ((const float2*)(feats + (size_t)s * D))[lane];
        DOT2(sx, cx, nrm, f.x);
        DOT2(sy, cy, nrm, f.y);
    }
    ((float2*)(agg + (size_t)node * D))[lane] = make_float2(sx + cx, sy + cy);
}

// ---------------- conv GEMM: new_feats = agg @ W_conv + b_conv (fp32, untouched) ----
__global__ __launch_bounds__(256) void k_conv(const float* __restrict__ agg,
                                              const float* __restrict__ W,
                                              const float* __restrict__ bias,
                                              float* __restrict__ out) {
    __shared__ float Wl[D * D];        // 64 KB
    __shared__ float xl[TILE_R * D];   // 16 KB
    int r0 = blockIdx.x * TILE_R;
    int rows = min(TILE_R, N_NODES - r0);
    for (int i = threadIdx.x; i < D * D / 4; i += 256)
        ((float4*)Wl)[i] = ((const float4*)W)[i];
    for (int i = threadIdx.x; i < rows * 32; i += 256) {
        int r = i >> 5, q = i & 31;
        ((float4*)(xl + r * D))[q] = ((const float4*)(agg + (size_t)(r0 + r) * D))[q];
    }
    __syncthreads();
    int c = threadIdx.x & 127;
    int half = threadIdx.x >> 7;
    float acc[16];
#pragma unroll
    for (int j = 0; j < 16; j++) acc[j] = 0.f;
    for (int k = 0; k < D; k++) {
        float w = Wl[k * D + c];
#pragma unroll
        for (int j = 0; j < 16; j++) acc[j] += xl[(half + j * 2) * D + k] * w;
    }
    float b = bias[c];
#pragma unroll
    for (int j = 0; j < 16; j++) {
        int r = half + j * 2;
        if (r < rows) out[(size_t)(r0 + r) * D + c] = acc[j] + b;
    }
}

// ---------------- gate v6: plain-f32 scores + gap test; comp-f32 rescore only if ----
// ---------------- decision margin < TAU (wave-uniform rare slow path) -------------
__global__ __launch_bounds__(256) void k_gate(const float* __restrict__ nf,
                                              const float* __restrict__ gW,
                                              const float* __restrict__ gb,
                                              float* __restrict__ gwout,
                                              int* __restrict__ topi) {
    __shared__ float Wl[D * NE];       // 32 KB, layout [k][e]
    __shared__ float xsh[16 * D];      // 8 KB
    for (int i = threadIdx.x; i < D * NE / 4; i += 256)
        ((float4*)Wl)[i] = ((const float4*)gW)[i];
    int t_base = blockIdx.x * 16;
    for (int i = threadIdx.x; i < 16 * 32; i += 256) {
        int r = i >> 5, q = i & 31;
        ((float4*)(xsh + r * D))[q] =
            ((const float4*)(nf + (size_t)(t_base + r) * D))[q];
    }
    __syncthreads();

    int wave = threadIdx.x >> 6;
    int lane = threadIdx.x & 63;      // lane = expert
    int t0 = t_base + wave * 4;
    const float* xw = xsh + wave * 4 * D;

    // ---- phase 1: plain f32 score GEMM (x broadcast from LDS; w stride-1) ----
    float a0 = 0.f, a1 = 0.f, a2 = 0.f, a3 = 0.f;
    for (int k4 = 0; k4 < D; k4 += 4) {
        float x0[4], x1[4], x2[4], x3[4];
        *(float4*)x0 = *(const float4*)(xw + k4);
        *(float4*)x1 = *(const float4*)(xw + D + k4);
        *(float4*)x2 = *(const float4*)(xw + 2 * D + k4);
        *(float4*)x3 = *(const float4*)(xw + 3 * D + k4);
#pragma unroll
        for (int u = 0; u < 4; u++) {
            float w = Wl[(k4 + u) * NE + lane];
            a0 = fmaf(x0[u], w, a0);
            a1 = fmaf(x1[u], w, a1);
            a2 = fmaf(x2[u], w, a2);
            a3 = fmaf(x3[u], w, a3);
        }
    }
    float gbf = gb[lane];
    float af[4] = {a0 + gbf, a1 + gbf, a2 + gbf, a3 + gbf};

    const float TAU = 2e-4f;   // >> plain-f32 dot error (~5e-6 realistic)

#pragma unroll
    for (int j = 0; j < 4; j++) {
        float sf = (j == 0) ? af[0] : (j == 1) ? af[1] : (j == 2) ? af[2] : af[3];
        int t = t0 + j;

        // top-1 (value, lower index wins ties)
        float v1 = sf; int i1 = lane;
#pragma unroll
        for (int off = 32; off; off >>= 1) {
            float ov = __shfl_xor(v1, off);
            int   oi = __shfl_xor(i1, off);
            if (ov > v1 || (ov == v1 && oi < i1)) { v1 = ov; i1 = oi; }
        }
        // top-2 excluding i1
        float v2 = (lane == i1) ? -INFINITY : sf; int i2 = lane;
#pragma unroll
        for (int off = 32; off; off >>= 1) {
            float ov = __shfl_xor(v2, off);
            int   oi = __shfl_xor(i2, off);
            if (ov > v2 || (ov == v2 && oi < i2)) { v2 = ov; i2 = oi; }
        }
        // top-3 value only (just for the gap test)
        float v3 = (lane == i1 || lane == i2) ? -INFINITY : sf;
#pragma unroll
        for (int off = 32; off; off >>= 1)
            v3 = fmaxf(v3, __shfl_xor(v3, off));

        int o1 = i1, o2 = i2;
        float dd = v2 - v1;
        bool need = (v1 - v2 <= TAU) || (v2 - v3 <= TAU);   // wave-uniform
        if (need) {
            // ---- rare slow path: full comp-f32 rescore, exact (v,r,idx) top-2 ----
            const float* xr = xw + j * D;
            float s = 0.f, c = 0.f;
            for (int k = 0; k < D; k++)
                DOT2(s, c, xr[k], Wl[k * NE + lane]);
            TSUM(s, c, gbf);
            float vv = s + c, rr = (s - vv) + c;

            float a1v = vv, a1r = rr; int b1i = lane;
#pragma unroll
            for (int off = 32; off; off >>= 1) {
                float ov = __shfl_xor(a1v, off);
                float orr = __shfl_xor(a1r, off);
                int   oi = __shfl_xor(b1i, off);
                bool gt = (ov > a1v) || (ov == a1v && (orr > a1r || (orr == a1r && oi < b1i)));
                if (gt) { a1v = ov; a1r = orr; b1i = oi; }
            }
            bool ex = (lane == b1i);
            float a2v = ex ? -INFINITY : vv;
            float a2r = ex ? 0.f : rr;
            int b2i = lane;
#pragma unroll
            for (int off = 32; off; off >>= 1) {
                float ov = __shfl_xor(a2v, off);
                float orr = __shfl_xor(a2r, off);
                int   oi = __shfl_xor(b2i, off);
                bool gt = (ov > a2v) || (ov == a2v && (orr > a2r || (orr == a2r && oi < b2i)));
                if (gt) { a2v = ov; a2r = orr; b2i = oi; }
            }
            o1 = b1i; o2 = b2i;
            dd = (a2v - a1v) + (a2r - a1r);
        }

        if (lane == 0) {
            float e2 = expf(dd);
            float g0 = 1.0f / (1.0f + e2);
            gwout[2 * t] = g0;
            gwout[2 * t + 1] = e2 * g0;
            topi[2 * t] = o1;
            topi[2 * t + 1] = o2;
        }
    }
}

// ---------------- dispatch: parallel two-level counting scatter ----------------
__global__ __launch_bounds__(1024) void k_disp(const int* __restrict__ topi,
                                               int* __restrict__ cnt,
                                               int* __restrict__ plist) {
    __shared__ int lcnt[NE];
    __shared__ int lbase[NE];
    int tid = threadIdx.x;
    if (tid < NE) lcnt[tid] = 0;
    __syncthreads();
    int p = blockIdx.x * 1024 + tid;
    int e = 0, lr = 0;
    bool act = (p < NPAIR);
    if (act) {
        e = topi[p];
        lr = atomicAdd(&lcnt[e], 1);
    }
    __syncthreads();
    if (tid < NE) {
        int n = lcnt[tid];
        lbase[tid] = n ? atomicAdd(&cnt[tid], n) : 0;
    }
    __syncthreads();
    if (act) {
        int slot = lbase[e] + lr;
        if (slot < CAP) plist[e * CAP + slot] = p;
    }
}

// ---------------- weight convert: f32 -> bf16 fragments, PRE-SWIZZLED --------------
__global__ __launch_bounds__(256) void k_wconv(const float* __restrict__ W1,
                                               const float* __restrict__ W2,
                                               unsigned short* __restrict__ w1c,
                                               unsigned short* __restrict__ w2c) {
    int gid = blockIdx.x * 256 + threadIdx.x;
    const int NW1 = NE * 4 * 256 * 4;            // 262144
    if (gid < NW1) {
        int lhi = gid & 3, h = (gid >> 2) & 255, ks = (gid >> 10) & 3, e = gid >> 12;
        int u = gid & 4095;                       // (ks*256+h)*4+lhi
        int d0 = ks * 32 + lhi * 8;
        unsigned short v[8] __attribute__((aligned(16)));
#pragma unroll
        for (int j = 0; j < 8; j++)
            v[j] = f2bf(W1[((size_t)e * D + d0 + j) * H + h]);
        *(int4*)((char*)w1c + (size_t)e * 65536 + ((u * 16) ^ ((h & 7) << 4))) = *(int4*)v;
    } else {
        int g = gid - NW1;
        int lhi = g & 3, d = (g >> 2) & 127, ks = (g >> 9) & 7, e = g >> 12;
        int u = g & 4095;                         // (ks*128+d)*4+lhi
        int h0 = ks * 32 + lhi * 8;
        unsigned short v[8] __attribute__((aligned(16)));
#pragma unroll
        for (int j = 0; j < 8; j++)
            v[j] = f2bf(W2[((size_t)e * H + h0 + j) * D + d]);
        *(int4*)((char*)w2c + (size_t)e * 65536 + ((u * 16) ^ ((d & 7) << 4))) = *(int4*)v;
    }
}

// ---------------- MoE FFN v4: 8 waves, W1+W2 resident in LDS (copied, pre-swizzled) --
__global__ __launch_bounds__(512, 1) void k_moe(const float* __restrict__ nf,
                                                const int* __restrict__ cnt,
                                                const int* __restrict__ plist,
                                                const unsigned short* __restrict__ w1c,
                                                const float* __restrict__ b1,
                                                const unsigned short* __restrict__ w2c,
                                                const float* __restrict__ b2,
                                                const float* __restrict__ gwbuf,
                                                unsigned short* __restrict__ ybuf) {
    __shared__ __align__(16) char smem[155648];
    const int W1L = 0, W2L = 65536, XA = 131072, HL = 139264;
    int e = blockIdx.x >> 2;
    int q = blockIdx.x & 3;
    int n = min(cnt[e], CAP);
    int ntile = (n + TILE_R - 1) / TILE_R;
    if (q >= ntile) return;
    int tid = threadIdx.x;

    {
        const int4* s1 = (const int4*)((const char*)w1c + (size_t)e * 65536);
        const int4* s2 = (const int4*)((const char*)w2c + (size_t)e * 65536);
#pragma unroll
        for (int i = 0; i < 8; i++) {
            ((int4*)(smem + W1L))[tid + i * 512] = s1[tid + i * 512];
            ((int4*)(smem + W2L))[tid + i * 512] = s2[tid + i * 512];
        }
    }

    int wv = tid >> 6, lane = tid & 63;
    int lhi = lane >> 4, llo = lane & 15;
    f32x4 zero = {0.f, 0.f, 0.f, 0.f};

    for (int rt = q; rt < ntile; rt += BQ) {
        int r0 = rt * TILE_R;
        int rows = min(TILE_R, n - r0);
        __syncthreads();

        {
            int r = tid >> 4, s = tid & 15;
            float vals[8];
            if (r < rows) {
                int p = plist[e * CAP + r0 + r];
                const float4* xr = (const float4*)(nf + (size_t)(p >> 1) * D + s * 8);
                *(float4*)(vals + 0) = xr[0];
                *(float4*)(vals + 4) = xr[1];
            } else {
#pragma unroll
                for (int k = 0; k < 8; k++) vals[k] = 0.f;
            }
            unsigned short hb[8] __attribute__((aligned(16)));
#pragma unroll
            for (int k = 0; k < 8; k++) hb[k] = f2bf(vals[k]);
            *(int4*)(smem + XA + r * 256 + ((s * 16) ^ ((r & 7) << 4))) = *(int4*)hb;
        }
        __syncthreads();

        f32x4 acc1[2][2];
#pragma unroll
        for (int mt = 0; mt < 2; mt++)
#pragma unroll
            for (int nt = 0; nt < 2; nt++) acc1[mt][nt] = zero;
#pragma unroll
        for (int ks = 0; ks < 4; ks++) {
            int kb = ks * 64 + lhi * 16;
            s16x8 a0 = *(const s16x8*)(smem + XA + llo * 256        + (kb ^ ((llo & 7) << 4)));
            s16x8 a1 = *(const s16x8*)(smem + XA + (llo + 16) * 256 + (kb ^ ((llo & 7) << 4)));
#pragma unroll
            for (int nt = 0; nt < 2; nt++) {
                int h = wv * 32 + nt * 16 + llo;
                int u = (ks * 256 + h) * 4 + lhi;
                s16x8 b = *(const s16x8*)(smem + W1L + ((u * 16) ^ ((h & 7) << 4)));
                acc1[0][nt] = __builtin_amdgcn_mfma_f32_16x16x32_bf16(a0, b, acc1[0][nt], 0, 0, 0);
                acc1[1][nt] = __builtin_amdgcn_mfma_f32_16x16x32_bf16(a1, b, acc1[1][nt], 0, 0, 0);
            }
        }

#pragma unroll
        for (int mt = 0; mt < 2; mt++)
#pragma unroll
            for (int nt = 0; nt < 2; nt++)
#pragma unroll
                for (int r = 0; r < 4; r++) {
                    int m = mt * 16 + lhi * 4 + r;
                    int hc = wv * 32 + nt * 16 + llo;
                    float hv = acc1[mt][nt][r] + b1[e * H + hc];
                    float g = 0.5f * hv * (1.0f + erff(hv * 0.70710678118654752f));
                    *(unsigned short*)(smem + HL + m * 512 + ((hc * 2) ^ ((m & 7) << 4))) = f2bf(g);
                }
        __syncthreads();

        f32x4 acc2[2];
        acc2[0] = zero; acc2[1] = zero;
#pragma unroll
        for (int ks = 0; ks < 8; ks++) {
            int kb = ks * 64 + lhi * 16;
            s16x8 a0 = *(const s16x8*)(smem + HL + llo * 512        + (kb ^ ((llo & 7) << 4)));
            s16x8 a1 = *(const s16x8*)(smem + HL + (llo + 16) * 512 + (kb ^ ((llo & 7) << 4)));
            int d = wv * 16 + llo;
            int u = (ks * 128 + d) * 4 + lhi;
            s16x8 b = *(const s16x8*)(smem + W2L + ((u * 16) ^ ((d & 7) << 4)));
            acc2[0] = __builtin_amdgcn_mfma_f32_16x16x32_bf16(a0, b, acc2[0], 0, 0, 0);
            acc2[1] = __builtin_amdgcn_mfma_f32_16x16x32_bf16(a1, b, acc2[1], 0, 0, 0);
        }

        int d = wv * 16 + llo;
        float bb = b2[e * D + d];
#pragma unroll
        for (int mt = 0; mt < 2; mt++)
#pragma unroll
            for (int r = 0; r < 4; r++) {
                int m = mt * 16 + lhi * 4 + r;
                if (m < rows) {
                    int p = plist[e * CAP + r0 + m];
                    ybuf[(size_t)p * D + d] = f2bf(gwbuf[p] * (acc2[mt][r] + bb));
                }
            }
    }
}

// ---------------- BatchNorm ----------------
__global__ __launch_bounds__(256) void k_bnpart(const float* __restrict__ nf,
                                                const unsigned short* __restrict__ ybuf,
                                                double* __restrict__ part) {
    int blk = blockIdx.x;
    int col = threadIdx.x & 127;
    int half = threadIdx.x >> 7;
    int r0 = blk * BN_ROWS;
    int r1 = min(r0 + BN_ROWS, N_NODES);
    double s = 0.0, ss = 0.0;
    for (int r = r0 + half; r < r1; r += 2) {
        float v32 = nf[(size_t)r * D + col]
                  + bf2f(ybuf[(size_t)(2 * r) * D + col])
                  + bf2f(ybuf[(size_t)(2 * r + 1) * D + col]);
        double v = (double)v32;
        s += v; ss += v * v;
    }
    __shared__ double sh[2][256];
    sh[0][threadIdx.x] = s; sh[1][threadIdx.x] = ss;
    __syncthreads();
    if (threadIdx.x < 128) {
        part[(size_t)blk * 256 + col]       = sh[0][col] + sh[0][col + 128];
        part[(size_t)blk * 256 + 128 + col] = sh[1][col] + sh[1][col + 128];
    }
}

__global__ void k_bnstats(const double* __restrict__ part,
                          const float* __restrict__ gamma,
                          float* __restrict__ stats) {
    int col = threadIdx.x;   // 128 threads
    double s = 0.0, ss = 0.0;
    for (int b = 0; b < BN_NBLK; b++) {
        s  += part[(size_t)b * 256 + col];
        ss += part[(size_t)b * 256 + 128 + col];
    }
    double mean = s / (double)N_NODES;
    double var = ss / (double)N_NODES - mean * mean;
    stats[col] = (float)mean;
    stats[128 + col] = gamma[col] * (float)(1.0 / sqrt(var + 1e-5));
}

__global__ __launch_bounds__(256) void k_bnapply(const unsigned short* __restrict__ ybuf,
                                                 const float* __restrict__ stats,
                                                 const float* __restrict__ beta,
                                                 float* __restrict__ out) {
    int i = blockIdx.x * blockDim.x + threadIdx.x;   // float4 index
    if (i >= N_NODES * (D / 4)) return;
    int t = i >> 5;
    int q = i & 31;
    int c0 = q * 4;
    float4 v  = ((float4*)out)[i];
    short4 y0v = *(const short4*)(ybuf + (size_t)(2 * t) * D + c0);
    short4 y1v = *(const short4*)(ybuf + (size_t)(2 * t + 1) * D + c0);
    float4 r;
    r.x = (v.x + bf2f((unsigned short)y0v.x) + bf2f((unsigned short)y1v.x) - stats[c0 + 0]) * stats[128 + c0 + 0] + beta[c0 + 0];
    r.y = (v.y + bf2f((unsigned short)y0v.y) + bf2f((unsigned short)y1v.y) - stats[c0 + 1]) * stats[128 + c0 + 1] + beta[c0 + 1];
    r.z = (v.z + bf2f((unsigned short)y0v.z) + bf2f((unsigned short)y1v.z) - stats[c0 + 2]) * stats[128 + c0 + 2] + beta[c0 + 2];
    r.w = (v.w + bf2f((unsigned short)y0v.w) + bf2f((unsigned short)y1v.w) - stats[c0 + 3]) * stats[128 + c0 + 3] + beta[c0 + 3];
    ((float4*)out)[i] = r;
}

// ---------------- launch ----------------
extern "C" void kernel_launch(void* const* d_in, const int* in_sizes, int n_in,
                              void* d_out, int out_size, void* d_ws, size_t ws_size,
                              hipStream_t stream) {
    const float* feats   = (const float*)d_in[0];
    const int*   esrc    = (const int*)d_in[1];
    const int*   edst    = (const int*)d_in[2];
    const float* W_conv  = (const float*)d_in[3];
    const float* b_conv  = (const float*)d_in[4];
    const float* gate_W  = (const float*)d_in[5];
    const float* gate_b  = (const float*)d_in[6];
    const float* W1      = (const float*)d_in[7];
    const float* b1      = (const float*)d_in[8];
    const float* W2      = (const float*)d_in[9];
    const float* b2      = (const float*)d_in[10];
    const float* bn_g    = (const float*)d_in[11];
    const float* bn_b    = (const float*)d_in[12];
    float* out = (float*)d_out;   // doubles as new_feats storage

    char* ws = (char*)d_ws;
    size_t off = 0;
    auto rup = [](size_t x) { return (x + 255) & ~(size_t)255; };
    int*    deg    = (int*)   (ws + off); off += rup((size_t)N_NODES * 4);
    int*    cursor = (int*)   (ws + off); off += rup((size_t)N_NODES * 4);
    int*    cnt    = (int*)   (ws + off); off += 256;
    size_t zero_bytes = off;                 // deg + cursor + cnt (~400 KB)
    float*  invs   = (float*) (ws + off); off += rup((size_t)N_NODES * 4);
    int*    rowptr = (int*)   (ws + off); off += rup((size_t)(N_NODES + 1) * 4);
    int*    csr    = (int*)   (ws + off); off += rup((size_t)N_EDGES * 4);
    float*  gwbuf  = (float*) (ws + off); off += rup((size_t)NPAIR * 4);
    int*    topi   = (int*)   (ws + off); off += rup((size_t)NPAIR * 4);
    int*    plist  = (int*)   (ws + off); off += rup((size_t)NE * CAP * 4);
    double* part   = (double*)(ws + off); off += rup((size_t)BN_NBLK * 256 * 8);
    float*  stats  = (float*) (ws + off); off += 1024;
    unsigned short* w1c = (unsigned short*)(ws + off); off += rup((size_t)NE * D * H * 2); // 4 MB
    unsigned short* w2c = (unsigned short*)(ws + off); off += rup((size_t)NE * D * H * 2); // 4 MB
    unsigned short* ybuf = (unsigned short*)(ws + off); off += rup((size_t)NPAIR * D * 2); // 25.6 MB
    float*  agg    = (float*)ybuf;   // lifetime-disjoint alias (agg dead before k_moe writes ybuf)
    (void)ws_size; (void)in_sizes; (void)n_in; (void)out_size;

    hipMemsetAsync(d_ws, 0, zero_bytes, stream);

    k_wconv<<<2 * NE * 4 * 256 * 4 / 256, 256, 0, stream>>>(W1, W2, w1c, w2c);
    k_deg<<<(N_EDGES + 255) / 256, 256, 0, stream>>>(edst, deg);
    k_invsqrt<<<(N_NODES + 255) / 256, 256, 0, stream>>>(deg, invs);
    k_scan<<<1, 1024, 0, stream>>>(deg, rowptr);
    k_scatter<<<(N_EDGES + 255) / 256, 256, 0, stream>>>(esrc, edst, rowptr, cursor, csr);
    k_gather<<<(N_NODES + 3) / 4, 256, 0, stream>>>(feats, rowptr, csr, invs, agg);
    k_conv<<<(N_NODES + TILE_R - 1) / TILE_R, 256, 0, stream>>>(agg, W_conv, b_conv, out);
    k_gate<<<N_NODES / 16, 256, 0, stream>>>(out, gate_W, gate_b, gwbuf, topi);
    k_disp<<<(NPAIR + 1023) / 1024, 1024, 0, stream>>>(topi, cnt, plist);
    k_moe<<<NE * BQ, 512, 0, stream>>>(out, cnt, plist, w1c, b1, w2c, b2, gwbuf, ybuf);
    k_bnpart<<<BN_NBLK, 256, 0, stream>>>(out, ybuf, part);
    k_bnstats<<<1, 128, 0, stream>>>(part, bn_g, stats);
    k_bnapply<<<(N_NODES * (D / 4) + 255) / 256, 256, 0, stream>>>(ybuf, stats, bn_b, out);
}

// Round 12
// 627.957 us; speedup vs baseline: 1.0306x; 1.0306x over previous
//
#include <hip/hip_runtime.h>
#include <math.h>

#define N_NODES 50000
#define N_EDGES 500000
#define D 128
#define H 256
#define NE 64
#define TOPK 2
#define NPAIR (N_NODES * TOPK)
#define CAP 3126               // 2 * ceil(100000/64)
#define TILE_R 32
#define BQ 4                   // blocks per expert in k_moe
#define BN_NBLK 128
#define BN_ROWS ((N_NODES + BN_NBLK - 1) / BN_NBLK) // 391

typedef __attribute__((ext_vector_type(8))) short s16x8;
typedef __attribute__((ext_vector_type(4))) float f32x4;

__device__ __forceinline__ unsigned short f2bf(float f) {
    unsigned u = __float_as_uint(f);
    unsigned r = (u + 0x7fffu + ((u >> 16) & 1u)) >> 16;
    return (unsigned short)r;
}
__device__ __forceinline__ float bf2f(unsigned short u) {
    return __uint_as_float(((unsigned)u) << 16);
}

// Compensated f32: TwoProd (mul + fma residual) + branch-free TwoSum.
#define DOT2(s, c, xx, ww) {                      \
    float p_ = (xx) * (ww);                       \
    float e1_ = fmaf((xx), (ww), -p_);            \
    float t_ = (s) + p_;                          \
    float z_ = t_ - (s);                          \
    float e2_ = ((s) - (t_ - z_)) + (p_ - z_);    \
    (s) = t_;                                     \
    (c) += e1_ + e2_; }

#define TSUM(s, c, pp) {                          \
    float p_ = (pp);                              \
    float t_ = (s) + p_;                          \
    float z_ = t_ - (s);                          \
    float e2_ = ((s) - (t_ - z_)) + (p_ - z_);    \
    (s) = t_;                                     \
    (c) += e2_; }

// ---------------- degree count ----------------
__global__ void k_deg(const int* __restrict__ dst, int* __restrict__ deg) {
    int i = blockIdx.x * blockDim.x + threadIdx.x;
    if (i < N_EDGES) atomicAdd(&deg[dst[i]], 1);
}

__global__ void k_invsqrt(const int* __restrict__ deg, float* __restrict__ invs) {
    int i = blockIdx.x * blockDim.x + threadIdx.x;
    if (i < N_NODES) {
        double d = (double)deg[i];
        if (d < 1.0) d = 1.0;
        invs[i] = (float)(1.0 / sqrt(d));
    }
}

// ---------------- exclusive scan of deg -> rowptr ----------------
__global__ __launch_bounds__(1024) void k_scan(const int* __restrict__ deg,
                                               int* __restrict__ rowptr) {
    __shared__ int sh[1024];
    int t = threadIdx.x;
    const int chunk = (N_NODES + 1023) / 1024;   // 49
    int lo = t * chunk;
    int hi = min(lo + chunk, N_NODES);
    int s = 0;
    for (int i = lo; i < hi; i++) s += deg[i];
    sh[t] = s;
    __syncthreads();
    for (int off = 1; off < 1024; off <<= 1) {
        int v = (t >= off) ? sh[t - off] : 0;
        __syncthreads();
        sh[t] += v;
        __syncthreads();
    }
    int run = (t == 0) ? 0 : sh[t - 1];
    for (int i = lo; i < hi; i++) { rowptr[i] = run; run += deg[i]; }
    if (t == 1023) rowptr[N_NODES] = run;
}

// ---------------- scatter edges into CSR ----------------
__global__ void k_scatter(const int* __restrict__ src, const int* __restrict__ dst,
                          const int* __restrict__ rowptr, int* __restrict__ cursor,
                          int* __restrict__ csr) {
    int e = blockIdx.x * blockDim.x + threadIdx.x;
    if (e >= N_EDGES) return;
    int d = dst[e];
    int pos = atomicAdd(&cursor[d], 1);
    csr[rowptr[d] + pos] = src[e];
}

// ---------------- per-node gather (compensated f32, order-independent ~1e-12) ----
__global__ __launch_bounds__(256) void k_gather(const float* __restrict__ feats,
                                                const int* __restrict__ rowptr,
                                                const int* __restrict__ csr,
                                                const float* __restrict__ invs,
                                                float* __restrict__ agg) {
    int node = blockIdx.x * 4 + (threadIdx.x >> 6);
    if (node >= N_NODES) return;
    int lane = threadIdx.x & 63;
    int beg = rowptr[node], end = rowptr[node + 1];
    float wd = invs[node];
    float sx = 0.f, cx = 0.f, sy = 0.f, cy = 0.f;
    for (int i = beg; i < end; i++) {
        int s = csr[i];
        float nrm = invs[s] * wd;
        float2 f = ((const float2*)(feats + (size_t)s * D))[lane];
        DOT2(sx, cx, nrm, f.x);
        DOT2(sy, cy, nrm, f.y);
    }
    ((float2*)(agg + (size_t)node * D))[lane] = make_float2(sx + cx, sy + cy);
}

// ---------------- conv GEMM: new_feats = agg @ W_conv + b_conv (fp32, untouched) ----
__global__ __launch_bounds__(256) void k_conv(const float* __restrict__ agg,
                                              const float* __restrict__ W,
                                              const float* __restrict__ bias,
                                              float* __restrict__ out) {
    __shared__ float Wl[D * D];        // 64 KB
    __shared__ float xl[TILE_R * D];   // 16 KB
    int r0 = blockIdx.x * TILE_R;
    int rows = min(TILE_R, N_NODES - r0);
    for (int i = threadIdx.x; i < D * D / 4; i += 256)
        ((float4*)Wl)[i] = ((const float4*)W)[i];
    for (int i = threadIdx.x; i < rows * 32; i += 256) {
        int r = i >> 5, q = i & 31;
        ((float4*)(xl + r * D))[q] = ((const float4*)(agg + (size_t)(r0 + r) * D))[q];
    }
    __syncthreads();
    int c = threadIdx.x & 127;
    int half = threadIdx.x >> 7;
    float acc[16];
#pragma unroll
    for (int j = 0; j < 16; j++) acc[j] = 0.f;
    for (int k = 0; k < D; k++) {
        float w = Wl[k * D + c];
#pragma unroll
        for (int j = 0; j < 16; j++) acc[j] += xl[(half + j * 2) * D + k] * w;
    }
    float b = bias[c];
#pragma unroll
    for (int j = 0; j < 16; j++) {
        int r = half + j * 2;
        if (r < rows) out[(size_t)(r0 + r) * D + c] = acc[j] + b;
    }
}

// ---------------- gate v7 FAST: plain-f32 scores + gap test; ambiguous -> redo list --
__global__ __launch_bounds__(256) void k_gate(const float* __restrict__ nf,
                                              const float* __restrict__ gW,
                                              const float* __restrict__ gb,
                                              float* __restrict__ gwout,
                                              int* __restrict__ topi,
                                              int* __restrict__ rcnt,
                                              int* __restrict__ redo) {
    __shared__ float Wl[D * NE];       // 32 KB, layout [k][e]
    __shared__ float xsh[16 * D];      // 8 KB
    for (int i = threadIdx.x; i < D * NE / 4; i += 256)
        ((float4*)Wl)[i] = ((const float4*)gW)[i];
    int t_base = blockIdx.x * 16;
    for (int i = threadIdx.x; i < 16 * 32; i += 256) {
        int r = i >> 5, q = i & 31;
        ((float4*)(xsh + r * D))[q] =
            ((const float4*)(nf + (size_t)(t_base + r) * D))[q];
    }
    __syncthreads();

    int wave = threadIdx.x >> 6;
    int lane = threadIdx.x & 63;      // lane = expert
    int t0 = t_base + wave * 4;
    const float* xw = xsh + wave * 4 * D;

    float a0 = 0.f, a1 = 0.f, a2 = 0.f, a3 = 0.f;
    for (int k4 = 0; k4 < D; k4 += 4) {
        float x0[4], x1[4], x2[4], x3[4];
        *(float4*)x0 = *(const float4*)(xw + k4);
        *(float4*)x1 = *(const float4*)(xw + D + k4);
        *(float4*)x2 = *(const float4*)(xw + 2 * D + k4);
        *(float4*)x3 = *(const float4*)(xw + 3 * D + k4);
#pragma unroll
        for (int u = 0; u < 4; u++) {
            float w = Wl[(k4 + u) * NE + lane];
            a0 = fmaf(x0[u], w, a0);
            a1 = fmaf(x1[u], w, a1);
            a2 = fmaf(x2[u], w, a2);
            a3 = fmaf(x3[u], w, a3);
        }
    }
    float gbf = gb[lane];
    float af[4] = {a0 + gbf, a1 + gbf, a2 + gbf, a3 + gbf};

    const float TAU = 2e-4f;   // >> plain-f32 dot error (~5e-6 realistic)

#pragma unroll
    for (int j = 0; j < 4; j++) {
        float sf = (j == 0) ? af[0] : (j == 1) ? af[1] : (j == 2) ? af[2] : af[3];
        int t = t0 + j;

        // top-1 (value, lower index wins ties)
        float v1 = sf; int i1 = lane;
#pragma unroll
        for (int off = 32; off; off >>= 1) {
            float ov = __shfl_xor(v1, off);
            int   oi = __shfl_xor(i1, off);
            if (ov > v1 || (ov == v1 && oi < i1)) { v1 = ov; i1 = oi; }
        }
        // top-2 excluding i1
        float v2 = (lane == i1) ? -INFINITY : sf; int i2 = lane;
#pragma unroll
        for (int off = 32; off; off >>= 1) {
            float ov = __shfl_xor(v2, off);
            int   oi = __shfl_xor(i2, off);
            if (ov > v2 || (ov == v2 && oi < i2)) { v2 = ov; i2 = oi; }
        }
        // top-3 value only (gap test)
        float v3 = (lane == i1 || lane == i2) ? -INFINITY : sf;
#pragma unroll
        for (int off = 32; off; off >>= 1)
            v3 = fmaxf(v3, __shfl_xor(v3, off));

        if (lane == 0) {
            float dd = v2 - v1;
            float e2 = expf(dd);
            float g0 = 1.0f / (1.0f + e2);
            gwout[2 * t] = g0;
            gwout[2 * t + 1] = e2 * g0;
            topi[2 * t] = i1;
            topi[2 * t + 1] = i2;
            if ((v1 - v2 <= TAU) || (v2 - v3 <= TAU)) {
                int slot = atomicAdd(rcnt, 1);
                redo[slot] = t;
            }
        }
    }
}

// ---------------- gate FIX: comp-f32 rescore of ambiguous tokens (rare) ------------
__global__ __launch_bounds__(256) void k_gfix(const float* __restrict__ nf,
                                              const float* __restrict__ gW,
                                              const float* __restrict__ gb,
                                              const int* __restrict__ rcnt,
                                              const int* __restrict__ redo,
                                              float* __restrict__ gwout,
                                              int* __restrict__ topi) {
    int nredo = *rcnt;
    int lane = threadIdx.x & 63;
    int widx = blockIdx.x * 4 + (threadIdx.x >> 6);
    float gbf = gb[lane];
    for (int i = widx; i < nredo; i += gridDim.x * 4) {
        int t = redo[i];
        const float* xr = nf + (size_t)t * D;
        float s = 0.f, c = 0.f;
        for (int k = 0; k < D; k++)
            DOT2(s, c, xr[k], gW[k * NE + lane]);
        TSUM(s, c, gbf);
        float vv = s + c, rr = (s - vv) + c;

        float a1v = vv, a1r = rr; int i1 = lane;
#pragma unroll
        for (int off = 32; off; off >>= 1) {
            float ov = __shfl_xor(a1v, off);
            float orr = __shfl_xor(a1r, off);
            int   oi = __shfl_xor(i1, off);
            bool gt = (ov > a1v) || (ov == a1v && (orr > a1r || (orr == a1r && oi < i1)));
            if (gt) { a1v = ov; a1r = orr; i1 = oi; }
        }
        bool ex = (lane == i1);
        float a2v = ex ? -INFINITY : vv;
        float a2r = ex ? 0.f : rr;
        int i2 = lane;
#pragma unroll
        for (int off = 32; off; off >>= 1) {
            float ov = __shfl_xor(a2v, off);
            float orr = __shfl_xor(a2r, off);
            int   oi = __shfl_xor(i2, off);
            bool gt = (ov > a2v) || (ov == a2v && (orr > a2r || (orr == a2r && oi < i2)));
            if (gt) { a2v = ov; a2r = orr; i2 = oi; }
        }

        if (lane == 0) {
            float dd = (a2v - a1v) + (a2r - a1r);
            float e2 = expf(dd);
            float g0 = 1.0f / (1.0f + e2);
            gwout[2 * t] = g0;
            gwout[2 * t + 1] = e2 * g0;
            topi[2 * t] = i1;
            topi[2 * t + 1] = i2;
        }
    }
}

// ---------------- dispatch: parallel two-level counting scatter ----------------
__global__ __launch_bounds__(1024) void k_disp(const int* __restrict__ topi,
                                               int* __restrict__ cnt,
                                               int* __restrict__ plist) {
    __shared__ int lcnt[NE];
    __shared__ int lbase[NE];
    int tid = threadIdx.x;
    if (tid < NE) lcnt[tid] = 0;
    __syncthreads();
    int p = blockIdx.x * 1024 + tid;
    int e = 0, lr = 0;
    bool act = (p < NPAIR);
    if (act) {
        e = topi[p];
        lr = atomicAdd(&lcnt[e], 1);
    }
    __syncthreads();
    if (tid < NE) {
        int n = lcnt[tid];
        lbase[tid] = n ? atomicAdd(&cnt[tid], n) : 0;
    }
    __syncthreads();
    if (act) {
        int slot = lbase[e] + lr;
        if (slot < CAP) plist[e * CAP + slot] = p;
    }
}

// ---------------- weight convert: f32 -> bf16 fragments, PRE-SWIZZLED --------------
__global__ __launch_bounds__(256) void k_wconv(const float* __restrict__ W1,
                                               const float* __restrict__ W2,
                                               unsigned short* __restrict__ w1c,
                                               unsigned short* __restrict__ w2c) {
    int gid = blockIdx.x * 256 + threadIdx.x;
    const int NW1 = NE * 4 * 256 * 4;            // 262144
    if (gid < NW1) {
        int lhi = gid & 3, h = (gid >> 2) & 255, ks = (gid >> 10) & 3, e = gid >> 12;
        int u = gid & 4095;                       // (ks*256+h)*4+lhi
        int d0 = ks * 32 + lhi * 8;
        unsigned short v[8] __attribute__((aligned(16)));
#pragma unroll
        for (int j = 0; j < 8; j++)
            v[j] = f2bf(W1[((size_t)e * D + d0 + j) * H + h]);
        *(int4*)((char*)w1c + (size_t)e * 65536 + ((u * 16) ^ ((h & 7) << 4))) = *(int4*)v;
    } else {
        int g = gid - NW1;
        int lhi = g & 3, d = (g >> 2) & 127, ks = (g >> 9) & 7, e = g >> 12;
        int u = g & 4095;                         // (ks*128+d)*4+lhi
        int h0 = ks * 32 + lhi * 8;
        unsigned short v[8] __attribute__((aligned(16)));
#pragma unroll
        for (int j = 0; j < 8; j++)
            v[j] = f2bf(W2[((size_t)e * H + h0 + j) * D + d]);
        *(int4*)((char*)w2c + (size_t)e * 65536 + ((u * 16) ^ ((d & 7) << 4))) = *(int4*)v;
    }
}

// ---------------- MoE FFN v4: 8 waves, W1+W2 resident in LDS (copied, pre-swizzled) --
__global__ __launch_bounds__(512, 1) void k_moe(const float* __restrict__ nf,
                                                const int* __restrict__ cnt,
                                                const int* __restrict__ plist,
                                                const unsigned short* __restrict__ w1c,
                                                const float* __restrict__ b1,
                                                const unsigned short* __restrict__ w2c,
                                                const float* __restrict__ b2,
                                                const float* __restrict__ gwbuf,
                                                unsigned short* __restrict__ ybuf) {
    __shared__ __align__(16) char smem[155648];
    const int W1L = 0, W2L = 65536, XA = 131072, HL = 139264;
    int e = blockIdx.x >> 2;
    int q = blockIdx.x & 3;
    int n = min(cnt[e], CAP);
    int ntile = (n + TILE_R - 1) / TILE_R;
    if (q >= ntile) return;
    int tid = threadIdx.x;

    {
        const int4* s1 = (const int4*)((const char*)w1c + (size_t)e * 65536);
        const int4* s2 = (const int4*)((const char*)w2c + (size_t)e * 65536);
#pragma unroll
        for (int i = 0; i < 8; i++) {
            ((int4*)(smem + W1L))[tid + i * 512] = s1[tid + i * 512];
            ((int4*)(smem + W2L))[tid + i * 512] = s2[tid + i * 512];
        }
    }

    int wv = tid >> 6, lane = tid & 63;
    int lhi = lane >> 4, llo = lane & 15;
    f32x4 zero = {0.f, 0.f, 0.f, 0.f};

    for (int rt = q; rt < ntile; rt += BQ) {
        int r0 = rt * TILE_R;
        int rows = min(TILE_R, n - r0);
        __syncthreads();

        {
            int r = tid >> 4, s = tid & 15;
            float vals[8];
            if (r < rows) {
                int p = plist[e * CAP + r0 + r];
                const float4* xr = (const float4*)(nf + (size_t)(p >> 1) * D + s * 8);
                *(float4*)(vals + 0) = xr[0];
                *(float4*)(vals + 4) = xr[1];
            } else {
#pragma unroll
                for (int k = 0; k < 8; k++) vals[k] = 0.f;
            }
            unsigned short hb[8] __attribute__((aligned(16)));
#pragma unroll
            for (int k = 0; k < 8; k++) hb[k] = f2bf(vals[k]);
            *(int4*)(smem + XA + r * 256 + ((s * 16) ^ ((r & 7) << 4))) = *(int4*)hb;
        }
        __syncthreads();

        f32x4 acc1[2][2];
#pragma unroll
        for (int mt = 0; mt < 2; mt++)
#pragma unroll
            for (int nt = 0; nt < 2; nt++) acc1[mt][nt] = zero;
#pragma unroll
        for (int ks = 0; ks < 4; ks++) {
            int kb = ks * 64 + lhi * 16;
            s16x8 a0 = *(const s16x8*)(smem + XA + llo * 256        + (kb ^ ((llo & 7) << 4)));
            s16x8 a1 = *(const s16x8*)(smem + XA + (llo + 16) * 256 + (kb ^ ((llo & 7) << 4)));
#pragma unroll
            for (int nt = 0; nt < 2; nt++) {
                int h = wv * 32 + nt * 16 + llo;
                int u = (ks * 256 + h) * 4 + lhi;
                s16x8 b = *(const s16x8*)(smem + W1L + ((u * 16) ^ ((h & 7) << 4)));
                acc1[0][nt] = __builtin_amdgcn_mfma_f32_16x16x32_bf16(a0, b, acc1[0][nt], 0, 0, 0);
                acc1[1][nt] = __builtin_amdgcn_mfma_f32_16x16x32_bf16(a1, b, acc1[1][nt], 0, 0, 0);
            }
        }

#pragma unroll
        for (int mt = 0; mt < 2; mt++)
#pragma unroll
            for (int nt = 0; nt < 2; nt++)
#pragma unroll
                for (int r = 0; r < 4; r++) {
                    int m = mt * 16 + lhi * 4 + r;
                    int hc = wv * 32 + nt * 16 + llo;
                    float hv = acc1[mt][nt][r] + b1[e * H + hc];
                    float g = 0.5f * hv * (1.0f + erff(hv * 0.70710678118654752f));
                    *(unsigned short*)(smem + HL + m * 512 + ((hc * 2) ^ ((m & 7) << 4))) = f2bf(g);
                }
        __syncthreads();

        f32x4 acc2[2];
        acc2[0] = zero; acc2[1] = zero;
#pragma unroll
        for (int ks = 0; ks < 8; ks++) {
            int kb = ks * 64 + lhi * 16;
            s16x8 a0 = *(const s16x8*)(smem + HL + llo * 512        + (kb ^ ((llo & 7) << 4)));
            s16x8 a1 = *(const s16x8*)(smem + HL + (llo + 16) * 512 + (kb ^ ((llo & 7) << 4)));
            int d = wv * 16 + llo;
            int u = (ks * 128 + d) * 4 + lhi;
            s16x8 b = *(const s16x8*)(smem + W2L + ((u * 16) ^ ((d & 7) << 4)));
            acc2[0] = __builtin_amdgcn_mfma_f32_16x16x32_bf16(a0, b, acc2[0], 0, 0, 0);
            acc2[1] = __builtin_amdgcn_mfma_f32_16x16x32_bf16(a1, b, acc2[1], 0, 0, 0);
        }

        int d = wv * 16 + llo;
        float bb = b2[e * D + d];
#pragma unroll
        for (int mt = 0; mt < 2; mt++)
#pragma unroll
            for (int r = 0; r < 4; r++) {
                int m = mt * 16 + lhi * 4 + r;
                if (m < rows) {
                    int p = plist[e * CAP + r0 + m];
                    ybuf[(size_t)p * D + d] = f2bf(gwbuf[p] * (acc2[mt][r] + bb));
                }
            }
    }
}

// ---------------- BatchNorm ----------------
__global__ __launch_bounds__(256) void k_bnpart(const float* __restrict__ nf,
                                                const unsigned short* __restrict__ ybuf,
                                                double* __restrict__ part) {
    int blk = blockIdx.x;
    int col = threadIdx.x & 127;
    int half = threadIdx.x >> 7;
    int r0 = blk * BN_ROWS;
    int r1 = min(r0 + BN_ROWS, N_NODES);
    double s = 0.0, ss = 0.0;
    for (int r = r0 + half; r < r1; r += 2) {
        float v32 = nf[(size_t)r * D + col]
                  + bf2f(ybuf[(size_t)(2 * r) * D + col])
                  + bf2f(ybuf[(size_t)(2 * r + 1) * D + col]);
        double v = (double)v32;
        s += v; ss += v * v;
    }
    __shared__ double sh[2][256];
    sh[0][threadIdx.x] = s; sh[1][threadIdx.x] = ss;
    __syncthreads();
    if (threadIdx.x < 128) {
        part[(size_t)blk * 256 + col]       = sh[0][col] + sh[0][col + 128];
        part[(size_t)blk * 256 + 128 + col] = sh[1][col] + sh[1][col + 128];
    }
}

__global__ void k_bnstats(const double* __restrict__ part,
                          const float* __restrict__ gamma,
                          float* __restrict__ stats) {
    int col = threadIdx.x;   // 128 threads
    double s = 0.0, ss = 0.0;
    for (int b = 0; b < BN_NBLK; b++) {
        s  += part[(size_t)b * 256 + col];
        ss += part[(size_t)b * 256 + 128 + col];
    }
    double mean = s / (double)N_NODES;
    double var = ss / (double)N_NODES - mean * mean;
    stats[col] = (float)mean;
    stats[128 + col] = gamma[col] * (float)(1.0 / sqrt(var + 1e-5));
}

__global__ __launch_bounds__(256) void k_bnapply(const unsigned short* __restrict__ ybuf,
                                                 const float* __restrict__ stats,
                                                 const float* __restrict__ beta,
                                                 float* __restrict__ out) {
    int i = blockIdx.x * blockDim.x + threadIdx.x;   // float4 index
    if (i >= N_NODES * (D / 4)) return;
    int t = i >> 5;
    int q = i & 31;
    int c0 = q * 4;
    float4 v  = ((float4*)out)[i];
    short4 y0v = *(const short4*)(ybuf + (size_t)(2 * t) * D + c0);
    short4 y1v = *(const short4*)(ybuf + (size_t)(2 * t + 1) * D + c0);
    float4 r;
    r.x = (v.x + bf2f((unsigned short)y0v.x) + bf2f((unsigned short)y1v.x) - stats[c0 + 0]) * stats[128 + c0 + 0] + beta[c0 + 0];
    r.y = (v.y + bf2f((unsigned short)y0v.y) + bf2f((unsigned short)y1v.y) - stats[c0 + 1]) * stats[128 + c0 + 1] + beta[c0 + 1];
    r.z = (v.z + bf2f((unsigned short)y0v.z) + bf2f((unsigned short)y1v.z) - stats[c0 + 2]) * stats[128 + c0 + 2] + beta[c0 + 2];
    r.w = (v.w + bf2f((unsigned short)y0v.w) + bf2f((unsigned short)y1v.w) - stats[c0 + 3]) * stats[128 + c0 + 3] + beta[c0 + 3];
    ((float4*)out)[i] = r;
}

// ---------------- launch ----------------
extern "C" void kernel_launch(void* const* d_in, const int* in_sizes, int n_in,
                              void* d_out, int out_size, void* d_ws, size_t ws_size,
                              hipStream_t stream) {
    const float* feats   = (const float*)d_in[0];
    const int*   esrc    = (const int*)d_in[1];
    const int*   edst    = (const int*)d_in[2];
    const float* W_conv  = (const float*)d_in[3];
    const float* b_conv  = (const float*)d_in[4];
    const float* gate_W  = (const float*)d_in[5];
    const float* gate_b  = (const float*)d_in[6];
    const float* W1      = (const float*)d_in[7];
    const float* b1      = (const float*)d_in[8];
    const float* W2      = (const float*)d_in[9];
    const float* b2      = (const float*)d_in[10];
    const float* bn_g    = (const float*)d_in[11];
    const float* bn_b    = (const float*)d_in[12];
    float* out = (float*)d_out;   // doubles as new_feats storage

    char* ws = (char*)d_ws;
    size_t off = 0;
    auto rup = [](size_t x) { return (x + 255) & ~(size_t)255; };
    int*    deg    = (int*)   (ws + off); off += rup((size_t)N_NODES * 4);
    int*    cursor = (int*)   (ws + off); off += rup((size_t)N_NODES * 4);
    int*    cnt    = (int*)   (ws + off); off += 256;
    int*    rcnt   = (int*)   (ws + off); off += 256;
    size_t zero_bytes = off;                 // deg + cursor + cnt + rcnt (~400 KB)
    float*  invs   = (float*) (ws + off); off += rup((size_t)N_NODES * 4);
    int*    rowptr = (int*)   (ws + off); off += rup((size_t)(N_NODES + 1) * 4);
    int*    csr    = (int*)   (ws + off); off += rup((size_t)N_EDGES * 4);
    float*  gwbuf  = (float*) (ws + off); off += rup((size_t)NPAIR * 4);
    int*    topi   = (int*)   (ws + off); off += rup((size_t)NPAIR * 4);
    int*    redo   = (int*)   (ws + off); off += rup((size_t)N_NODES * 4);
    int*    plist  = (int*)   (ws + off); off += rup((size_t)NE * CAP * 4);
    double* part   = (double*)(ws + off); off += rup((size_t)BN_NBLK * 256 * 8);
    float*  stats  = (float*) (ws + off); off += 1024;
    unsigned short* w1c = (unsigned short*)(ws + off); off += rup((size_t)NE * D * H * 2); // 4 MB
    unsigned short* w2c = (unsigned short*)(ws + off); off += rup((size_t)NE * D * H * 2); // 4 MB
    unsigned short* ybuf = (unsigned short*)(ws + off); off += rup((size_t)NPAIR * D * 2); // 25.6 MB
    float*  agg    = (float*)ybuf;   // lifetime-disjoint alias (agg dead before k_moe writes ybuf)
    (void)ws_size; (void)in_sizes; (void)n_in; (void)out_size;

    hipMemsetAsync(d_ws, 0, zero_bytes, stream);

    k_wconv<<<2 * NE * 4 * 256 * 4 / 256, 256, 0, stream>>>(W1, W2, w1c, w2c);
    k_deg<<<(N_EDGES + 255) / 256, 256, 0, stream>>>(edst, deg);
    k_invsqrt<<<(N_NODES + 255) / 256, 256, 0, stream>>>(deg, invs);
    k_scan<<<1, 1024, 0, stream>>>(deg, rowptr);
    k_scatter<<<(N_EDGES + 255) / 256, 256, 0, stream>>>(esrc, edst, rowptr, cursor, csr);
    k_gather<<<(N_NODES + 3) / 4, 256, 0, stream>>>(feats, rowptr, csr, invs, agg);
    k_conv<<<(N_NODES + TILE_R - 1) / TILE_R, 256, 0, stream>>>(agg, W_conv, b_conv, out);
    k_gate<<<N_NODES / 16, 256, 0, stream>>>(out, gate_W, gate_b, gwbuf, topi, rcnt, redo);
    k_gfix<<<128, 256, 0, stream>>>(out, gate_W, gate_b, rcnt, redo, gwbuf, topi);
    k_disp<<<(NPAIR + 1023) / 1024, 1024, 0, stream>>>(topi, cnt, plist);
    k_moe<<<NE * BQ, 512, 0, stream>>>(out, cnt, plist, w1c, b1, w2c, b2, gwbuf, ybuf);
    k_bnpart<<<BN_NBLK, 256, 0, stream>>>(out, ybuf, part);
    k_bnstats<<<1, 128, 0, stream>>>(part, bn_g, stats);
    k_bnapply<<<(N_NODES * (D / 4) + 255) / 256, 256, 0, stream>>>(ybuf, stats, bn_b, out);
}

// Round 13
// 521.466 us; speedup vs baseline: 1.2411x; 1.2042x over previous
//
#include <hip/hip_runtime.h>
#include <math.h>

#define N_NODES 50000
#define N_EDGES 500000
#define D 128
#define H 256
#define NE 64
#define TOPK 2
#define NPAIR (N_NODES * TOPK)
#define CAP 3126               // 2 * ceil(100000/64)
#define TILE_R 32
#define BQ 4                   // blocks per expert in k_moe
#define BN_NBLK 128
#define BN_ROWS ((N_NODES + BN_NBLK - 1) / BN_NBLK) // 391

typedef __attribute__((ext_vector_type(8))) short s16x8;
typedef __attribute__((ext_vector_type(4))) float f32x4;

__device__ __forceinline__ unsigned short f2bf(float f) {
    unsigned u = __float_as_uint(f);
    unsigned r = (u + 0x7fffu + ((u >> 16) & 1u)) >> 16;
    return (unsigned short)r;
}
__device__ __forceinline__ float bf2f(unsigned short u) {
    return __uint_as_float(((unsigned)u) << 16);
}

// Compensated f32: TwoProd (mul + fma residual) + branch-free TwoSum.
#define DOT2(s, c, xx, ww) {                      \
    float p_ = (xx) * (ww);                       \
    float e1_ = fmaf((xx), (ww), -p_);            \
    float t_ = (s) + p_;                          \
    float z_ = t_ - (s);                          \
    float e2_ = ((s) - (t_ - z_)) + (p_ - z_);    \
    (s) = t_;                                     \
    (c) += e1_ + e2_; }

#define TSUM(s, c, pp) {                          \
    float p_ = (pp);                              \
    float t_ = (s) + p_;                          \
    float z_ = t_ - (s);                          \
    float e2_ = ((s) - (t_ - z_)) + (p_ - z_);    \
    (s) = t_;                                     \
    (c) += e2_; }

// ---------------- degree count ----------------
__global__ void k_deg(const int* __restrict__ dst, int* __restrict__ deg) {
    int i = blockIdx.x * blockDim.x + threadIdx.x;
    if (i < N_EDGES) atomicAdd(&deg[dst[i]], 1);
}

__global__ void k_invsqrt(const int* __restrict__ deg, float* __restrict__ invs) {
    int i = blockIdx.x * blockDim.x + threadIdx.x;
    if (i < N_NODES) {
        double d = (double)deg[i];
        if (d < 1.0) d = 1.0;
        invs[i] = (float)(1.0 / sqrt(d));
    }
}

// ---------------- exclusive scan of deg -> rowptr ----------------
__global__ __launch_bounds__(1024) void k_scan(const int* __restrict__ deg,
                                               int* __restrict__ rowptr) {
    __shared__ int sh[1024];
    int t = threadIdx.x;
    const int chunk = (N_NODES + 1023) / 1024;   // 49
    int lo = t * chunk;
    int hi = min(lo + chunk, N_NODES);
    int s = 0;
    for (int i = lo; i < hi; i++) s += deg[i];
    sh[t] = s;
    __syncthreads();
    for (int off = 1; off < 1024; off <<= 1) {
        int v = (t >= off) ? sh[t - off] : 0;
        __syncthreads();
        sh[t] += v;
        __syncthreads();
    }
    int run = (t == 0) ? 0 : sh[t - 1];
    for (int i = lo; i < hi; i++) { rowptr[i] = run; run += deg[i]; }
    if (t == 1023) rowptr[N_NODES] = run;
}

// ---------------- scatter edges into CSR ----------------
__global__ void k_scatter(const int* __restrict__ src, const int* __restrict__ dst,
                          const int* __restrict__ rowptr, int* __restrict__ cursor,
                          int* __restrict__ csr) {
    int e = blockIdx.x * blockDim.x + threadIdx.x;
    if (e >= N_EDGES) return;
    int d = dst[e];
    int pos = atomicAdd(&cursor[d], 1);
    csr[rowptr[d] + pos] = src[e];
}

// ---------------- per-node gather (compensated f32, order-independent ~1e-12) ----
__global__ __launch_bounds__(256) void k_gather(const float* __restrict__ feats,
                                                const int* __restrict__ rowptr,
                                                const int* __restrict__ csr,
                                                const float* __restrict__ invs,
                                                float* __restrict__ agg) {
    int node = blockIdx.x * 4 + (threadIdx.x >> 6);
    if (node >= N_NODES) return;
    int lane = threadIdx.x & 63;
    int beg = rowptr[node], end = rowptr[node + 1];
    float wd = invs[node];
    float sx = 0.f, cx = 0.f, sy = 0.f, cy = 0.f;
    for (int i = beg; i < end; i++) {
        int s = csr[i];
        float nrm = invs[s] * wd;
        float2 f = ((const float2*)(feats + (size_t)s * D))[lane];
        DOT2(sx, cx, nrm, f.x);
        DOT2(sy, cy, nrm, f.y);
    }
    ((float2*)(agg + (size_t)node * D))[lane] = make_float2(sx + cx, sy + cy);
}

// ---------------- conv GEMM: new_feats = agg @ W_conv + b_conv (fp32, untouched) ----
__global__ __launch_bounds__(256) void k_conv(const float* __restrict__ agg,
                                              const float* __restrict__ W,
                                              const float* __restrict__ bias,
                                              float* __restrict__ out) {
    __shared__ float Wl[D * D];        // 64 KB
    __shared__ float xl[TILE_R * D];   // 16 KB
    int r0 = blockIdx.x * TILE_R;
    int rows = min(TILE_R, N_NODES - r0);
    for (int i = threadIdx.x; i < D * D / 4; i += 256)
        ((float4*)Wl)[i] = ((const float4*)W)[i];
    for (int i = threadIdx.x; i < rows * 32; i += 256) {
        int r = i >> 5, q = i & 31;
        ((float4*)(xl + r * D))[q] = ((const float4*)(agg + (size_t)(r0 + r) * D))[q];
    }
    __syncthreads();
    int c = threadIdx.x & 127;
    int half = threadIdx.x >> 7;
    float acc[16];
#pragma unroll
    for (int j = 0; j < 16; j++) acc[j] = 0.f;
    for (int k = 0; k < D; k++) {
        float w = Wl[k * D + c];
#pragma unroll
        for (int j = 0; j < 16; j++) acc[j] += xl[(half + j * 2) * D + k] * w;
    }
    float b = bias[c];
#pragma unroll
    for (int j = 0; j < 16; j++) {
        int r = half + j * 2;
        if (r < rows) out[(size_t)(r0 + r) * D + c] = acc[j] + b;
    }
}

// ---------------- gate v7 FAST: plain-f32 scores + gap test; ambiguous -> redo list --
// __launch_bounds__(256,4): cap VGPR at 128 (4 waves/EU) — without it the scheduler
// hoists the fully-unrolled k4-loop's LDS loads to 256 VGPR and spills 56 MB (r11).
__global__ __launch_bounds__(256, 4) void k_gate(const float* __restrict__ nf,
                                                 const float* __restrict__ gW,
                                                 const float* __restrict__ gb,
                                                 float* __restrict__ gwout,
                                                 int* __restrict__ topi,
                                                 int* __restrict__ rcnt,
                                                 int* __restrict__ redo) {
    __shared__ float Wl[D * NE];       // 32 KB, layout [k][e]
    __shared__ float xsh[16 * D];      // 8 KB
    for (int i = threadIdx.x; i < D * NE / 4; i += 256)
        ((float4*)Wl)[i] = ((const float4*)gW)[i];
    int t_base = blockIdx.x * 16;
    for (int i = threadIdx.x; i < 16 * 32; i += 256) {
        int r = i >> 5, q = i & 31;
        ((float4*)(xsh + r * D))[q] =
            ((const float4*)(nf + (size_t)(t_base + r) * D))[q];
    }
    __syncthreads();

    int wave = threadIdx.x >> 6;
    int lane = threadIdx.x & 63;      // lane = expert
    int t0 = t_base + wave * 4;
    const float* xw = xsh + wave * 4 * D;

    float a0 = 0.f, a1 = 0.f, a2 = 0.f, a3 = 0.f;
#pragma unroll 4
    for (int k4 = 0; k4 < D; k4 += 4) {
        float x0[4], x1[4], x2[4], x3[4];
        *(float4*)x0 = *(const float4*)(xw + k4);
        *(float4*)x1 = *(const float4*)(xw + D + k4);
        *(float4*)x2 = *(const float4*)(xw + 2 * D + k4);
        *(float4*)x3 = *(const float4*)(xw + 3 * D + k4);
#pragma unroll
        for (int u = 0; u < 4; u++) {
            float w = Wl[(k4 + u) * NE + lane];
            a0 = fmaf(x0[u], w, a0);
            a1 = fmaf(x1[u], w, a1);
            a2 = fmaf(x2[u], w, a2);
            a3 = fmaf(x3[u], w, a3);
        }
    }
    float gbf = gb[lane];
    float af[4] = {a0 + gbf, a1 + gbf, a2 + gbf, a3 + gbf};

    const float TAU = 2e-4f;   // >> plain-f32 dot error (~5e-6 realistic)

#pragma unroll
    for (int j = 0; j < 4; j++) {
        float sf = (j == 0) ? af[0] : (j == 1) ? af[1] : (j == 2) ? af[2] : af[3];
        int t = t0 + j;

        // top-1 (value, lower index wins ties)
        float v1 = sf; int i1 = lane;
#pragma unroll
        for (int off = 32; off; off >>= 1) {
            float ov = __shfl_xor(v1, off);
            int   oi = __shfl_xor(i1, off);
            if (ov > v1 || (ov == v1 && oi < i1)) { v1 = ov; i1 = oi; }
        }
        // top-2 excluding i1
        float v2 = (lane == i1) ? -INFINITY : sf; int i2 = lane;
#pragma unroll
        for (int off = 32; off; off >>= 1) {
            float ov = __shfl_xor(v2, off);
            int   oi = __shfl_xor(i2, off);
            if (ov > v2 || (ov == v2 && oi < i2)) { v2 = ov; i2 = oi; }
        }
        // top-3 value only (gap test)
        float v3 = (lane == i1 || lane == i2) ? -INFINITY : sf;
#pragma unroll
        for (int off = 32; off; off >>= 1)
            v3 = fmaxf(v3, __shfl_xor(v3, off));

        if (lane == 0) {
            float dd = v2 - v1;
            float e2 = expf(dd);
            float g0 = 1.0f / (1.0f + e2);
            gwout[2 * t] = g0;
            gwout[2 * t + 1] = e2 * g0;
            topi[2 * t] = i1;
            topi[2 * t + 1] = i2;
            if ((v1 - v2 <= TAU) || (v2 - v3 <= TAU)) {
                int slot = atomicAdd(rcnt, 1);
                redo[slot] = t;
            }
        }
    }
}

// ---------------- gate FIX: comp-f32 rescore of ambiguous tokens (rare) ------------
__global__ __launch_bounds__(256) void k_gfix(const float* __restrict__ nf,
                                              const float* __restrict__ gW,
                                              const float* __restrict__ gb,
                                              const int* __restrict__ rcnt,
                                              const int* __restrict__ redo,
                                              float* __restrict__ gwout,
                                              int* __restrict__ topi) {
    int nredo = *rcnt;
    int lane = threadIdx.x & 63;
    int widx = blockIdx.x * 4 + (threadIdx.x >> 6);
    float gbf = gb[lane];
    for (int i = widx; i < nredo; i += gridDim.x * 4) {
        int t = redo[i];
        const float* xr = nf + (size_t)t * D;
        float s = 0.f, c = 0.f;
        for (int k = 0; k < D; k++)
            DOT2(s, c, xr[k], gW[k * NE + lane]);
        TSUM(s, c, gbf);
        float vv = s + c, rr = (s - vv) + c;

        float a1v = vv, a1r = rr; int i1 = lane;
#pragma unroll
        for (int off = 32; off; off >>= 1) {
            float ov = __shfl_xor(a1v, off);
            float orr = __shfl_xor(a1r, off);
            int   oi = __shfl_xor(i1, off);
            bool gt = (ov > a1v) || (ov == a1v && (orr > a1r || (orr == a1r && oi < i1)));
            if (gt) { a1v = ov; a1r = orr; i1 = oi; }
        }
        bool ex = (lane == i1);
        float a2v = ex ? -INFINITY : vv;
        float a2r = ex ? 0.f : rr;
        int i2 = lane;
#pragma unroll
        for (int off = 32; off; off >>= 1) {
            float ov = __shfl_xor(a2v, off);
            float orr = __shfl_xor(a2r, off);
            int   oi = __shfl_xor(i2, off);
            bool gt = (ov > a2v) || (ov == a2v && (orr > a2r || (orr == a2r && oi < i2)));
            if (gt) { a2v = ov; a2r = orr; i2 = oi; }
        }

        if (lane == 0) {
            float dd = (a2v - a1v) + (a2r - a1r);
            float e2 = expf(dd);
            float g0 = 1.0f / (1.0f + e2);
            gwout[2 * t] = g0;
            gwout[2 * t + 1] = e2 * g0;
            topi[2 * t] = i1;
            topi[2 * t + 1] = i2;
        }
    }
}

// ---------------- dispatch: parallel two-level counting scatter ----------------
__global__ __launch_bounds__(1024) void k_disp(const int* __restrict__ topi,
                                               int* __restrict__ cnt,
                                               int* __restrict__ plist) {
    __shared__ int lcnt[NE];
    __shared__ int lbase[NE];
    int tid = threadIdx.x;
    if (tid < NE) lcnt[tid] = 0;
    __syncthreads();
    int p = blockIdx.x * 1024 + tid;
    int e = 0, lr = 0;
    bool act = (p < NPAIR);
    if (act) {
        e = topi[p];
        lr = atomicAdd(&lcnt[e], 1);
    }
    __syncthreads();
    if (tid < NE) {
        int n = lcnt[tid];
        lbase[tid] = n ? atomicAdd(&cnt[tid], n) : 0;
    }
    __syncthreads();
    if (act) {
        int slot = lbase[e] + lr;
        if (slot < CAP) plist[e * CAP + slot] = p;
    }
}

// ---------------- weight convert: f32 -> bf16 fragments, PRE-SWIZZLED --------------
__global__ __launch_bounds__(256) void k_wconv(const float* __restrict__ W1,
                                               const float* __restrict__ W2,
                                               unsigned short* __restrict__ w1c,
                                               unsigned short* __restrict__ w2c) {
    int gid = blockIdx.x * 256 + threadIdx.x;
    const int NW1 = NE * 4 * 256 * 4;            // 262144
    if (gid < NW1) {
        int lhi = gid & 3, h = (gid >> 2) & 255, ks = (gid >> 10) & 3, e = gid >> 12;
        int u = gid & 4095;                       // (ks*256+h)*4+lhi
        int d0 = ks * 32 + lhi * 8;
        unsigned short v[8] __attribute__((aligned(16)));
#pragma unroll
        for (int j = 0; j < 8; j++)
            v[j] = f2bf(W1[((size_t)e * D + d0 + j) * H + h]);
        *(int4*)((char*)w1c + (size_t)e * 65536 + ((u * 16) ^ ((h & 7) << 4))) = *(int4*)v;
    } else {
        int g = gid - NW1;
        int lhi = g & 3, d = (g >> 2) & 127, ks = (g >> 9) & 7, e = g >> 12;
        int u = g & 4095;                         // (ks*128+d)*4+lhi
        int h0 = ks * 32 + lhi * 8;
        unsigned short v[8] __attribute__((aligned(16)));
#pragma unroll
        for (int j = 0; j < 8; j++)
            v[j] = f2bf(W2[((size_t)e * H + h0 + j) * D + d]);
        *(int4*)((char*)w2c + (size_t)e * 65536 + ((u * 16) ^ ((d & 7) << 4))) = *(int4*)v;
    }
}

// ---------------- MoE FFN v4: 8 waves, W1+W2 resident in LDS (copied, pre-swizzled) --
__global__ __launch_bounds__(512, 1) void k_moe(const float* __restrict__ nf,
                                                const int* __restrict__ cnt,
                                                const int* __restrict__ plist,
                                                const unsigned short* __restrict__ w1c,
                                                const float* __restrict__ b1,
                                                const unsigned short* __restrict__ w2c,
                                                const float* __restrict__ b2,
                                                const float* __restrict__ gwbuf,
                                                unsigned short* __restrict__ ybuf) {
    __shared__ __align__(16) char smem[155648];
    const int W1L = 0, W2L = 65536, XA = 131072, HL = 139264;
    int e = blockIdx.x >> 2;
    int q = blockIdx.x & 3;
    int n = min(cnt[e], CAP);
    int ntile = (n + TILE_R - 1) / TILE_R;
    if (q >= ntile) return;
    int tid = threadIdx.x;

    {
        const int4* s1 = (const int4*)((const char*)w1c + (size_t)e * 65536);
        const int4* s2 = (const int4*)((const char*)w2c + (size_t)e * 65536);
#pragma unroll
        for (int i = 0; i < 8; i++) {
            ((int4*)(smem + W1L))[tid + i * 512] = s1[tid + i * 512];
            ((int4*)(smem + W2L))[tid + i * 512] = s2[tid + i * 512];
        }
    }

    int wv = tid >> 6, lane = tid & 63;
    int lhi = lane >> 4, llo = lane & 15;
    f32x4 zero = {0.f, 0.f, 0.f, 0.f};

    for (int rt = q; rt < ntile; rt += BQ) {
        int r0 = rt * TILE_R;
        int rows = min(TILE_R, n - r0);
        __syncthreads();

        {
            int r = tid >> 4, s = tid & 15;
            float vals[8];
            if (r < rows) {
                int p = plist[e * CAP + r0 + r];
                const float4* xr = (const float4*)(nf + (size_t)(p >> 1) * D + s * 8);
                *(float4*)(vals + 0) = xr[0];
                *(float4*)(vals + 4) = xr[1];
            } else {
#pragma unroll
                for (int k = 0; k < 8; k++) vals[k] = 0.f;
            }
            unsigned short hb[8] __attribute__((aligned(16)));
#pragma unroll
            for (int k = 0; k < 8; k++) hb[k] = f2bf(vals[k]);
            *(int4*)(smem + XA + r * 256 + ((s * 16) ^ ((r & 7) << 4))) = *(int4*)hb;
        }
        __syncthreads();

        f32x4 acc1[2][2];
#pragma unroll
        for (int mt = 0; mt < 2; mt++)
#pragma unroll
            for (int nt = 0; nt < 2; nt++) acc1[mt][nt] = zero;
#pragma unroll
        for (int ks = 0; ks < 4; ks++) {
            int kb = ks * 64 + lhi * 16;
            s16x8 a0 = *(const s16x8*)(smem + XA + llo * 256        + (kb ^ ((llo & 7) << 4)));
            s16x8 a1 = *(const s16x8*)(smem + XA + (llo + 16) * 256 + (kb ^ ((llo & 7) << 4)));
#pragma unroll
            for (int nt = 0; nt < 2; nt++) {
                int h = wv * 32 + nt * 16 + llo;
                int u = (ks * 256 + h) * 4 + lhi;
                s16x8 b = *(const s16x8*)(smem + W1L + ((u * 16) ^ ((h & 7) << 4)));
                acc1[0][nt] = __builtin_amdgcn_mfma_f32_16x16x32_bf16(a0, b, acc1[0][nt], 0, 0, 0);
                acc1[1][nt] = __builtin_amdgcn_mfma_f32_16x16x32_bf16(a1, b, acc1[1][nt], 0, 0, 0);
            }
        }

#pragma unroll
        for (int mt = 0; mt < 2; mt++)
#pragma unroll
            for (int nt = 0; nt < 2; nt++)
#pragma unroll
                for (int r = 0; r < 4; r++) {
                    int m = mt * 16 + lhi * 4 + r;
                    int hc = wv * 32 + nt * 16 + llo;
                    float hv = acc1[mt][nt][r] + b1[e * H + hc];
                    float g = 0.5f * hv * (1.0f + erff(hv * 0.70710678118654752f));
                    *(unsigned short*)(smem + HL + m * 512 + ((hc * 2) ^ ((m & 7) << 4))) = f2bf(g);
                }
        __syncthreads();

        f32x4 acc2[2];
        acc2[0] = zero; acc2[1] = zero;
#pragma unroll
        for (int ks = 0; ks < 8; ks++) {
            int kb = ks * 64 + lhi * 16;
            s16x8 a0 = *(const s16x8*)(smem + HL + llo * 512        + (kb ^ ((llo & 7) << 4)));
            s16x8 a1 = *(const s16x8*)(smem + HL + (llo + 16) * 512 + (kb ^ ((llo & 7) << 4)));
            int d = wv * 16 + llo;
            int u = (ks * 128 + d) * 4 + lhi;
            s16x8 b = *(const s16x8*)(smem + W2L + ((u * 16) ^ ((d & 7) << 4)));
            acc2[0] = __builtin_amdgcn_mfma_f32_16x16x32_bf16(a0, b, acc2[0], 0, 0, 0);
            acc2[1] = __builtin_amdgcn_mfma_f32_16x16x32_bf16(a1, b, acc2[1], 0, 0, 0);
        }

        int d = wv * 16 + llo;
        float bb = b2[e * D + d];
#pragma unroll
        for (int mt = 0; mt < 2; mt++)
#pragma unroll
            for (int r = 0; r < 4; r++) {
                int m = mt * 16 + lhi * 4 + r;
                if (m < rows) {
                    int p = plist[e * CAP + r0 + m];
                    ybuf[(size_t)p * D + d] = f2bf(gwbuf[p] * (acc2[mt][r] + bb));
                }
            }
    }
}

// ---------------- BatchNorm ----------------
__global__ __launch_bounds__(256) void k_bnpart(const float* __restrict__ nf,
                                                const unsigned short* __restrict__ ybuf,
                                                double* __restrict__ part) {
    int blk = blockIdx.x;
    int col = threadIdx.x & 127;
    int half = threadIdx.x >> 7;
    int r0 = blk * BN_ROWS;
    int r1 = min(r0 + BN_ROWS, N_NODES);
    double s = 0.0, ss = 0.0;
    for (int r = r0 + half; r < r1; r += 2) {
        float v32 = nf[(size_t)r * D + col]
                  + bf2f(ybuf[(size_t)(2 * r) * D + col])
                  + bf2f(ybuf[(size_t)(2 * r + 1) * D + col]);
        double v = (double)v32;
        s += v; ss += v * v;
    }
    __shared__ double sh[2][256];
    sh[0][threadIdx.x] = s; sh[1][threadIdx.x] = ss;
    __syncthreads();
    if (threadIdx.x < 128) {
        part[(size_t)blk * 256 + col]       = sh[0][col] + sh[0][col + 128];
        part[(size_t)blk * 256 + 128 + col] = sh[1][col] + sh[1][col + 128];
    }
}

__global__ void k_bnstats(const double* __restrict__ part,
                          const float* __restrict__ gamma,
                          float* __restrict__ stats) {
    int col = threadIdx.x;   // 128 threads
    double s = 0.0, ss = 0.0;
    for (int b = 0; b < BN_NBLK; b++) {
        s  += part[(size_t)b * 256 + col];
        ss += part[(size_t)b * 256 + 128 + col];
    }
    double mean = s / (double)N_NODES;
    double var = ss / (double)N_NODES - mean * mean;
    stats[col] = (float)mean;
    stats[128 + col] = gamma[col] * (float)(1.0 / sqrt(var + 1e-5));
}

__global__ __launch_bounds__(256) void k_bnapply(const unsigned short* __restrict__ ybuf,
                                                 const float* __restrict__ stats,
                                                 const float* __restrict__ beta,
                                                 float* __restrict__ out) {
    int i = blockIdx.x * blockDim.x + threadIdx.x;   // float4 index
    if (i >= N_NODES * (D / 4)) return;
    int t = i >> 5;
    int q = i & 31;
    int c0 = q * 4;
    float4 v  = ((float4*)out)[i];
    short4 y0v = *(const short4*)(ybuf + (size_t)(2 * t) * D + c0);
    short4 y1v = *(const short4*)(ybuf + (size_t)(2 * t + 1) * D + c0);
    float4 r;
    r.x = (v.x + bf2f((unsigned short)y0v.x) + bf2f((unsigned short)y1v.x) - stats[c0 + 0]) * stats[128 + c0 + 0] + beta[c0 + 0];
    r.y = (v.y + bf2f((unsigned short)y0v.y) + bf2f((unsigned short)y1v.y) - stats[c0 + 1]) * stats[128 + c0 + 1] + beta[c0 + 1];
    r.z = (v.z + bf2f((unsigned short)y0v.z) + bf2f((unsigned short)y1v.z) - stats[c0 + 2]) * stats[128 + c0 + 2] + beta[c0 + 2];
    r.w = (v.w + bf2f((unsigned short)y0v.w) + bf2f((unsigned short)y1v.w) - stats[c0 + 3]) * stats[128 + c0 + 3] + beta[c0 + 3];
    ((float4*)out)[i] = r;
}

// ---------------- launch ----------------
extern "C" void kernel_launch(void* const* d_in, const int* in_sizes, int n_in,
                              void* d_out, int out_size, void* d_ws, size_t ws_size,
                              hipStream_t stream) {
    const float* feats   = (const float*)d_in[0];
    const int*   esrc    = (const int*)d_in[1];
    const int*   edst    = (const int*)d_in[2];
    const float* W_conv  = (const float*)d_in[3];
    const float* b_conv  = (const float*)d_in[4];
    const float* gate_W  = (const float*)d_in[5];
    const float* gate_b  = (const float*)d_in[6];
    const float* W1      = (const float*)d_in[7];
    const float* b1      = (const float*)d_in[8];
    const float* W2      = (const float*)d_in[9];
    const float* b2      = (const float*)d_in[10];
    const float* bn_g    = (const float*)d_in[11];
    const float* bn_b    = (const float*)d_in[12];
    float* out = (float*)d_out;   // doubles as new_feats storage

    char* ws = (char*)d_ws;
    size_t off = 0;
    auto rup = [](size_t x) { return (x + 255) & ~(size_t)255; };
    int*    deg    = (int*)   (ws + off); off += rup((size_t)N_NODES * 4);
    int*    cursor = (int*)   (ws + off); off += rup((size_t)N_NODES * 4);
    int*    cnt    = (int*)   (ws + off); off += 256;
    int*    rcnt   = (int*)   (ws + off); off += 256;
    size_t zero_bytes = off;                 // deg + cursor + cnt + rcnt (~400 KB)
    float*  invs   = (float*) (ws + off); off += rup((size_t)N_NODES * 4);
    int*    rowptr = (int*)   (ws + off); off += rup((size_t)(N_NODES + 1) * 4);
    int*    csr    = (int*)   (ws + off); off += rup((size_t)N_EDGES * 4);
    float*  gwbuf  = (float*) (ws + off); off += rup((size_t)NPAIR * 4);
    int*    topi   = (int*)   (ws + off); off += rup((size_t)NPAIR * 4);
    int*    redo   = (int*)   (ws + off); off += rup((size_t)N_NODES * 4);
    int*    plist  = (int*)   (ws + off); off += rup((size_t)NE * CAP * 4);
    double* part   = (double*)(ws + off); off += rup((size_t)BN_NBLK * 256 * 8);
    float*  stats  = (float*) (ws + off); off += 1024;
    unsigned short* w1c = (unsigned short*)(ws + off); off += rup((size_t)NE * D * H * 2); // 4 MB
    unsigned short* w2c = (unsigned short*)(ws + off); off += rup((size_t)NE * D * H * 2); // 4 MB
    unsigned short* ybuf = (unsigned short*)(ws + off); off += rup((size_t)NPAIR * D * 2); // 25.6 MB
    float*  agg    = (float*)ybuf;   // lifetime-disjoint alias (agg dead before k_moe writes ybuf)
    (void)ws_size; (void)in_sizes; (void)n_in; (void)out_size;

    hipMemsetAsync(d_ws, 0, zero_bytes, stream);

    k_wconv<<<2 * NE * 4 * 256 * 4 / 256, 256, 0, stream>>>(W1, W2, w1c, w2c);
    k_deg<<<(N_EDGES + 255) / 256, 256, 0, stream>>>(edst, deg);
    k_invsqrt<<<(N_NODES + 255) / 256, 256, 0, stream>>>(deg, invs);
    k_scan<<<1, 1024, 0, stream>>>(deg, rowptr);
    k_scatter<<<(N_EDGES + 255) / 256, 256, 0, stream>>>(esrc, edst, rowptr, cursor, csr);
    k_gather<<<(N_NODES + 3) / 4, 256, 0, stream>>>(feats, rowptr, csr, invs, agg);
    k_conv<<<(N_NODES + TILE_R - 1) / TILE_R, 256, 0, stream>>>(agg, W_conv, b_conv, out);
    k_gate<<<N_NODES / 16, 256, 0, stream>>>(out, gate_W, gate_b, gwbuf, topi, rcnt, redo);
    k_gfix<<<128, 256, 0, stream>>>(out, gate_W, gate_b, rcnt, redo, gwbuf, topi);
    k_disp<<<(NPAIR + 1023) / 1024, 1024, 0, stream>>>(topi, cnt, plist);
    k_moe<<<NE * BQ, 512, 0, stream>>>(out, cnt, plist, w1c, b1, w2c, b2, gwbuf, ybuf);
    k_bnpart<<<BN_NBLK, 256, 0, stream>>>(out, ybuf, part);
    k_bnstats<<<1, 128, 0, stream>>>(part, bn_g, stats);
    k_bnapply<<<(N_NODES * (D / 4) + 255) / 256, 256, 0, stream>>>(ybuf, stats, bn_b, out);
}

// Round 14
// 510.786 us; speedup vs baseline: 1.2670x; 1.0209x over previous
//
#include <hip/hip_runtime.h>
#include <math.h>

#define N_NODES 50000
#define N_EDGES 500000
#define D 128
#define H 256
#define NE 64
#define TOPK 2
#define NPAIR (N_NODES * TOPK)
#define CAP 3126               // 2 * ceil(100000/64)
#define TILE_R 32
#define BQ 4                   // blocks per expert in k_moe
#define BN_NBLK 128
#define BN_ROWS ((N_NODES + BN_NBLK - 1) / BN_NBLK) // 391

typedef __attribute__((ext_vector_type(8))) short s16x8;
typedef __attribute__((ext_vector_type(4))) float f32x4;

__device__ __forceinline__ unsigned short f2bf(float f) {
    unsigned u = __float_as_uint(f);
    unsigned r = (u + 0x7fffu + ((u >> 16) & 1u)) >> 16;
    return (unsigned short)r;
}
__device__ __forceinline__ float bf2f(unsigned short u) {
    return __uint_as_float(((unsigned)u) << 16);
}

// Compensated f32: TwoProd (mul + fma residual) + branch-free TwoSum.
#define DOT2(s, c, xx, ww) {                      \
    float p_ = (xx) * (ww);                       \
    float e1_ = fmaf((xx), (ww), -p_);            \
    float t_ = (s) + p_;                          \
    float z_ = t_ - (s);                          \
    float e2_ = ((s) - (t_ - z_)) + (p_ - z_);    \
    (s) = t_;                                     \
    (c) += e1_ + e2_; }

#define TSUM(s, c, pp) {                          \
    float p_ = (pp);                              \
    float t_ = (s) + p_;                          \
    float z_ = t_ - (s);                          \
    float e2_ = ((s) - (t_ - z_)) + (p_ - z_);    \
    (s) = t_;                                     \
    (c) += e2_; }

// ---------------- degree count ----------------
__global__ void k_deg(const int* __restrict__ dst, int* __restrict__ deg) {
    int i = blockIdx.x * blockDim.x + threadIdx.x;
    if (i < N_EDGES) atomicAdd(&deg[dst[i]], 1);
}

__global__ void k_invsqrt(const int* __restrict__ deg, float* __restrict__ invs) {
    int i = blockIdx.x * blockDim.x + threadIdx.x;
    if (i < N_NODES) {
        double d = (double)deg[i];
        if (d < 1.0) d = 1.0;
        invs[i] = (float)(1.0 / sqrt(d));
    }
}

// ---------------- exclusive scan of deg -> rowptr ----------------
__global__ __launch_bounds__(1024) void k_scan(const int* __restrict__ deg,
                                               int* __restrict__ rowptr) {
    __shared__ int sh[1024];
    int t = threadIdx.x;
    const int chunk = (N_NODES + 1023) / 1024;   // 49
    int lo = t * chunk;
    int hi = min(lo + chunk, N_NODES);
    int s = 0;
    for (int i = lo; i < hi; i++) s += deg[i];
    sh[t] = s;
    __syncthreads();
    for (int off = 1; off < 1024; off <<= 1) {
        int v = (t >= off) ? sh[t - off] : 0;
        __syncthreads();
        sh[t] += v;
        __syncthreads();
    }
    int run = (t == 0) ? 0 : sh[t - 1];
    for (int i = lo; i < hi; i++) { rowptr[i] = run; run += deg[i]; }
    if (t == 1023) rowptr[N_NODES] = run;
}

// ---------------- scatter edges into CSR ----------------
__global__ void k_scatter(const int* __restrict__ src, const int* __restrict__ dst,
                          const int* __restrict__ rowptr, int* __restrict__ cursor,
                          int* __restrict__ csr) {
    int e = blockIdx.x * blockDim.x + threadIdx.x;
    if (e >= N_EDGES) return;
    int d = dst[e];
    int pos = atomicAdd(&cursor[d], 1);
    csr[rowptr[d] + pos] = src[e];
}

// ---------------- per-node gather (compensated f32, order-independent ~1e-12) ----
__global__ __launch_bounds__(256) void k_gather(const float* __restrict__ feats,
                                                const int* __restrict__ rowptr,
                                                const int* __restrict__ csr,
                                                const float* __restrict__ invs,
                                                float* __restrict__ agg) {
    int node = blockIdx.x * 4 + (threadIdx.x >> 6);
    if (node >= N_NODES) return;
    int lane = threadIdx.x & 63;
    int beg = rowptr[node], end = rowptr[node + 1];
    float wd = invs[node];
    float sx = 0.f, cx = 0.f, sy = 0.f, cy = 0.f;
    for (int i = beg; i < end; i++) {
        int s = csr[i];
        float nrm = invs[s] * wd;
        float2 f = ((const float2*)(feats + (size_t)s * D))[lane];
        DOT2(sx, cx, nrm, f.x);
        DOT2(sy, cy, nrm, f.y);
    }
    ((float2*)(agg + (size_t)node * D))[lane] = make_float2(sx + cx, sy + cy);
}

// ---------------- conv GEMM: new_feats = agg @ W_conv + b_conv (fp32, untouched) ----
__global__ __launch_bounds__(256) void k_conv(const float* __restrict__ agg,
                                              const float* __restrict__ W,
                                              const float* __restrict__ bias,
                                              float* __restrict__ out) {
    __shared__ float Wl[D * D];        // 64 KB
    __shared__ float xl[TILE_R * D];   // 16 KB
    int r0 = blockIdx.x * TILE_R;
    int rows = min(TILE_R, N_NODES - r0);
    for (int i = threadIdx.x; i < D * D / 4; i += 256)
        ((float4*)Wl)[i] = ((const float4*)W)[i];
    for (int i = threadIdx.x; i < rows * 32; i += 256) {
        int r = i >> 5, q = i & 31;
        ((float4*)(xl + r * D))[q] = ((const float4*)(agg + (size_t)(r0 + r) * D))[q];
    }
    __syncthreads();
    int c = threadIdx.x & 127;
    int half = threadIdx.x >> 7;
    float acc[16];
#pragma unroll
    for (int j = 0; j < 16; j++) acc[j] = 0.f;
    for (int k = 0; k < D; k++) {
        float w = Wl[k * D + c];
#pragma unroll
        for (int j = 0; j < 16; j++) acc[j] += xl[(half + j * 2) * D + k] * w;
    }
    float b = bias[c];
#pragma unroll
    for (int j = 0; j < 16; j++) {
        int r = half + j * 2;
        if (r < rows) out[(size_t)(r0 + r) * D + c] = acc[j] + b;
    }
}

// ---------------- gate v7 FAST: plain-f32 scores + gap test; ambiguous -> redo list --
// __launch_bounds__(256,4): cap VGPR at 128 (4 waves/EU) — without it the scheduler
// hoists the fully-unrolled k4-loop's LDS loads to 256 VGPR and spills 56 MB (r11).
__global__ __launch_bounds__(256, 4) void k_gate(const float* __restrict__ nf,
                                                 const float* __restrict__ gW,
                                                 const float* __restrict__ gb,
                                                 float* __restrict__ gwout,
                                                 int* __restrict__ topi,
                                                 int* __restrict__ rcnt,
                                                 int* __restrict__ redo) {
    __shared__ float Wl[D * NE];       // 32 KB, layout [k][e]
    __shared__ float xsh[16 * D];      // 8 KB
    for (int i = threadIdx.x; i < D * NE / 4; i += 256)
        ((float4*)Wl)[i] = ((const float4*)gW)[i];
    int t_base = blockIdx.x * 16;
    for (int i = threadIdx.x; i < 16 * 32; i += 256) {
        int r = i >> 5, q = i & 31;
        ((float4*)(xsh + r * D))[q] =
            ((const float4*)(nf + (size_t)(t_base + r) * D))[q];
    }
    __syncthreads();

    int wave = threadIdx.x >> 6;
    int lane = threadIdx.x & 63;      // lane = expert
    int t0 = t_base + wave * 4;
    const float* xw = xsh + wave * 4 * D;

    float a0 = 0.f, a1 = 0.f, a2 = 0.f, a3 = 0.f;
#pragma unroll 4
    for (int k4 = 0; k4 < D; k4 += 4) {
        float x0[4], x1[4], x2[4], x3[4];
        *(float4*)x0 = *(const float4*)(xw + k4);
        *(float4*)x1 = *(const float4*)(xw + D + k4);
        *(float4*)x2 = *(const float4*)(xw + 2 * D + k4);
        *(float4*)x3 = *(const float4*)(xw + 3 * D + k4);
#pragma unroll
        for (int u = 0; u < 4; u++) {
            float w = Wl[(k4 + u) * NE + lane];
            a0 = fmaf(x0[u], w, a0);
            a1 = fmaf(x1[u], w, a1);
            a2 = fmaf(x2[u], w, a2);
            a3 = fmaf(x3[u], w, a3);
        }
    }
    float gbf = gb[lane];
    float af[4] = {a0 + gbf, a1 + gbf, a2 + gbf, a3 + gbf};

    const float TAU = 2e-4f;   // >> plain-f32 dot error (~5e-6 realistic)

#pragma unroll
    for (int j = 0; j < 4; j++) {
        float sf = (j == 0) ? af[0] : (j == 1) ? af[1] : (j == 2) ? af[2] : af[3];
        int t = t0 + j;

        // top-1 (value, lower index wins ties)
        float v1 = sf; int i1 = lane;
#pragma unroll
        for (int off = 32; off; off >>= 1) {
            float ov = __shfl_xor(v1, off);
            int   oi = __shfl_xor(i1, off);
            if (ov > v1 || (ov == v1 && oi < i1)) { v1 = ov; i1 = oi; }
        }
        // top-2 excluding i1
        float v2 = (lane == i1) ? -INFINITY : sf; int i2 = lane;
#pragma unroll
        for (int off = 32; off; off >>= 1) {
            float ov = __shfl_xor(v2, off);
            int   oi = __shfl_xor(i2, off);
            if (ov > v2 || (ov == v2 && oi < i2)) { v2 = ov; i2 = oi; }
        }
        // top-3 value only (gap test)
        float v3 = (lane == i1 || lane == i2) ? -INFINITY : sf;
#pragma unroll
        for (int off = 32; off; off >>= 1)
            v3 = fmaxf(v3, __shfl_xor(v3, off));

        if (lane == 0) {
            float dd = v2 - v1;
            float e2 = expf(dd);
            float g0 = 1.0f / (1.0f + e2);
            gwout[2 * t] = g0;
            gwout[2 * t + 1] = e2 * g0;
            topi[2 * t] = i1;
            topi[2 * t + 1] = i2;
            if ((v1 - v2 <= TAU) || (v2 - v3 <= TAU)) {
                int slot = atomicAdd(rcnt, 1);
                redo[slot] = t;
            }
        }
    }
}

// ---------------- gate FIX: comp-f32 rescore of ambiguous tokens (rare) ------------
__global__ __launch_bounds__(256) void k_gfix(const float* __restrict__ nf,
                                              const float* __restrict__ gW,
                                              const float* __restrict__ gb,
                                              const int* __restrict__ rcnt,
                                              const int* __restrict__ redo,
                                              float* __restrict__ gwout,
                                              int* __restrict__ topi) {
    int nredo = *rcnt;
    int lane = threadIdx.x & 63;
    int widx = blockIdx.x * 4 + (threadIdx.x >> 6);
    float gbf = gb[lane];
    for (int i = widx; i < nredo; i += gridDim.x * 4) {
        int t = redo[i];
        const float* xr = nf + (size_t)t * D;
        float s = 0.f, c = 0.f;
        for (int k = 0; k < D; k++)
            DOT2(s, c, xr[k], gW[k * NE + lane]);
        TSUM(s, c, gbf);
        float vv = s + c, rr = (s - vv) + c;

        float a1v = vv, a1r = rr; int i1 = lane;
#pragma unroll
        for (int off = 32; off; off >>= 1) {
            float ov = __shfl_xor(a1v, off);
            float orr = __shfl_xor(a1r, off);
            int   oi = __shfl_xor(i1, off);
            bool gt = (ov > a1v) || (ov == a1v && (orr > a1r || (orr == a1r && oi < i1)));
            if (gt) { a1v = ov; a1r = orr; i1 = oi; }
        }
        bool ex = (lane == i1);
        float a2v = ex ? -INFINITY : vv;
        float a2r = ex ? 0.f : rr;
        int i2 = lane;
#pragma unroll
        for (int off = 32; off; off >>= 1) {
            float ov = __shfl_xor(a2v, off);
            float orr = __shfl_xor(a2r, off);
            int   oi = __shfl_xor(i2, off);
            bool gt = (ov > a2v) || (ov == a2v && (orr > a2r || (orr == a2r && oi < i2)));
            if (gt) { a2v = ov; a2r = orr; i2 = oi; }
        }

        if (lane == 0) {
            float dd = (a2v - a1v) + (a2r - a1r);
            float e2 = expf(dd);
            float g0 = 1.0f / (1.0f + e2);
            gwout[2 * t] = g0;
            gwout[2 * t + 1] = e2 * g0;
            topi[2 * t] = i1;
            topi[2 * t + 1] = i2;
        }
    }
}

// ---------------- dispatch: parallel two-level counting scatter ----------------
__global__ __launch_bounds__(1024) void k_disp(const int* __restrict__ topi,
                                               int* __restrict__ cnt,
                                               int* __restrict__ plist) {
    __shared__ int lcnt[NE];
    __shared__ int lbase[NE];
    int tid = threadIdx.x;
    if (tid < NE) lcnt[tid] = 0;
    __syncthreads();
    int p = blockIdx.x * 1024 + tid;
    int e = 0, lr = 0;
    bool act = (p < NPAIR);
    if (act) {
        e = topi[p];
        lr = atomicAdd(&lcnt[e], 1);
    }
    __syncthreads();
    if (tid < NE) {
        int n = lcnt[tid];
        lbase[tid] = n ? atomicAdd(&cnt[tid], n) : 0;
    }
    __syncthreads();
    if (act) {
        int slot = lbase[e] + lr;
        if (slot < CAP) plist[e * CAP + slot] = p;
    }
}

// ---------------- weight convert: f32 -> bf16 fragments, PRE-SWIZZLED --------------
__global__ __launch_bounds__(256) void k_wconv(const float* __restrict__ W1,
                                               const float* __restrict__ W2,
                                               unsigned short* __restrict__ w1c,
                                               unsigned short* __restrict__ w2c) {
    int gid = blockIdx.x * 256 + threadIdx.x;
    const int NW1 = NE * 4 * 256 * 4;            // 262144
    if (gid < NW1) {
        int lhi = gid & 3, h = (gid >> 2) & 255, ks = (gid >> 10) & 3, e = gid >> 12;
        int u = gid & 4095;                       // (ks*256+h)*4+lhi
        int d0 = ks * 32 + lhi * 8;
        unsigned short v[8] __attribute__((aligned(16)));
#pragma unroll
        for (int j = 0; j < 8; j++)
            v[j] = f2bf(W1[((size_t)e * D + d0 + j) * H + h]);
        *(int4*)((char*)w1c + (size_t)e * 65536 + ((u * 16) ^ ((h & 7) << 4))) = *(int4*)v;
    } else {
        int g = gid - NW1;
        int lhi = g & 3, d = (g >> 2) & 127, ks = (g >> 9) & 7, e = g >> 12;
        int u = g & 4095;                         // (ks*128+d)*4+lhi
        int h0 = ks * 32 + lhi * 8;
        unsigned short v[8] __attribute__((aligned(16)));
#pragma unroll
        for (int j = 0; j < 8; j++)
            v[j] = f2bf(W2[((size_t)e * H + h0 + j) * D + d]);
        *(int4*)((char*)w2c + (size_t)e * 65536 + ((u * 16) ^ ((d & 7) << 4))) = *(int4*)v;
    }
}

// ---------------- MoE FFN v5: XCD-co-located blocks + async x-row prefetch ---------
// e = blockIdx&63: expert e's 4 blocks are {e, e+64, e+128, e+192} ≡ e (mod 8) ->
// same XCD -> W staged from L2 by 3 of 4 blocks (was 32 MB HBM with e=blk>>2, r13).
// Per-tile: loads for tile t+BQ issued right after XA-ready barrier, consumed next
// iteration -> HBM latency hides under GEMM1+gelu+GEMM2 (T14 async-STAGE).
__global__ __launch_bounds__(512, 1) void k_moe(const float* __restrict__ nf,
                                                const int* __restrict__ cnt,
                                                const int* __restrict__ plist,
                                                const unsigned short* __restrict__ w1c,
                                                const float* __restrict__ b1,
                                                const unsigned short* __restrict__ w2c,
                                                const float* __restrict__ b2,
                                                const float* __restrict__ gwbuf,
                                                unsigned short* __restrict__ ybuf) {
    __shared__ __align__(16) char smem[155648];
    const int W1L = 0, W2L = 65536, XA = 131072, HL = 139264;
    int e = blockIdx.x & 63;
    int q = blockIdx.x >> 6;
    int n = min(cnt[e], CAP);
    int ntile = (n + TILE_R - 1) / TILE_R;
    if (q >= ntile) return;
    int tid = threadIdx.x;

    // ---- stage W1+W2 fragments: pure 16B copy (coalesced read, conflict-free write) --
    {
        const int4* s1 = (const int4*)((const char*)w1c + (size_t)e * 65536);
        const int4* s2 = (const int4*)((const char*)w2c + (size_t)e * 65536);
#pragma unroll
        for (int i = 0; i < 8; i++) {
            ((int4*)(smem + W1L))[tid + i * 512] = s1[tid + i * 512];
            ((int4*)(smem + W2L))[tid + i * 512] = s2[tid + i * 512];
        }
    }

    int wv = tid >> 6, lane = tid & 63;
    int lhi = lane >> 4, llo = lane & 15;
    int sr = tid >> 4, ss = tid & 15;   // staging role: row, 16B-chunk
    f32x4 zero = {0.f, 0.f, 0.f, 0.f};

    float vals[8];
    auto loadt = [&](int rt2, float* v) {
        bool ok = false;
        if (rt2 < ntile) {
            int rows2 = min(TILE_R, n - rt2 * TILE_R);
            if (sr < rows2) {
                int p = plist[e * CAP + rt2 * TILE_R + sr];
                const float4* xr = (const float4*)(nf + (size_t)(p >> 1) * D + ss * 8);
                *(float4*)(v + 0) = xr[0];
                *(float4*)(v + 4) = xr[1];
                ok = true;
            }
        }
        if (!ok) {
#pragma unroll
            for (int k = 0; k < 8; k++) v[k] = 0.f;
        }
    };
    loadt(q, vals);   // prefetch first tile (overlaps W staging)

    for (int rt = q; rt < ntile; rt += BQ) {
        int r0 = rt * TILE_R;
        int rows = min(TILE_R, n - r0);
        __syncthreads();   // W staged (1st iter); XA & HL free (later: GEMM1/GEMM2 reads done)

        // ---- write XA from prefetched regs (bf16, swizzled) ----
        {
            unsigned short hb[8] __attribute__((aligned(16)));
#pragma unroll
            for (int k = 0; k < 8; k++) hb[k] = f2bf(vals[k]);
            *(int4*)(smem + XA + sr * 256 + ((ss * 16) ^ ((sr & 7) << 4))) = *(int4*)hb;
        }
        __syncthreads();   // XA ready

        loadt(rt + BQ, vals);   // issue next tile's loads; latency hidden under compute

        // ---- GEMM1: H[32x256] = X @ W1; wave wv owns h-cols [wv*32, +32) ----
        f32x4 acc1[2][2];
#pragma unroll
        for (int mt = 0; mt < 2; mt++)
#pragma unroll
            for (int nt = 0; nt < 2; nt++) acc1[mt][nt] = zero;
#pragma unroll
        for (int ks = 0; ks < 4; ks++) {
            int kb = ks * 64 + lhi * 16;
            s16x8 a0 = *(const s16x8*)(smem + XA + llo * 256        + (kb ^ ((llo & 7) << 4)));
            s16x8 a1 = *(const s16x8*)(smem + XA + (llo + 16) * 256 + (kb ^ ((llo & 7) << 4)));
#pragma unroll
            for (int nt = 0; nt < 2; nt++) {
                int h = wv * 32 + nt * 16 + llo;
                int u = (ks * 256 + h) * 4 + lhi;
                s16x8 b = *(const s16x8*)(smem + W1L + ((u * 16) ^ ((h & 7) << 4)));
                acc1[0][nt] = __builtin_amdgcn_mfma_f32_16x16x32_bf16(a0, b, acc1[0][nt], 0, 0, 0);
                acc1[1][nt] = __builtin_amdgcn_mfma_f32_16x16x32_bf16(a1, b, acc1[1][nt], 0, 0, 0);
            }
        }

        // ---- gelu -> HL (bf16, swizzled) ----
#pragma unroll
        for (int mt = 0; mt < 2; mt++)
#pragma unroll
            for (int nt = 0; nt < 2; nt++)
#pragma unroll
                for (int r = 0; r < 4; r++) {
                    int m = mt * 16 + lhi * 4 + r;
                    int hc = wv * 32 + nt * 16 + llo;
                    float hv = acc1[mt][nt][r] + b1[e * H + hc];
                    float g = 0.5f * hv * (1.0f + erff(hv * 0.70710678118654752f));
                    *(unsigned short*)(smem + HL + m * 512 + ((hc * 2) ^ ((m & 7) << 4))) = f2bf(g);
                }
        __syncthreads();   // HL ready

        // ---- GEMM2: Y[32x128] = H @ W2; wave wv owns d-cols [wv*16, +16) ----
        f32x4 acc2[2];
        acc2[0] = zero; acc2[1] = zero;
#pragma unroll
        for (int ks = 0; ks < 8; ks++) {
            int kb = ks * 64 + lhi * 16;
            s16x8 a0 = *(const s16x8*)(smem + HL + llo * 512        + (kb ^ ((llo & 7) << 4)));
            s16x8 a1 = *(const s16x8*)(smem + HL + (llo + 16) * 512 + (kb ^ ((llo & 7) << 4)));
            int d = wv * 16 + llo;
            int u = (ks * 128 + d) * 4 + lhi;
            s16x8 b = *(const s16x8*)(smem + W2L + ((u * 16) ^ ((d & 7) << 4)));
            acc2[0] = __builtin_amdgcn_mfma_f32_16x16x32_bf16(a0, b, acc2[0], 0, 0, 0);
            acc2[1] = __builtin_amdgcn_mfma_f32_16x16x32_bf16(a1, b, acc2[1], 0, 0, 0);
        }

        // ---- epilogue: y = gw * (acc + b2) -> ybuf (bf16) ----
        int d = wv * 16 + llo;
        float bb = b2[e * D + d];
#pragma unroll
        for (int mt = 0; mt < 2; mt++)
#pragma unroll
            for (int r = 0; r < 4; r++) {
                int m = mt * 16 + lhi * 4 + r;
                if (m < rows) {
                    int p = plist[e * CAP + r0 + m];
                    ybuf[(size_t)p * D + d] = f2bf(gwbuf[p] * (acc2[mt][r] + bb));
                }
            }
    }
}

// ---------------- BatchNorm ----------------
__global__ __launch_bounds__(256) void k_bnpart(const float* __restrict__ nf,
                                                const unsigned short* __restrict__ ybuf,
                                                double* __restrict__ part) {
    int blk = blockIdx.x;
    int col = threadIdx.x & 127;
    int half = threadIdx.x >> 7;
    int r0 = blk * BN_ROWS;
    int r1 = min(r0 + BN_ROWS, N_NODES);
    double s = 0.0, ss = 0.0;
    for (int r = r0 + half; r < r1; r += 2) {
        float v32 = nf[(size_t)r * D + col]
                  + bf2f(ybuf[(size_t)(2 * r) * D + col])
                  + bf2f(ybuf[(size_t)(2 * r + 1) * D + col]);
        double v = (double)v32;
        s += v; ss += v * v;
    }
    __shared__ double sh[2][256];
    sh[0][threadIdx.x] = s; sh[1][threadIdx.x] = ss;
    __syncthreads();
    if (threadIdx.x < 128) {
        part[(size_t)blk * 256 + col]       = sh[0][col] + sh[0][col + 128];
        part[(size_t)blk * 256 + 128 + col] = sh[1][col] + sh[1][col + 128];
    }
}

__global__ void k_bnstats(const double* __restrict__ part,
                          const float* __restrict__ gamma,
                          float* __restrict__ stats) {
    int col = threadIdx.x;   // 128 threads
    double s = 0.0, ss = 0.0;
    for (int b = 0; b < BN_NBLK; b++) {
        s  += part[(size_t)b * 256 + col];
        ss += part[(size_t)b * 256 + 128 + col];
    }
    double mean = s / (double)N_NODES;
    double var = ss / (double)N_NODES - mean * mean;
    stats[col] = (float)mean;
    stats[128 + col] = gamma[col] * (float)(1.0 / sqrt(var + 1e-5));
}

__global__ __launch_bounds__(256) void k_bnapply(const unsigned short* __restrict__ ybuf,
                                                 const float* __restrict__ stats,
                                                 const float* __restrict__ beta,
                                                 float* __restrict__ out) {
    int i = blockIdx.x * blockDim.x + threadIdx.x;   // float4 index
    if (i >= N_NODES * (D / 4)) return;
    int t = i >> 5;
    int q = i & 31;
    int c0 = q * 4;
    float4 v  = ((float4*)out)[i];
    short4 y0v = *(const short4*)(ybuf + (size_t)(2 * t) * D + c0);
    short4 y1v = *(const short4*)(ybuf + (size_t)(2 * t + 1) * D + c0);
    float4 r;
    r.x = (v.x + bf2f((unsigned short)y0v.x) + bf2f((unsigned short)y1v.x) - stats[c0 + 0]) * stats[128 + c0 + 0] + beta[c0 + 0];
    r.y = (v.y + bf2f((unsigned short)y0v.y) + bf2f((unsigned short)y1v.y) - stats[c0 + 1]) * stats[128 + c0 + 1] + beta[c0 + 1];
    r.z = (v.z + bf2f((unsigned short)y0v.z) + bf2f((unsigned short)y1v.z) - stats[c0 + 2]) * stats[128 + c0 + 2] + beta[c0 + 2];
    r.w = (v.w + bf2f((unsigned short)y0v.w) + bf2f((unsigned short)y1v.w) - stats[c0 + 3]) * stats[128 + c0 + 3] + beta[c0 + 3];
    ((float4*)out)[i] = r;
}

// ---------------- launch ----------------
extern "C" void kernel_launch(void* const* d_in, const int* in_sizes, int n_in,
                              void* d_out, int out_size, void* d_ws, size_t ws_size,
                              hipStream_t stream) {
    const float* feats   = (const float*)d_in[0];
    const int*   esrc    = (const int*)d_in[1];
    const int*   edst    = (const int*)d_in[2];
    const float* W_conv  = (const float*)d_in[3];
    const float* b_conv  = (const float*)d_in[4];
    const float* gate_W  = (const float*)d_in[5];
    const float* gate_b  = (const float*)d_in[6];
    const float* W1      = (const float*)d_in[7];
    const float* b1      = (const float*)d_in[8];
    const float* W2      = (const float*)d_in[9];
    const float* b2      = (const float*)d_in[10];
    const float* bn_g    = (const float*)d_in[11];
    const float* bn_b    = (const float*)d_in[12];
    float* out = (float*)d_out;   // doubles as new_feats storage

    char* ws = (char*)d_ws;
    size_t off = 0;
    auto rup = [](size_t x) { return (x + 255) & ~(size_t)255; };
    int*    deg    = (int*)   (ws + off); off += rup((size_t)N_NODES * 4);
    int*    cursor = (int*)   (ws + off); off += rup((size_t)N_NODES * 4);
    int*    cnt    = (int*)   (ws + off); off += 256;
    int*    rcnt   = (int*)   (ws + off); off += 256;
    size_t zero_bytes = off;                 // deg + cursor + cnt + rcnt (~400 KB)
    float*  invs   = (float*) (ws + off); off += rup((size_t)N_NODES * 4);
    int*    rowptr = (int*)   (ws + off); off += rup((size_t)(N_NODES + 1) * 4);
    int*    csr    = (int*)   (ws + off); off += rup((size_t)N_EDGES * 4);
    float*  gwbuf  = (float*) (ws + off); off += rup((size_t)NPAIR * 4);
    int*    topi   = (int*)   (ws + off); off += rup((size_t)NPAIR * 4);
    int*    redo   = (int*)   (ws + off); off += rup((size_t)N_NODES * 4);
    int*    plist  = (int*)   (ws + off); off += rup((size_t)NE * CAP * 4);
    double* part   = (double*)(ws + off); off += rup((size_t)BN_NBLK * 256 * 8);
    float*  stats  = (float*) (ws + off); off += 1024;
    unsigned short* w1c = (unsigned short*)(ws + off); off += rup((size_t)NE * D * H * 2); // 4 MB
    unsigned short* w2c = (unsigned short*)(ws + off); off += rup((size_t)NE * D * H * 2); // 4 MB
    unsigned short* ybuf = (unsigned short*)(ws + off); off += rup((size_t)NPAIR * D * 2); // 25.6 MB
    float*  agg    = (float*)ybuf;   // lifetime-disjoint alias (agg dead before k_moe writes ybuf)
    (void)ws_size; (void)in_sizes; (void)n_in; (void)out_size;

    hipMemsetAsync(d_ws, 0, zero_bytes, stream);

    k_wconv<<<2 * NE * 4 * 256 * 4 / 256, 256, 0, stream>>>(W1, W2, w1c, w2c);
    k_deg<<<(N_EDGES + 255) / 256, 256, 0, stream>>>(edst, deg);
    k_invsqrt<<<(N_NODES + 255) / 256, 256, 0, stream>>>(deg, invs);
    k_scan<<<1, 1024, 0, stream>>>(deg, rowptr);
    k_scatter<<<(N_EDGES + 255) / 256, 256, 0, stream>>>(esrc, edst, rowptr, cursor, csr);
    k_gather<<<(N_NODES + 3) / 4, 256, 0, stream>>>(feats, rowptr, csr, invs, agg);
    k_conv<<<(N_NODES + TILE_R - 1) / TILE_R, 256, 0, stream>>>(agg, W_conv, b_conv, out);
    k_gate<<<N_NODES / 16, 256, 0, stream>>>(out, gate_W, gate_b, gwbuf, topi, rcnt, redo);
    k_gfix<<<128, 256, 0, stream>>>(out, gate_W, gate_b, rcnt, redo, gwbuf, topi);
    k_disp<<<(NPAIR + 1023) / 1024, 1024, 0, stream>>>(topi, cnt, plist);
    k_moe<<<NE * BQ, 512, 0, stream>>>(out, cnt, plist, w1c, b1, w2c, b2, gwbuf, ybuf);
    k_bnpart<<<BN_NBLK, 256, 0, stream>>>(out, ybuf, part);
    k_bnstats<<<1, 128, 0, stream>>>(part, bn_g, stats);
    k_bnapply<<<(N_NODES * (D / 4) + 255) / 256, 256, 0, stream>>>(ybuf, stats, bn_b, out);
}

// Round 15
// 507.741 us; speedup vs baseline: 1.2746x; 1.0060x over previous
//
#include <hip/hip_runtime.h>
#include <math.h>

#define N_NODES 50000
#define N_EDGES 500000
#define D 128
#define H 256
#define NE 64
#define TOPK 2
#define NPAIR (N_NODES * TOPK)
#define CAP 3126               // 2 * ceil(100000/64)
#define TILE_R 32
#define BQ 8                   // blocks per expert in k_moe (512 blocks = 2/CU)
#define BN_NBLK 128
#define BN_ROWS ((N_NODES + BN_NBLK - 1) / BN_NBLK) // 391

typedef __attribute__((ext_vector_type(8))) short s16x8;
typedef __attribute__((ext_vector_type(4))) float f32x4;

__device__ __forceinline__ unsigned short f2bf(float f) {
    unsigned u = __float_as_uint(f);
    unsigned r = (u + 0x7fffu + ((u >> 16) & 1u)) >> 16;
    return (unsigned short)r;
}
__device__ __forceinline__ float bf2f(unsigned short u) {
    return __uint_as_float(((unsigned)u) << 16);
}

// Compensated f32: TwoProd (mul + fma residual) + branch-free TwoSum.
#define DOT2(s, c, xx, ww) {                      \
    float p_ = (xx) * (ww);                       \
    float e1_ = fmaf((xx), (ww), -p_);            \
    float t_ = (s) + p_;                          \
    float z_ = t_ - (s);                          \
    float e2_ = ((s) - (t_ - z_)) + (p_ - z_);    \
    (s) = t_;                                     \
    (c) += e1_ + e2_; }

#define TSUM(s, c, pp) {                          \
    float p_ = (pp);                              \
    float t_ = (s) + p_;                          \
    float z_ = t_ - (s);                          \
    float e2_ = ((s) - (t_ - z_)) + (p_ - z_);    \
    (s) = t_;                                     \
    (c) += e2_; }

// ---------------- degree count ----------------
__global__ void k_deg(const int* __restrict__ dst, int* __restrict__ deg) {
    int i = blockIdx.x * blockDim.x + threadIdx.x;
    if (i < N_EDGES) atomicAdd(&deg[dst[i]], 1);
}

__global__ void k_invsqrt(const int* __restrict__ deg, float* __restrict__ invs) {
    int i = blockIdx.x * blockDim.x + threadIdx.x;
    if (i < N_NODES) {
        double d = (double)deg[i];
        if (d < 1.0) d = 1.0;
        invs[i] = (float)(1.0 / sqrt(d));
    }
}

// ---------------- exclusive scan of deg -> rowptr ----------------
__global__ __launch_bounds__(1024) void k_scan(const int* __restrict__ deg,
                                               int* __restrict__ rowptr) {
    __shared__ int sh[1024];
    int t = threadIdx.x;
    const int chunk = (N_NODES + 1023) / 1024;   // 49
    int lo = t * chunk;
    int hi = min(lo + chunk, N_NODES);
    int s = 0;
    for (int i = lo; i < hi; i++) s += deg[i];
    sh[t] = s;
    __syncthreads();
    for (int off = 1; off < 1024; off <<= 1) {
        int v = (t >= off) ? sh[t - off] : 0;
        __syncthreads();
        sh[t] += v;
        __syncthreads();
    }
    int run = (t == 0) ? 0 : sh[t - 1];
    for (int i = lo; i < hi; i++) { rowptr[i] = run; run += deg[i]; }
    if (t == 1023) rowptr[N_NODES] = run;
}

// ---------------- scatter edges into CSR ----------------
__global__ void k_scatter(const int* __restrict__ src, const int* __restrict__ dst,
                          const int* __restrict__ rowptr, int* __restrict__ cursor,
                          int* __restrict__ csr) {
    int e = blockIdx.x * blockDim.x + threadIdx.x;
    if (e >= N_EDGES) return;
    int d = dst[e];
    int pos = atomicAdd(&cursor[d], 1);
    csr[rowptr[d] + pos] = src[e];
}

// ---------------- per-node gather (compensated f32, order-independent ~1e-12) ----
__global__ __launch_bounds__(256) void k_gather(const float* __restrict__ feats,
                                                const int* __restrict__ rowptr,
                                                const int* __restrict__ csr,
                                                const float* __restrict__ invs,
                                                float* __restrict__ agg) {
    int node = blockIdx.x * 4 + (threadIdx.x >> 6);
    if (node >= N_NODES) return;
    int lane = threadIdx.x & 63;
    int beg = rowptr[node], end = rowptr[node + 1];
    float wd = invs[node];
    float sx = 0.f, cx = 0.f, sy = 0.f, cy = 0.f;
    for (int i = beg; i < end; i++) {
        int s = csr[i];
        float nrm = invs[s] * wd;
        float2 f = ((const float2*)(feats + (size_t)s * D))[lane];
        DOT2(sx, cx, nrm, f.x);
        DOT2(sy, cy, nrm, f.y);
    }
    ((float2*)(agg + (size_t)node * D))[lane] = make_float2(sx + cx, sy + cy);
}

// ---------------- conv GEMM: new_feats = agg @ W_conv + b_conv (fp32, untouched) ----
__global__ __launch_bounds__(256) void k_conv(const float* __restrict__ agg,
                                              const float* __restrict__ W,
                                              const float* __restrict__ bias,
                                              float* __restrict__ out) {
    __shared__ float Wl[D * D];        // 64 KB
    __shared__ float xl[TILE_R * D];   // 16 KB
    int r0 = blockIdx.x * TILE_R;
    int rows = min(TILE_R, N_NODES - r0);
    for (int i = threadIdx.x; i < D * D / 4; i += 256)
        ((float4*)Wl)[i] = ((const float4*)W)[i];
    for (int i = threadIdx.x; i < rows * 32; i += 256) {
        int r = i >> 5, q = i & 31;
        ((float4*)(xl + r * D))[q] = ((const float4*)(agg + (size_t)(r0 + r) * D))[q];
    }
    __syncthreads();
    int c = threadIdx.x & 127;
    int half = threadIdx.x >> 7;
    float acc[16];
#pragma unroll
    for (int j = 0; j < 16; j++) acc[j] = 0.f;
    for (int k = 0; k < D; k++) {
        float w = Wl[k * D + c];
#pragma unroll
        for (int j = 0; j < 16; j++) acc[j] += xl[(half + j * 2) * D + k] * w;
    }
    float b = bias[c];
#pragma unroll
    for (int j = 0; j < 16; j++) {
        int r = half + j * 2;
        if (r < rows) out[(size_t)(r0 + r) * D + c] = acc[j] + b;
    }
}

// ---------------- gate v7 FAST: plain-f32 scores + gap test; ambiguous -> redo list --
// __launch_bounds__(256,4): cap VGPR at 128 (4 waves/EU) — without it the scheduler
// hoists the fully-unrolled k4-loop's LDS loads to 256 VGPR and spills 56 MB (r11).
__global__ __launch_bounds__(256, 4) void k_gate(const float* __restrict__ nf,
                                                 const float* __restrict__ gW,
                                                 const float* __restrict__ gb,
                                                 float* __restrict__ gwout,
                                                 int* __restrict__ topi,
                                                 int* __restrict__ rcnt,
                                                 int* __restrict__ redo) {
    __shared__ float Wl[D * NE];       // 32 KB, layout [k][e]
    __shared__ float xsh[16 * D];      // 8 KB
    for (int i = threadIdx.x; i < D * NE / 4; i += 256)
        ((float4*)Wl)[i] = ((const float4*)gW)[i];
    int t_base = blockIdx.x * 16;
    for (int i = threadIdx.x; i < 16 * 32; i += 256) {
        int r = i >> 5, q = i & 31;
        ((float4*)(xsh + r * D))[q] =
            ((const float4*)(nf + (size_t)(t_base + r) * D))[q];
    }
    __syncthreads();

    int wave = threadIdx.x >> 6;
    int lane = threadIdx.x & 63;      // lane = expert
    int t0 = t_base + wave * 4;
    const float* xw = xsh + wave * 4 * D;

    float a0 = 0.f, a1 = 0.f, a2 = 0.f, a3 = 0.f;
#pragma unroll 4
    for (int k4 = 0; k4 < D; k4 += 4) {
        float x0[4], x1[4], x2[4], x3[4];
        *(float4*)x0 = *(const float4*)(xw + k4);
        *(float4*)x1 = *(const float4*)(xw + D + k4);
        *(float4*)x2 = *(const float4*)(xw + 2 * D + k4);
        *(float4*)x3 = *(const float4*)(xw + 3 * D + k4);
#pragma unroll
        for (int u = 0; u < 4; u++) {
            float w = Wl[(k4 + u) * NE + lane];
            a0 = fmaf(x0[u], w, a0);
            a1 = fmaf(x1[u], w, a1);
            a2 = fmaf(x2[u], w, a2);
            a3 = fmaf(x3[u], w, a3);
        }
    }
    float gbf = gb[lane];
    float af[4] = {a0 + gbf, a1 + gbf, a2 + gbf, a3 + gbf};

    const float TAU = 2e-4f;   // >> plain-f32 dot error (~5e-6 realistic)

#pragma unroll
    for (int j = 0; j < 4; j++) {
        float sf = (j == 0) ? af[0] : (j == 1) ? af[1] : (j == 2) ? af[2] : af[3];
        int t = t0 + j;

        // top-1 (value, lower index wins ties)
        float v1 = sf; int i1 = lane;
#pragma unroll
        for (int off = 32; off; off >>= 1) {
            float ov = __shfl_xor(v1, off);
            int   oi = __shfl_xor(i1, off);
            if (ov > v1 || (ov == v1 && oi < i1)) { v1 = ov; i1 = oi; }
        }
        // top-2 excluding i1
        float v2 = (lane == i1) ? -INFINITY : sf; int i2 = lane;
#pragma unroll
        for (int off = 32; off; off >>= 1) {
            float ov = __shfl_xor(v2, off);
            int   oi = __shfl_xor(i2, off);
            if (ov > v2 || (ov == v2 && oi < i2)) { v2 = ov; i2 = oi; }
        }
        // top-3 value only (gap test)
        float v3 = (lane == i1 || lane == i2) ? -INFINITY : sf;
#pragma unroll
        for (int off = 32; off; off >>= 1)
            v3 = fmaxf(v3, __shfl_xor(v3, off));

        if (lane == 0) {
            float dd = v2 - v1;
            float e2 = expf(dd);
            float g0 = 1.0f / (1.0f + e2);
            gwout[2 * t] = g0;
            gwout[2 * t + 1] = e2 * g0;
            topi[2 * t] = i1;
            topi[2 * t + 1] = i2;
            if ((v1 - v2 <= TAU) || (v2 - v3 <= TAU)) {
                int slot = atomicAdd(rcnt, 1);
                redo[slot] = t;
            }
        }
    }
}

// ---------------- gate FIX: comp-f32 rescore of ambiguous tokens (rare) ------------
__global__ __launch_bounds__(256) void k_gfix(const float* __restrict__ nf,
                                              const float* __restrict__ gW,
                                              const float* __restrict__ gb,
                                              const int* __restrict__ rcnt,
                                              const int* __restrict__ redo,
                                              float* __restrict__ gwout,
                                              int* __restrict__ topi) {
    int nredo = *rcnt;
    int lane = threadIdx.x & 63;
    int widx = blockIdx.x * 4 + (threadIdx.x >> 6);
    float gbf = gb[lane];
    for (int i = widx; i < nredo; i += gridDim.x * 4) {
        int t = redo[i];
        const float* xr = nf + (size_t)t * D;
        float s = 0.f, c = 0.f;
        for (int k = 0; k < D; k++)
            DOT2(s, c, xr[k], gW[k * NE + lane]);
        TSUM(s, c, gbf);
        float vv = s + c, rr = (s - vv) + c;

        float a1v = vv, a1r = rr; int i1 = lane;
#pragma unroll
        for (int off = 32; off; off >>= 1) {
            float ov = __shfl_xor(a1v, off);
            float orr = __shfl_xor(a1r, off);
            int   oi = __shfl_xor(i1, off);
            bool gt = (ov > a1v) || (ov == a1v && (orr > a1r || (orr == a1r && oi < i1)));
            if (gt) { a1v = ov; a1r = orr; i1 = oi; }
        }
        bool ex = (lane == i1);
        float a2v = ex ? -INFINITY : vv;
        float a2r = ex ? 0.f : rr;
        int i2 = lane;
#pragma unroll
        for (int off = 32; off; off >>= 1) {
            float ov = __shfl_xor(a2v, off);
            float orr = __shfl_xor(a2r, off);
            int   oi = __shfl_xor(i2, off);
            bool gt = (ov > a2v) || (ov == a2v && (orr > a2r || (orr == a2r && oi < i2)));
            if (gt) { a2v = ov; a2r = orr; i2 = oi; }
        }

        if (lane == 0) {
            float dd = (a2v - a1v) + (a2r - a1r);
            float e2 = expf(dd);
            float g0 = 1.0f / (1.0f + e2);
            gwout[2 * t] = g0;
            gwout[2 * t + 1] = e2 * g0;
            topi[2 * t] = i1;
            topi[2 * t + 1] = i2;
        }
    }
}

// ---------------- dispatch: parallel two-level counting scatter ----------------
__global__ __launch_bounds__(1024) void k_disp(const int* __restrict__ topi,
                                               int* __restrict__ cnt,
                                               int* __restrict__ plist) {
    __shared__ int lcnt[NE];
    __shared__ int lbase[NE];
    int tid = threadIdx.x;
    if (tid < NE) lcnt[tid] = 0;
    __syncthreads();
    int p = blockIdx.x * 1024 + tid;
    int e = 0, lr = 0;
    bool act = (p < NPAIR);
    if (act) {
        e = topi[p];
        lr = atomicAdd(&lcnt[e], 1);
    }
    __syncthreads();
    if (tid < NE) {
        int n = lcnt[tid];
        lbase[tid] = n ? atomicAdd(&cnt[tid], n) : 0;
    }
    __syncthreads();
    if (act) {
        int slot = lbase[e] + lr;
        if (slot < CAP) plist[e * CAP + slot] = p;
    }
}

// ---------------- weight convert: f32 -> bf16 fragments, LINEAR layout -------------
// w1 unit u1 = (ks*256+h)*4+lhi  (k = ks*32 + lhi*8 + j), per-expert 4096 units
// w2 unit u2 = (ks*128+d)*4+lhi
__global__ __launch_bounds__(256) void k_wconv(const float* __restrict__ W1,
                                               const float* __restrict__ W2,
                                               unsigned short* __restrict__ w1c,
                                               unsigned short* __restrict__ w2c) {
    int gid = blockIdx.x * 256 + threadIdx.x;
    const int NW1 = NE * 4 * 256 * 4;            // 262144
    if (gid < NW1) {
        int lhi = gid & 3, h = (gid >> 2) & 255, ks = (gid >> 10) & 3, e = gid >> 12;
        int d0 = ks * 32 + lhi * 8;
        unsigned short v[8] __attribute__((aligned(16)));
#pragma unroll
        for (int j = 0; j < 8; j++)
            v[j] = f2bf(W1[((size_t)e * D + d0 + j) * H + h]);
        *(int4*)(w1c + (size_t)gid * 8) = *(int4*)v;
    } else {
        int g = gid - NW1;
        int lhi = g & 3, d = (g >> 2) & 127, ks = (g >> 9) & 7, e = g >> 12;
        int h0 = ks * 32 + lhi * 8;
        unsigned short v[8] __attribute__((aligned(16)));
#pragma unroll
        for (int j = 0; j < 8; j++)
            v[j] = f2bf(W2[((size_t)e * H + h0 + j) * D + d]);
        *(int4*)(w2c + (size_t)g * 8) = *(int4*)v;
    }
}

// ---------------- MoE FFN v6: W fragments in REGISTERS, LDS = XA+HL only (24 KB) ----
// Each wave's B-frag slice is fixed: GEMM1 h in [wv*32,+32) -> 8 frags; GEMM2
// d = wv*16+llo -> 8 frags. 64 VGPR of W per thread, loaded once per block.
// 24 KB LDS + <=128 VGPR -> 2 blocks/CU = 16 waves (was 1 block / 8 waves, r14).
__global__ __launch_bounds__(512, 4) void k_moe(const float* __restrict__ nf,
                                                const int* __restrict__ cnt,
                                                const int* __restrict__ plist,
                                                const unsigned short* __restrict__ w1c,
                                                const float* __restrict__ b1,
                                                const unsigned short* __restrict__ w2c,
                                                const float* __restrict__ b2,
                                                const float* __restrict__ gwbuf,
                                                unsigned short* __restrict__ ybuf) {
    __shared__ __align__(16) char smem[24576];
    const int XA = 0, HL = 8192;
    int e = blockIdx.x & 63;         // same-expert blocks on same XCD (L2 W reuse)
    int q = blockIdx.x >> 6;
    int n = min(cnt[e], CAP);
    int ntile = (n + TILE_R - 1) / TILE_R;
    if (q >= ntile) return;
    int tid = threadIdx.x;

    int wv = tid >> 6, lane = tid & 63;
    int lhi = lane >> 4, llo = lane & 15;
    int sr = tid >> 4, ss = tid & 15;   // staging role: row, 16B-chunk
    f32x4 zero = {0.f, 0.f, 0.f, 0.f};

    // ---- load W fragments into registers (once per block; coalesced 1KB/wave) ----
    s16x8 w1f[4][2];
#pragma unroll
    for (int ks = 0; ks < 4; ks++)
#pragma unroll
        for (int nt = 0; nt < 2; nt++) {
            int h = wv * 32 + nt * 16 + llo;
            w1f[ks][nt] = *(const s16x8*)(w1c +
                ((size_t)e * 4096 + (ks * 256 + h) * 4 + lhi) * 8);
        }
    s16x8 w2f[8];
    {
        int d = wv * 16 + llo;
#pragma unroll
        for (int ks = 0; ks < 8; ks++)
            w2f[ks] = *(const s16x8*)(w2c +
                ((size_t)e * 4096 + (ks * 128 + d) * 4 + lhi) * 8);
    }

    float vals[8];
    auto loadt = [&](int rt2, float* v) {
        bool ok = false;
        if (rt2 < ntile) {
            int rows2 = min(TILE_R, n - rt2 * TILE_R);
            if (sr < rows2) {
                int p = plist[e * CAP + rt2 * TILE_R + sr];
                const float4* xr = (const float4*)(nf + (size_t)(p >> 1) * D + ss * 8);
                *(float4*)(v + 0) = xr[0];
                *(float4*)(v + 4) = xr[1];
                ok = true;
            }
        }
        if (!ok) {
#pragma unroll
            for (int k = 0; k < 8; k++) v[k] = 0.f;
        }
    };
    loadt(q, vals);   // prefetch first tile (overlaps W-frag loads)

    for (int rt = q; rt < ntile; rt += BQ) {
        int r0 = rt * TILE_R;
        int rows = min(TILE_R, n - r0);
        __syncthreads();   // XA & HL free (prev iter's reads done)

        // ---- write XA from prefetched regs (bf16, swizzled) ----
        {
            unsigned short hb[8] __attribute__((aligned(16)));
#pragma unroll
            for (int k = 0; k < 8; k++) hb[k] = f2bf(vals[k]);
            *(int4*)(smem + XA + sr * 256 + ((ss * 16) ^ ((sr & 7) << 4))) = *(int4*)hb;
        }
        __syncthreads();   // XA ready

        loadt(rt + BQ, vals);   // issue next tile's loads; latency hidden under compute

        // ---- GEMM1: H[32x256] = X @ W1; wave wv owns h-cols [wv*32, +32) ----
        f32x4 acc1[2][2];
#pragma unroll
        for (int mt = 0; mt < 2; mt++)
#pragma unroll
            for (int nt = 0; nt < 2; nt++) acc1[mt][nt] = zero;
#pragma unroll
        for (int ks = 0; ks < 4; ks++) {
            int kb = ks * 64 + lhi * 16;
            s16x8 a0 = *(const s16x8*)(smem + XA + llo * 256        + (kb ^ ((llo & 7) << 4)));
            s16x8 a1 = *(const s16x8*)(smem + XA + (llo + 16) * 256 + (kb ^ ((llo & 7) << 4)));
#pragma unroll
            for (int nt = 0; nt < 2; nt++) {
                acc1[0][nt] = __builtin_amdgcn_mfma_f32_16x16x32_bf16(a0, w1f[ks][nt], acc1[0][nt], 0, 0, 0);
                acc1[1][nt] = __builtin_amdgcn_mfma_f32_16x16x32_bf16(a1, w1f[ks][nt], acc1[1][nt], 0, 0, 0);
            }
        }

        // ---- gelu -> HL (bf16, swizzled) ----
#pragma unroll
        for (int mt = 0; mt < 2; mt++)
#pragma unroll
            for (int nt = 0; nt < 2; nt++)
#pragma unroll
                for (int r = 0; r < 4; r++) {
                    int m = mt * 16 + lhi * 4 + r;
                    int hc = wv * 32 + nt * 16 + llo;
                    float hv = acc1[mt][nt][r] + b1[e * H + hc];
                    float g = 0.5f * hv * (1.0f + erff(hv * 0.70710678118654752f));
                    *(unsigned short*)(smem + HL + m * 512 + ((hc * 2) ^ ((m & 7) << 4))) = f2bf(g);
                }
        __syncthreads();   // HL ready

        // ---- GEMM2: Y[32x128] = H @ W2; wave wv owns d-cols [wv*16, +16) ----
        f32x4 acc2[2];
        acc2[0] = zero; acc2[1] = zero;
#pragma unroll
        for (int ks = 0; ks < 8; ks++) {
            int kb = ks * 64 + lhi * 16;
            s16x8 a0 = *(const s16x8*)(smem + HL + llo * 512        + (kb ^ ((llo & 7) << 4)));
            s16x8 a1 = *(const s16x8*)(smem + HL + (llo + 16) * 512 + (kb ^ ((llo & 7) << 4)));
            acc2[0] = __builtin_amdgcn_mfma_f32_16x16x32_bf16(a0, w2f[ks], acc2[0], 0, 0, 0);
            acc2[1] = __builtin_amdgcn_mfma_f32_16x16x32_bf16(a1, w2f[ks], acc2[1], 0, 0, 0);
        }

        // ---- epilogue: y = gw * (acc + b2) -> ybuf (bf16) ----
        int d = wv * 16 + llo;
        float bb = b2[e * D + d];
#pragma unroll
        for (int mt = 0; mt < 2; mt++)
#pragma unroll
            for (int r = 0; r < 4; r++) {
                int m = mt * 16 + lhi * 4 + r;
                if (m < rows) {
                    int p = plist[e * CAP + r0 + m];
                    ybuf[(size_t)p * D + d] = f2bf(gwbuf[p] * (acc2[mt][r] + bb));
                }
            }
    }
}

// ---------------- BatchNorm ----------------
__global__ __launch_bounds__(256) void k_bnpart(const float* __restrict__ nf,
                                                const unsigned short* __restrict__ ybuf,
                                                double* __restrict__ part) {
    int blk = blockIdx.x;
    int col = threadIdx.x & 127;
    int half = threadIdx.x >> 7;
    int r0 = blk * BN_ROWS;
    int r1 = min(r0 + BN_ROWS, N_NODES);
    double s = 0.0, ss = 0.0;
    for (int r = r0 + half; r < r1; r += 2) {
        float v32 = nf[(size_t)r * D + col]
                  + bf2f(ybuf[(size_t)(2 * r) * D + col])
                  + bf2f(ybuf[(size_t)(2 * r + 1) * D + col]);
        double v = (double)v32;
        s += v; ss += v * v;
    }
    __shared__ double sh[2][256];
    sh[0][threadIdx.x] = s; sh[1][threadIdx.x] = ss;
    __syncthreads();
    if (threadIdx.x < 128) {
        part[(size_t)blk * 256 + col]       = sh[0][col] + sh[0][col + 128];
        part[(size_t)blk * 256 + 128 + col] = sh[1][col] + sh[1][col + 128];
    }
}

__global__ void k_bnstats(const double* __restrict__ part,
                          const float* __restrict__ gamma,
                          float* __restrict__ stats) {
    int col = threadIdx.x;   // 128 threads
    double s = 0.0, ss = 0.0;
    for (int b = 0; b < BN_NBLK; b++) {
        s  += part[(size_t)b * 256 + col];
        ss += part[(size_t)b * 256 + 128 + col];
    }
    double mean = s / (double)N_NODES;
    double var = ss / (double)N_NODES - mean * mean;
    stats[col] = (float)mean;
    stats[128 + col] = gamma[col] * (float)(1.0 / sqrt(var + 1e-5));
}

__global__ __launch_bounds__(256) void k_bnapply(const unsigned short* __restrict__ ybuf,
                                                 const float* __restrict__ stats,
                                                 const float* __restrict__ beta,
                                                 float* __restrict__ out) {
    int i = blockIdx.x * blockDim.x + threadIdx.x;   // float4 index
    if (i >= N_NODES * (D / 4)) return;
    int t = i >> 5;
    int q = i & 31;
    int c0 = q * 4;
    float4 v  = ((float4*)out)[i];
    short4 y0v = *(const short4*)(ybuf + (size_t)(2 * t) * D + c0);
    short4 y1v = *(const short4*)(ybuf + (size_t)(2 * t + 1) * D + c0);
    float4 r;
    r.x = (v.x + bf2f((unsigned short)y0v.x) + bf2f((unsigned short)y1v.x) - stats[c0 + 0]) * stats[128 + c0 + 0] + beta[c0 + 0];
    r.y = (v.y + bf2f((unsigned short)y0v.y) + bf2f((unsigned short)y1v.y) - stats[c0 + 1]) * stats[128 + c0 + 1] + beta[c0 + 1];
    r.z = (v.z + bf2f((unsigned short)y0v.z) + bf2f((unsigned short)y1v.z) - stats[c0 + 2]) * stats[128 + c0 + 2] + beta[c0 + 2];
    r.w = (v.w + bf2f((unsigned short)y0v.w) + bf2f((unsigned short)y1v.w) - stats[c0 + 3]) * stats[128 + c0 + 3] + beta[c0 + 3];
    ((float4*)out)[i] = r;
}

// ---------------- launch ----------------
extern "C" void kernel_launch(void* const* d_in, const int* in_sizes, int n_in,
                              void* d_out, int out_size, void* d_ws, size_t ws_size,
                              hipStream_t stream) {
    const float* feats   = (const float*)d_in[0];
    const int*   esrc    = (const int*)d_in[1];
    const int*   edst    = (const int*)d_in[2];
    const float* W_conv  = (const float*)d_in[3];
    const float* b_conv  = (const float*)d_in[4];
    const float* gate_W  = (const float*)d_in[5];
    const float* gate_b  = (const float*)d_in[6];
    const float* W1      = (const float*)d_in[7];
    const float* b1      = (const float*)d_in[8];
    const float* W2      = (const float*)d_in[9];
    const float* b2      = (const float*)d_in[10];
    const float* bn_g    = (const float*)d_in[11];
    const float* bn_b    = (const float*)d_in[12];
    float* out = (float*)d_out;   // doubles as new_feats storage

    char* ws = (char*)d_ws;
    size_t off = 0;
    auto rup = [](size_t x) { return (x + 255) & ~(size_t)255; };
    int*    deg    = (int*)   (ws + off); off += rup((size_t)N_NODES * 4);
    int*    cursor = (int*)   (ws + off); off += rup((size_t)N_NODES * 4);
    int*    cnt    = (int*)   (ws + off); off += 256;
    int*    rcnt   = (int*)   (ws + off); off += 256;
    size_t zero_bytes = off;                 // deg + cursor + cnt + rcnt (~400 KB)
    float*  invs   = (float*) (ws + off); off += rup((size_t)N_NODES * 4);
    int*    rowptr = (int*)   (ws + off); off += rup((size_t)(N_NODES + 1) * 4);
    int*    csr    = (int*)   (ws + off); off += rup((size_t)N_EDGES * 4);
    float*  gwbuf  = (float*) (ws + off); off += rup((size_t)NPAIR * 4);
    int*    topi   = (int*)   (ws + off); off += rup((size_t)NPAIR * 4);
    int*    redo   = (int*)   (ws + off); off += rup((size_t)N_NODES * 4);
    int*    plist  = (int*)   (ws + off); off += rup((size_t)NE * CAP * 4);
    double* part   = (double*)(ws + off); off += rup((size_t)BN_NBLK * 256 * 8);
    float*  stats  = (float*) (ws + off); off += 1024;
    unsigned short* w1c = (unsigned short*)(ws + off); off += rup((size_t)NE * D * H * 2); // 4 MB
    unsigned short* w2c = (unsigned short*)(ws + off); off += rup((size_t)NE * D * H * 2); // 4 MB
    unsigned short* ybuf = (unsigned short*)(ws + off); off += rup((size_t)NPAIR * D * 2); // 25.6 MB
    float*  agg    = (float*)ybuf;   // lifetime-disjoint alias (agg dead before k_moe writes ybuf)
    (void)ws_size; (void)in_sizes; (void)n_in; (void)out_size;

    hipMemsetAsync(d_ws, 0, zero_bytes, stream);

    k_wconv<<<2 * NE * 4 * 256 * 4 / 256, 256, 0, stream>>>(W1, W2, w1c, w2c);
    k_deg<<<(N_EDGES + 255) / 256, 256, 0, stream>>>(edst, deg);
    k_invsqrt<<<(N_NODES + 255) / 256, 256, 0, stream>>>(deg, invs);
    k_scan<<<1, 1024, 0, stream>>>(deg, rowptr);
    k_scatter<<<(N_EDGES + 255) / 256, 256, 0, stream>>>(esrc, edst, rowptr, cursor, csr);
    k_gather<<<(N_NODES + 3) / 4, 256, 0, stream>>>(feats, rowptr, csr, invs, agg);
    k_conv<<<(N_NODES + TILE_R - 1) / TILE_R, 256, 0, stream>>>(agg, W_conv, b_conv, out);
    k_gate<<<N_NODES / 16, 256, 0, stream>>>(out, gate_W, gate_b, gwbuf, topi, rcnt, redo);
    k_gfix<<<128, 256, 0, stream>>>(out, gate_W, gate_b, rcnt, redo, gwbuf, topi);
    k_disp<<<(NPAIR + 1023) / 1024, 1024, 0, stream>>>(topi, cnt, plist);
    k_moe<<<NE * BQ, 512, 0, stream>>>(out, cnt, plist, w1c, b1, w2c, b2, gwbuf, ybuf);
    k_bnpart<<<BN_NBLK, 256, 0, stream>>>(out, ybuf, part);
    k_bnstats<<<1, 128, 0, stream>>>(part, bn_g, stats);
    k_bnapply<<<(N_NODES * (D / 4) + 255) / 256, 256, 0, stream>>>(ybuf, stats, bn_b, out);
}

// Round 16
// 491.955 us; speedup vs baseline: 1.3155x; 1.0321x over previous
//
#include <hip/hip_runtime.h>
#include <math.h>

#define N_NODES 50000
#define N_EDGES 500000
#define D 128
#define H 256
#define NE 64
#define TOPK 2
#define NPAIR (N_NODES * TOPK)
#define CAP 3126               // 2 * ceil(100000/64)
#define TILE_R 32
#define BQ 16                  // blocks per expert in k_moe (1024 blocks = 4/CU)
#define BN_NBLK 128
#define BN_ROWS ((N_NODES + BN_NBLK - 1) / BN_NBLK) // 391

typedef __attribute__((ext_vector_type(8))) short s16x8;
typedef __attribute__((ext_vector_type(4))) float f32x4;

__device__ __forceinline__ unsigned short f2bf(float f) {
    unsigned u = __float_as_uint(f);
    unsigned r = (u + 0x7fffu + ((u >> 16) & 1u)) >> 16;
    return (unsigned short)r;
}
__device__ __forceinline__ float bf2f(unsigned short u) {
    return __uint_as_float(((unsigned)u) << 16);
}

// Compensated f32: TwoProd (mul + fma residual) + branch-free TwoSum.
#define DOT2(s, c, xx, ww) {                      \
    float p_ = (xx) * (ww);                       \
    float e1_ = fmaf((xx), (ww), -p_);            \
    float t_ = (s) + p_;                          \
    float z_ = t_ - (s);                          \
    float e2_ = ((s) - (t_ - z_)) + (p_ - z_);    \
    (s) = t_;                                     \
    (c) += e1_ + e2_; }

#define TSUM(s, c, pp) {                          \
    float p_ = (pp);                              \
    float t_ = (s) + p_;                          \
    float z_ = t_ - (s);                          \
    float e2_ = ((s) - (t_ - z_)) + (p_ - z_);    \
    (s) = t_;                                     \
    (c) += e2_; }

// ---------------- degree count ----------------
__global__ void k_deg(const int* __restrict__ dst, int* __restrict__ deg) {
    int i = blockIdx.x * blockDim.x + threadIdx.x;
    if (i < N_EDGES) atomicAdd(&deg[dst[i]], 1);
}

__global__ void k_invsqrt(const int* __restrict__ deg, float* __restrict__ invs) {
    int i = blockIdx.x * blockDim.x + threadIdx.x;
    if (i < N_NODES) {
        double d = (double)deg[i];
        if (d < 1.0) d = 1.0;
        invs[i] = (float)(1.0 / sqrt(d));
    }
}

// ---------------- exclusive scan of deg -> rowptr ----------------
__global__ __launch_bounds__(1024) void k_scan(const int* __restrict__ deg,
                                               int* __restrict__ rowptr) {
    __shared__ int sh[1024];
    int t = threadIdx.x;
    const int chunk = (N_NODES + 1023) / 1024;   // 49
    int lo = t * chunk;
    int hi = min(lo + chunk, N_NODES);
    int s = 0;
    for (int i = lo; i < hi; i++) s += deg[i];
    sh[t] = s;
    __syncthreads();
    for (int off = 1; off < 1024; off <<= 1) {
        int v = (t >= off) ? sh[t - off] : 0;
        __syncthreads();
        sh[t] += v;
        __syncthreads();
    }
    int run = (t == 0) ? 0 : sh[t - 1];
    for (int i = lo; i < hi; i++) { rowptr[i] = run; run += deg[i]; }
    if (t == 1023) rowptr[N_NODES] = run;
}

// ---------------- scatter edges into CSR ----------------
__global__ void k_scatter(const int* __restrict__ src, const int* __restrict__ dst,
                          const int* __restrict__ rowptr, int* __restrict__ cursor,
                          int* __restrict__ csr) {
    int e = blockIdx.x * blockDim.x + threadIdx.x;
    if (e >= N_EDGES) return;
    int d = dst[e];
    int pos = atomicAdd(&cursor[d], 1);
    csr[rowptr[d] + pos] = src[e];
}

// ---------------- per-node gather (compensated f32, order-independent ~1e-12) ----
__global__ __launch_bounds__(256) void k_gather(const float* __restrict__ feats,
                                                const int* __restrict__ rowptr,
                                                const int* __restrict__ csr,
                                                const float* __restrict__ invs,
                                                float* __restrict__ agg) {
    int node = blockIdx.x * 4 + (threadIdx.x >> 6);
    if (node >= N_NODES) return;
    int lane = threadIdx.x & 63;
    int beg = rowptr[node], end = rowptr[node + 1];
    float wd = invs[node];
    float sx = 0.f, cx = 0.f, sy = 0.f, cy = 0.f;
    for (int i = beg; i < end; i++) {
        int s = csr[i];
        float nrm = invs[s] * wd;
        float2 f = ((const float2*)(feats + (size_t)s * D))[lane];
        DOT2(sx, cx, nrm, f.x);
        DOT2(sy, cy, nrm, f.y);
    }
    ((float2*)(agg + (size_t)node * D))[lane] = make_float2(sx + cx, sy + cy);
}

// ---------------- conv GEMM: new_feats = agg @ W_conv + b_conv (fp32, untouched) ----
__global__ __launch_bounds__(256) void k_conv(const float* __restrict__ agg,
                                              const float* __restrict__ W,
                                              const float* __restrict__ bias,
                                              float* __restrict__ out) {
    __shared__ float Wl[D * D];        // 64 KB
    __shared__ float xl[TILE_R * D];   // 16 KB
    int r0 = blockIdx.x * TILE_R;
    int rows = min(TILE_R, N_NODES - r0);
    for (int i = threadIdx.x; i < D * D / 4; i += 256)
        ((float4*)Wl)[i] = ((const float4*)W)[i];
    for (int i = threadIdx.x; i < rows * 32; i += 256) {
        int r = i >> 5, q = i & 31;
        ((float4*)(xl + r * D))[q] = ((const float4*)(agg + (size_t)(r0 + r) * D))[q];
    }
    __syncthreads();
    int c = threadIdx.x & 127;
    int half = threadIdx.x >> 7;
    float acc[16];
#pragma unroll
    for (int j = 0; j < 16; j++) acc[j] = 0.f;
    for (int k = 0; k < D; k++) {
        float w = Wl[k * D + c];
#pragma unroll
        for (int j = 0; j < 16; j++) acc[j] += xl[(half + j * 2) * D + k] * w;
    }
    float b = bias[c];
#pragma unroll
    for (int j = 0; j < 16; j++) {
        int r = half + j * 2;
        if (r < rows) out[(size_t)(r0 + r) * D + c] = acc[j] + b;
    }
}

// ---------------- gate v7 FAST: plain-f32 scores + gap test; ambiguous -> redo list --
// __launch_bounds__(256,4): cap VGPR at 128 (4 waves/EU) — without it the scheduler
// hoists the fully-unrolled k4-loop's LDS loads to 256 VGPR and spills 56 MB (r11).
__global__ __launch_bounds__(256, 4) void k_gate(const float* __restrict__ nf,
                                                 const float* __restrict__ gW,
                                                 const float* __restrict__ gb,
                                                 float* __restrict__ gwout,
                                                 int* __restrict__ topi,
                                                 int* __restrict__ rcnt,
                                                 int* __restrict__ redo) {
    __shared__ float Wl[D * NE];       // 32 KB, layout [k][e]
    __shared__ float xsh[16 * D];      // 8 KB
    for (int i = threadIdx.x; i < D * NE / 4; i += 256)
        ((float4*)Wl)[i] = ((const float4*)gW)[i];
    int t_base = blockIdx.x * 16;
    for (int i = threadIdx.x; i < 16 * 32; i += 256) {
        int r = i >> 5, q = i & 31;
        ((float4*)(xsh + r * D))[q] =
            ((const float4*)(nf + (size_t)(t_base + r) * D))[q];
    }
    __syncthreads();

    int wave = threadIdx.x >> 6;
    int lane = threadIdx.x & 63;      // lane = expert
    int t0 = t_base + wave * 4;
    const float* xw = xsh + wave * 4 * D;

    float a0 = 0.f, a1 = 0.f, a2 = 0.f, a3 = 0.f;
#pragma unroll 4
    for (int k4 = 0; k4 < D; k4 += 4) {
        float x0[4], x1[4], x2[4], x3[4];
        *(float4*)x0 = *(const float4*)(xw + k4);
        *(float4*)x1 = *(const float4*)(xw + D + k4);
        *(float4*)x2 = *(const float4*)(xw + 2 * D + k4);
        *(float4*)x3 = *(const float4*)(xw + 3 * D + k4);
#pragma unroll
        for (int u = 0; u < 4; u++) {
            float w = Wl[(k4 + u) * NE + lane];
            a0 = fmaf(x0[u], w, a0);
            a1 = fmaf(x1[u], w, a1);
            a2 = fmaf(x2[u], w, a2);
            a3 = fmaf(x3[u], w, a3);
        }
    }
    float gbf = gb[lane];
    float af[4] = {a0 + gbf, a1 + gbf, a2 + gbf, a3 + gbf};

    const float TAU = 2e-4f;   // >> plain-f32 dot error (~5e-6 realistic)

#pragma unroll
    for (int j = 0; j < 4; j++) {
        float sf = (j == 0) ? af[0] : (j == 1) ? af[1] : (j == 2) ? af[2] : af[3];
        int t = t0 + j;

        // top-1 (value, lower index wins ties)
        float v1 = sf; int i1 = lane;
#pragma unroll
        for (int off = 32; off; off >>= 1) {
            float ov = __shfl_xor(v1, off);
            int   oi = __shfl_xor(i1, off);
            if (ov > v1 || (ov == v1 && oi < i1)) { v1 = ov; i1 = oi; }
        }
        // top-2 excluding i1
        float v2 = (lane == i1) ? -INFINITY : sf; int i2 = lane;
#pragma unroll
        for (int off = 32; off; off >>= 1) {
            float ov = __shfl_xor(v2, off);
            int   oi = __shfl_xor(i2, off);
            if (ov > v2 || (ov == v2 && oi < i2)) { v2 = ov; i2 = oi; }
        }
        // top-3 value only (gap test)
        float v3 = (lane == i1 || lane == i2) ? -INFINITY : sf;
#pragma unroll
        for (int off = 32; off; off >>= 1)
            v3 = fmaxf(v3, __shfl_xor(v3, off));

        if (lane == 0) {
            float dd = v2 - v1;
            float e2 = expf(dd);
            float g0 = 1.0f / (1.0f + e2);
            gwout[2 * t] = g0;
            gwout[2 * t + 1] = e2 * g0;
            topi[2 * t] = i1;
            topi[2 * t + 1] = i2;
            if ((v1 - v2 <= TAU) || (v2 - v3 <= TAU)) {
                int slot = atomicAdd(rcnt, 1);
                redo[slot] = t;
            }
        }
    }
}

// ---------------- gate FIX: comp-f32 rescore of ambiguous tokens (rare) ------------
__global__ __launch_bounds__(256) void k_gfix(const float* __restrict__ nf,
                                              const float* __restrict__ gW,
                                              const float* __restrict__ gb,
                                              const int* __restrict__ rcnt,
                                              const int* __restrict__ redo,
                                              float* __restrict__ gwout,
                                              int* __restrict__ topi) {
    int nredo = *rcnt;
    int lane = threadIdx.x & 63;
    int widx = blockIdx.x * 4 + (threadIdx.x >> 6);
    float gbf = gb[lane];
    for (int i = widx; i < nredo; i += gridDim.x * 4) {
        int t = redo[i];
        const float* xr = nf + (size_t)t * D;
        float s = 0.f, c = 0.f;
        for (int k = 0; k < D; k++)
            DOT2(s, c, xr[k], gW[k * NE + lane]);
        TSUM(s, c, gbf);
        float vv = s + c, rr = (s - vv) + c;

        float a1v = vv, a1r = rr; int i1 = lane;
#pragma unroll
        for (int off = 32; off; off >>= 1) {
            float ov = __shfl_xor(a1v, off);
            float orr = __shfl_xor(a1r, off);
            int   oi = __shfl_xor(i1, off);
            bool gt = (ov > a1v) || (ov == a1v && (orr > a1r || (orr == a1r && oi < i1)));
            if (gt) { a1v = ov; a1r = orr; i1 = oi; }
        }
        bool ex = (lane == i1);
        float a2v = ex ? -INFINITY : vv;
        float a2r = ex ? 0.f : rr;
        int i2 = lane;
#pragma unroll
        for (int off = 32; off; off >>= 1) {
            float ov = __shfl_xor(a2v, off);
            float orr = __shfl_xor(a2r, off);
            int   oi = __shfl_xor(i2, off);
            bool gt = (ov > a2v) || (ov == a2v && (orr > a2r || (orr == a2r && oi < i2)));
            if (gt) { a2v = ov; a2r = orr; i2 = oi; }
        }

        if (lane == 0) {
            float dd = (a2v - a1v) + (a2r - a1r);
            float e2 = expf(dd);
            float g0 = 1.0f / (1.0f + e2);
            gwout[2 * t] = g0;
            gwout[2 * t + 1] = e2 * g0;
            topi[2 * t] = i1;
            topi[2 * t + 1] = i2;
        }
    }
}

// ---------------- dispatch: parallel two-level counting scatter ----------------
__global__ __launch_bounds__(1024) void k_disp(const int* __restrict__ topi,
                                               int* __restrict__ cnt,
                                               int* __restrict__ plist) {
    __shared__ int lcnt[NE];
    __shared__ int lbase[NE];
    int tid = threadIdx.x;
    if (tid < NE) lcnt[tid] = 0;
    __syncthreads();
    int p = blockIdx.x * 1024 + tid;
    int e = 0, lr = 0;
    bool act = (p < NPAIR);
    if (act) {
        e = topi[p];
        lr = atomicAdd(&lcnt[e], 1);
    }
    __syncthreads();
    if (tid < NE) {
        int n = lcnt[tid];
        lbase[tid] = n ? atomicAdd(&cnt[tid], n) : 0;
    }
    __syncthreads();
    if (act) {
        int slot = lbase[e] + lr;
        if (slot < CAP) plist[e * CAP + slot] = p;
    }
}

// ---------------- weight convert: f32 -> bf16 fragments, LINEAR layout -------------
// w1 unit u1 = (ks*256+h)*4+lhi  (k = ks*32 + lhi*8 + j), per-expert 4096 units
// w2 unit u2 = (ks*128+d)*4+lhi
__global__ __launch_bounds__(256) void k_wconv(const float* __restrict__ W1,
                                               const float* __restrict__ W2,
                                               unsigned short* __restrict__ w1c,
                                               unsigned short* __restrict__ w2c) {
    int gid = blockIdx.x * 256 + threadIdx.x;
    const int NW1 = NE * 4 * 256 * 4;            // 262144
    if (gid < NW1) {
        int lhi = gid & 3, h = (gid >> 2) & 255, ks = (gid >> 10) & 3, e = gid >> 12;
        int d0 = ks * 32 + lhi * 8;
        unsigned short v[8] __attribute__((aligned(16)));
#pragma unroll
        for (int j = 0; j < 8; j++)
            v[j] = f2bf(W1[((size_t)e * D + d0 + j) * H + h]);
        *(int4*)(w1c + (size_t)gid * 8) = *(int4*)v;
    } else {
        int g = gid - NW1;
        int lhi = g & 3, d = (g >> 2) & 127, ks = (g >> 9) & 7, e = g >> 12;
        int h0 = ks * 32 + lhi * 8;
        unsigned short v[8] __attribute__((aligned(16)));
#pragma unroll
        for (int j = 0; j < 8; j++)
            v[j] = f2bf(W2[((size_t)e * H + h0 + j) * D + d]);
        *(int4*)(w2c + (size_t)g * 8) = *(int4*)v;
    }
}

// ---------------- MoE FFN v7: W in registers; coalesced ybuf writes via YB bounce ---
// LDS 32 KB (XA 8 | HL 16 | YB 8) + 64 VGPR -> 4 blocks/CU (BQ=16, 1024 blocks).
// Epilogue: y staged in YB then written as full 256B rows (fixes 2B-scatter RMW, r15:
// WRITE 47MB / FETCH +25MB were partial-cacheline read-modify-write).
__global__ __launch_bounds__(512, 4) void k_moe(const float* __restrict__ nf,
                                                const int* __restrict__ cnt,
                                                const int* __restrict__ plist,
                                                const unsigned short* __restrict__ w1c,
                                                const float* __restrict__ b1,
                                                const unsigned short* __restrict__ w2c,
                                                const float* __restrict__ b2,
                                                const float* __restrict__ gwbuf,
                                                unsigned short* __restrict__ ybuf) {
    __shared__ __align__(16) char smem[32768];
    const int XA = 0, HL = 8192, YB = 24576;
    int e = blockIdx.x & 63;         // same-expert blocks on same XCD (L2 W reuse)
    int q = blockIdx.x >> 6;
    int n = min(cnt[e], CAP);
    int ntile = (n + TILE_R - 1) / TILE_R;
    if (q >= ntile) return;
    int tid = threadIdx.x;

    int wv = tid >> 6, lane = tid & 63;
    int lhi = lane >> 4, llo = lane & 15;
    int sr = tid >> 4, ss = tid & 15;   // staging role: row, 16B-chunk
    f32x4 zero = {0.f, 0.f, 0.f, 0.f};

    // ---- load W fragments into registers (once per block; coalesced 1KB/wave) ----
    s16x8 w1f[4][2];
#pragma unroll
    for (int ks = 0; ks < 4; ks++)
#pragma unroll
        for (int nt = 0; nt < 2; nt++) {
            int h = wv * 32 + nt * 16 + llo;
            w1f[ks][nt] = *(const s16x8*)(w1c +
                ((size_t)e * 4096 + (ks * 256 + h) * 4 + lhi) * 8);
        }
    s16x8 w2f[8];
    {
        int d = wv * 16 + llo;
#pragma unroll
        for (int ks = 0; ks < 8; ks++)
            w2f[ks] = *(const s16x8*)(w2c +
                ((size_t)e * 4096 + (ks * 128 + d) * 4 + lhi) * 8);
    }

    float vals[8];
    auto loadt = [&](int rt2, float* v) {
        bool ok = false;
        if (rt2 < ntile) {
            int rows2 = min(TILE_R, n - rt2 * TILE_R);
            if (sr < rows2) {
                int p = plist[e * CAP + rt2 * TILE_R + sr];
                const float4* xr = (const float4*)(nf + (size_t)(p >> 1) * D + ss * 8);
                *(float4*)(v + 0) = xr[0];
                *(float4*)(v + 4) = xr[1];
                ok = true;
            }
        }
        if (!ok) {
#pragma unroll
            for (int k = 0; k < 8; k++) v[k] = 0.f;
        }
    };
    loadt(q, vals);   // prefetch first tile (overlaps W-frag loads)

    for (int rt = q; rt < ntile; rt += BQ) {
        int r0 = rt * TILE_R;
        int rows = min(TILE_R, n - r0);
        __syncthreads();   // XA/HL/YB free (prev iter's reads done)

        // ---- write XA from prefetched regs (bf16, swizzled) ----
        {
            unsigned short hb[8] __attribute__((aligned(16)));
#pragma unroll
            for (int k = 0; k < 8; k++) hb[k] = f2bf(vals[k]);
            *(int4*)(smem + XA + sr * 256 + ((ss * 16) ^ ((sr & 7) << 4))) = *(int4*)hb;
        }
        __syncthreads();   // XA ready

        loadt(rt + BQ, vals);   // issue next tile's loads; latency hidden under compute

        // ---- GEMM1: H[32x256] = X @ W1; wave wv owns h-cols [wv*32, +32) ----
        f32x4 acc1[2][2];
#pragma unroll
        for (int mt = 0; mt < 2; mt++)
#pragma unroll
            for (int nt = 0; nt < 2; nt++) acc1[mt][nt] = zero;
#pragma unroll
        for (int ks = 0; ks < 4; ks++) {
            int kb = ks * 64 + lhi * 16;
            s16x8 a0 = *(const s16x8*)(smem + XA + llo * 256        + (kb ^ ((llo & 7) << 4)));
            s16x8 a1 = *(const s16x8*)(smem + XA + (llo + 16) * 256 + (kb ^ ((llo & 7) << 4)));
#pragma unroll
            for (int nt = 0; nt < 2; nt++) {
                acc1[0][nt] = __builtin_amdgcn_mfma_f32_16x16x32_bf16(a0, w1f[ks][nt], acc1[0][nt], 0, 0, 0);
                acc1[1][nt] = __builtin_amdgcn_mfma_f32_16x16x32_bf16(a1, w1f[ks][nt], acc1[1][nt], 0, 0, 0);
            }
        }

        // ---- gelu -> HL (bf16, swizzled) ----
#pragma unroll
        for (int mt = 0; mt < 2; mt++)
#pragma unroll
            for (int nt = 0; nt < 2; nt++)
#pragma unroll
                for (int r = 0; r < 4; r++) {
                    int m = mt * 16 + lhi * 4 + r;
                    int hc = wv * 32 + nt * 16 + llo;
                    float hv = acc1[mt][nt][r] + b1[e * H + hc];
                    float g = 0.5f * hv * (1.0f + erff(hv * 0.70710678118654752f));
                    *(unsigned short*)(smem + HL + m * 512 + ((hc * 2) ^ ((m & 7) << 4))) = f2bf(g);
                }
        __syncthreads();   // HL ready

        // ---- GEMM2: Y[32x128] = H @ W2; wave wv owns d-cols [wv*16, +16) ----
        f32x4 acc2[2];
        acc2[0] = zero; acc2[1] = zero;
#pragma unroll
        for (int ks = 0; ks < 8; ks++) {
            int kb = ks * 64 + lhi * 16;
            s16x8 a0 = *(const s16x8*)(smem + HL + llo * 512        + (kb ^ ((llo & 7) << 4)));
            s16x8 a1 = *(const s16x8*)(smem + HL + (llo + 16) * 512 + (kb ^ ((llo & 7) << 4)));
            acc2[0] = __builtin_amdgcn_mfma_f32_16x16x32_bf16(a0, w2f[ks], acc2[0], 0, 0, 0);
            acc2[1] = __builtin_amdgcn_mfma_f32_16x16x32_bf16(a1, w2f[ks], acc2[1], 0, 0, 0);
        }

        // ---- stage y (acc2 + b2) into YB (bf16, swizzled) ----
        {
            int d = wv * 16 + llo;
            float bb = b2[e * D + d];
#pragma unroll
            for (int mt = 0; mt < 2; mt++)
#pragma unroll
                for (int r = 0; r < 4; r++) {
                    int m = mt * 16 + lhi * 4 + r;
                    *(unsigned short*)(smem + YB + m * 256 + ((d * 2) ^ ((m & 7) << 4))) =
                        f2bf(acc2[mt][r] + bb);
                }
        }
        __syncthreads();   // YB ready

        // ---- coalesced ybuf write: thread owns (row sr, 16B chunk ss) ----
        if (sr < rows) {
            int p = plist[e * CAP + r0 + sr];
            float gw = gwbuf[p];
            unsigned short yv[8] __attribute__((aligned(16)));
            *(int4*)yv = *(const int4*)(smem + YB + sr * 256 + ((ss * 16) ^ ((sr & 7) << 4)));
#pragma unroll
            for (int k = 0; k < 8; k++) yv[k] = f2bf(gw * bf2f(yv[k]));
            *(int4*)(ybuf + (size_t)p * D + ss * 8) = *(int4*)yv;
        }
    }
}

// ---------------- BatchNorm ----------------
__global__ __launch_bounds__(256) void k_bnpart(const float* __restrict__ nf,
                                                const unsigned short* __restrict__ ybuf,
                                                double* __restrict__ part) {
    int blk = blockIdx.x;
    int col = threadIdx.x & 127;
    int half = threadIdx.x >> 7;
    int r0 = blk * BN_ROWS;
    int r1 = min(r0 + BN_ROWS, N_NODES);
    double s = 0.0, ss = 0.0;
    for (int r = r0 + half; r < r1; r += 2) {
        float v32 = nf[(size_t)r * D + col]
                  + bf2f(ybuf[(size_t)(2 * r) * D + col])
                  + bf2f(ybuf[(size_t)(2 * r + 1) * D + col]);
        double v = (double)v32;
        s += v; ss += v * v;
    }
    __shared__ double sh[2][256];
    sh[0][threadIdx.x] = s; sh[1][threadIdx.x] = ss;
    __syncthreads();
    if (threadIdx.x < 128) {
        part[(size_t)blk * 256 + col]       = sh[0][col] + sh[0][col + 128];
        part[(size_t)blk * 256 + 128 + col] = sh[1][col] + sh[1][col + 128];
    }
}

__global__ void k_bnstats(const double* __restrict__ part,
                          const float* __restrict__ gamma,
                          float* __restrict__ stats) {
    int col = threadIdx.x;   // 128 threads
    double s = 0.0, ss = 0.0;
    for (int b = 0; b < BN_NBLK; b++) {
        s  += part[(size_t)b * 256 + col];
        ss += part[(size_t)b * 256 + 128 + col];
    }
    double mean = s / (double)N_NODES;
    double var = ss / (double)N_NODES - mean * mean;
    stats[col] = (float)mean;
    stats[128 + col] = gamma[col] * (float)(1.0 / sqrt(var + 1e-5));
}

__global__ __launch_bounds__(256) void k_bnapply(const unsigned short* __restrict__ ybuf,
                                                 const float* __restrict__ stats,
                                                 const float* __restrict__ beta,
                                                 float* __restrict__ out) {
    int i = blockIdx.x * blockDim.x + threadIdx.x;   // float4 index
    if (i >= N_NODES * (D / 4)) return;
    int t = i >> 5;
    int q = i & 31;
    int c0 = q * 4;
    float4 v  = ((float4*)out)[i];
    short4 y0v = *(const short4*)(ybuf + (size_t)(2 * t) * D + c0);
    short4 y1v = *(const short4*)(ybuf + (size_t)(2 * t + 1) * D + c0);
    float4 r;
    r.x = (v.x + bf2f((unsigned short)y0v.x) + bf2f((unsigned short)y1v.x) - stats[c0 + 0]) * stats[128 + c0 + 0] + beta[c0 + 0];
    r.y = (v.y + bf2f((unsigned short)y0v.y) + bf2f((unsigned short)y1v.y) - stats[c0 + 1]) * stats[128 + c0 + 1] + beta[c0 + 1];
    r.z = (v.z + bf2f((unsigned short)y0v.z) + bf2f((unsigned short)y1v.z) - stats[c0 + 2]) * stats[128 + c0 + 2] + beta[c0 + 2];
    r.w = (v.w + bf2f((unsigned short)y0v.w) + bf2f((unsigned short)y1v.w) - stats[c0 + 3]) * stats[128 + c0 + 3] + beta[c0 + 3];
    ((float4*)out)[i] = r;
}

// ---------------- launch ----------------
extern "C" void kernel_launch(void* const* d_in, const int* in_sizes, int n_in,
                              void* d_out, int out_size, void* d_ws, size_t ws_size,
                              hipStream_t stream) {
    const float* feats   = (const float*)d_in[0];
    const int*   esrc    = (const int*)d_in[1];
    const int*   edst    = (const int*)d_in[2];
    const float* W_conv  = (const float*)d_in[3];
    const float* b_conv  = (const float*)d_in[4];
    const float* gate_W  = (const float*)d_in[5];
    const float* gate_b  = (const float*)d_in[6];
    const float* W1      = (const float*)d_in[7];
    const float* b1      = (const float*)d_in[8];
    const float* W2      = (const float*)d_in[9];
    const float* b2      = (const float*)d_in[10];
    const float* bn_g    = (const float*)d_in[11];
    const float* bn_b    = (const float*)d_in[12];
    float* out = (float*)d_out;   // doubles as new_feats storage

    char* ws = (char*)d_ws;
    size_t off = 0;
    auto rup = [](size_t x) { return (x + 255) & ~(size_t)255; };
    int*    deg    = (int*)   (ws + off); off += rup((size_t)N_NODES * 4);
    int*    cursor = (int*)   (ws + off); off += rup((size_t)N_NODES * 4);
    int*    cnt    = (int*)   (ws + off); off += 256;
    int*    rcnt   = (int*)   (ws + off); off += 256;
    size_t zero_bytes = off;                 // deg + cursor + cnt + rcnt (~400 KB)
    float*  invs   = (float*) (ws + off); off += rup((size_t)N_NODES * 4);
    int*    rowptr = (int*)   (ws + off); off += rup((size_t)(N_NODES + 1) * 4);
    int*    csr    = (int*)   (ws + off); off += rup((size_t)N_EDGES * 4);
    float*  gwbuf  = (float*) (ws + off); off += rup((size_t)NPAIR * 4);
    int*    topi   = (int*)   (ws + off); off += rup((size_t)NPAIR * 4);
    int*    redo   = (int*)   (ws + off); off += rup((size_t)N_NODES * 4);
    int*    plist  = (int*)   (ws + off); off += rup((size_t)NE * CAP * 4);
    double* part   = (double*)(ws + off); off += rup((size_t)BN_NBLK * 256 * 8);
    float*  stats  = (float*) (ws + off); off += 1024;
    unsigned short* w1c = (unsigned short*)(ws + off); off += rup((size_t)NE * D * H * 2); // 4 MB
    unsigned short* w2c = (unsigned short*)(ws + off); off += rup((size_t)NE * D * H * 2); // 4 MB
    unsigned short* ybuf = (unsigned short*)(ws + off); off += rup((size_t)NPAIR * D * 2); // 25.6 MB
    float*  agg    = (float*)ybuf;   // lifetime-disjoint alias (agg dead before k_moe writes ybuf)
    (void)ws_size; (void)in_sizes; (void)n_in; (void)out_size;

    hipMemsetAsync(d_ws, 0, zero_bytes, stream);

    k_wconv<<<2 * NE * 4 * 256 * 4 / 256, 256, 0, stream>>>(W1, W2, w1c, w2c);
    k_deg<<<(N_EDGES + 255) / 256, 256, 0, stream>>>(edst, deg);
    k_invsqrt<<<(N_NODES + 255) / 256, 256, 0, stream>>>(deg, invs);
    k_scan<<<1, 1024, 0, stream>>>(deg, rowptr);
    k_scatter<<<(N_EDGES + 255) / 256, 256, 0, stream>>>(esrc, edst, rowptr, cursor, csr);
    k_gather<<<(N_NODES + 3) / 4, 256, 0, stream>>>(feats, rowptr, csr, invs, agg);
    k_conv<<<(N_NODES + TILE_R - 1) / TILE_R, 256, 0, stream>>>(agg, W_conv, b_conv, out);
    k_gate<<<N_NODES / 16, 256, 0, stream>>>(out, gate_W, gate_b, gwbuf, topi, rcnt, redo);
    k_gfix<<<128, 256, 0, stream>>>(out, gate_W, gate_b, rcnt, redo, gwbuf, topi);
    k_disp<<<(NPAIR + 1023) / 1024, 1024, 0, stream>>>(topi, cnt, plist);
    k_moe<<<NE * BQ, 512, 0, stream>>>(out, cnt, plist, w1c, b1, w2c, b2, gwbuf, ybuf);
    k_bnpart<<<BN_NBLK, 256, 0, stream>>>(out, ybuf, part);
    k_bnstats<<<1, 128, 0, stream>>>(part, bn_g, stats);
    k_bnapply<<<(N_NODES * (D / 4) + 255) / 256, 256, 0, stream>>>(ybuf, stats, bn_b, out);
}

// Round 17
// 461.225 us; speedup vs baseline: 1.4032x; 1.0666x over previous
//
#include <hip/hip_runtime.h>
#include <math.h>

#define N_NODES 50000
#define N_EDGES 500000
#define D 128
#define H 256
#define NE 64
#define TOPK 2
#define NPAIR (N_NODES * TOPK)
#define CAP 3126               // 2 * ceil(100000/64)
#define TILE_R 32
#define BQ 16                  // blocks per expert in k_moe (1024 blocks = 4/CU)
#define BN_NBLK 128
#define BN_ROWS ((N_NODES + BN_NBLK - 1) / BN_NBLK) // 391

typedef __attribute__((ext_vector_type(8))) short s16x8;
typedef __attribute__((ext_vector_type(4))) float f32x4;

__device__ __forceinline__ unsigned short f2bf(float f) {
    unsigned u = __float_as_uint(f);
    unsigned r = (u + 0x7fffu + ((u >> 16) & 1u)) >> 16;
    return (unsigned short)r;
}
__device__ __forceinline__ float bf2f(unsigned short u) {
    return __uint_as_float(((unsigned)u) << 16);
}

// gelu(x) = 0.5x(1+erf(x/sqrt2)); erf via A&S 7.1.26 (|err|<=1.5e-7 << bf16 quant)
__device__ __forceinline__ float gelu_f(float x) {
    float u = 0.70710678118654752f * x;
    float au = fabsf(u);
    float t = 1.0f / fmaf(0.3275911f, au, 1.0f);
    float poly = t * fmaf(t, fmaf(t, fmaf(t, fmaf(t, 1.061405429f, -1.453152027f),
                      1.421413741f), -0.284496736f), 0.254829592f);
    float e = __expf(-u * u);
    float erfa = 1.0f - poly * e;
    float erfu = copysignf(erfa, u);
    return 0.5f * x * (1.0f + erfu);
}

// Compensated f32: TwoProd (mul + fma residual) + branch-free TwoSum.
#define DOT2(s, c, xx, ww) {                      \
    float p_ = (xx) * (ww);                       \
    float e1_ = fmaf((xx), (ww), -p_);            \
    float t_ = (s) + p_;                          \
    float z_ = t_ - (s);                          \
    float e2_ = ((s) - (t_ - z_)) + (p_ - z_);    \
    (s) = t_;                                     \
    (c) += e1_ + e2_; }

#define TSUM(s, c, pp) {                          \
    float p_ = (pp);                              \
    float t_ = (s) + p_;                          \
    float z_ = t_ - (s);                          \
    float e2_ = ((s) - (t_ - z_)) + (p_ - z_);    \
    (s) = t_;                                     \
    (c) += e2_; }

// Kahan add: 4 ops; order-variation ~1e-7 rel (covered by gate TAU band)
#define KAH(s, c, pp) {                           \
    float y_ = (pp) - (c);                        \
    float t_ = (s) + y_;                          \
    (c) = (t_ - (s)) - y_;                        \
    (s) = t_; }

// ---------------- degree count ----------------
__global__ void k_deg(const int* __restrict__ dst, int* __restrict__ deg) {
    int i = blockIdx.x * blockDim.x + threadIdx.x;
    if (i < N_EDGES) atomicAdd(&deg[dst[i]], 1);
}

__global__ void k_invsqrt(const int* __restrict__ deg, float* __restrict__ invs) {
    int i = blockIdx.x * blockDim.x + threadIdx.x;
    if (i < N_NODES) {
        double d = (double)deg[i];
        if (d < 1.0) d = 1.0;
        invs[i] = (float)(1.0 / sqrt(d));
    }
}

// ---------------- exclusive scan of deg -> rowptr ----------------
__global__ __launch_bounds__(1024) void k_scan(const int* __restrict__ deg,
                                               int* __restrict__ rowptr) {
    __shared__ int sh[1024];
    int t = threadIdx.x;
    const int chunk = (N_NODES + 1023) / 1024;   // 49
    int lo = t * chunk;
    int hi = min(lo + chunk, N_NODES);
    int s = 0;
    for (int i = lo; i < hi; i++) s += deg[i];
    sh[t] = s;
    __syncthreads();
    for (int off = 1; off < 1024; off <<= 1) {
        int v = (t >= off) ? sh[t - off] : 0;
        __syncthreads();
        sh[t] += v;
        __syncthreads();
    }
    int run = (t == 0) ? 0 : sh[t - 1];
    for (int i = lo; i < hi; i++) { rowptr[i] = run; run += deg[i]; }
    if (t == 1023) rowptr[N_NODES] = run;
}

// ---------------- scatter edges into CSR ----------------
__global__ void k_scatter(const int* __restrict__ src, const int* __restrict__ dst,
                          const int* __restrict__ rowptr, int* __restrict__ cursor,
                          int* __restrict__ csr) {
    int e = blockIdx.x * blockDim.x + threadIdx.x;
    if (e >= N_EDGES) return;
    int d = dst[e];
    int pos = atomicAdd(&cursor[d], 1);
    csr[rowptr[d] + pos] = src[e];
}

// ---------------- per-node gather: Kahan f32, 4-edge unroll (4-way MLP) -----------
__global__ __launch_bounds__(256) void k_gather(const float* __restrict__ feats,
                                                const int* __restrict__ rowptr,
                                                const int* __restrict__ csr,
                                                const float* __restrict__ invs,
                                                float* __restrict__ agg) {
    int node = blockIdx.x * 4 + (threadIdx.x >> 6);
    if (node >= N_NODES) return;
    int lane = threadIdx.x & 63;
    int beg = rowptr[node], end = rowptr[node + 1];
    float wd = invs[node];
    float sx = 0.f, cx = 0.f, sy = 0.f, cy = 0.f;
    int i = beg;
    for (; i + 4 <= end; i += 4) {
        int s0 = csr[i], s1 = csr[i + 1], s2 = csr[i + 2], s3 = csr[i + 3];
        float n0 = invs[s0] * wd, n1 = invs[s1] * wd;
        float n2 = invs[s2] * wd, n3 = invs[s3] * wd;
        float2 f0 = ((const float2*)(feats + (size_t)s0 * D))[lane];
        float2 f1 = ((const float2*)(feats + (size_t)s1 * D))[lane];
        float2 f2 = ((const float2*)(feats + (size_t)s2 * D))[lane];
        float2 f3 = ((const float2*)(feats + (size_t)s3 * D))[lane];
        KAH(sx, cx, n0 * f0.x); KAH(sy, cy, n0 * f0.y);
        KAH(sx, cx, n1 * f1.x); KAH(sy, cy, n1 * f1.y);
        KAH(sx, cx, n2 * f2.x); KAH(sy, cy, n2 * f2.y);
        KAH(sx, cx, n3 * f3.x); KAH(sy, cy, n3 * f3.y);
    }
    for (; i < end; i++) {
        int s = csr[i];
        float nrm = invs[s] * wd;
        float2 f = ((const float2*)(feats + (size_t)s * D))[lane];
        KAH(sx, cx, nrm * f.x);
        KAH(sy, cy, nrm * f.y);
    }
    ((float2*)(agg + (size_t)node * D))[lane] = make_float2(sx, sy);
}

// ---------------- conv GEMM: new_feats = agg @ W_conv + b_conv (fp32, untouched) ----
__global__ __launch_bounds__(256) void k_conv(const float* __restrict__ agg,
                                              const float* __restrict__ W,
                                              const float* __restrict__ bias,
                                              float* __restrict__ out) {
    __shared__ float Wl[D * D];        // 64 KB
    __shared__ float xl[TILE_R * D];   // 16 KB
    int r0 = blockIdx.x * TILE_R;
    int rows = min(TILE_R, N_NODES - r0);
    for (int i = threadIdx.x; i < D * D / 4; i += 256)
        ((float4*)Wl)[i] = ((const float4*)W)[i];
    for (int i = threadIdx.x; i < rows * 32; i += 256) {
        int r = i >> 5, q = i & 31;
        ((float4*)(xl + r * D))[q] = ((const float4*)(agg + (size_t)(r0 + r) * D))[q];
    }
    __syncthreads();
    int c = threadIdx.x & 127;
    int half = threadIdx.x >> 7;
    float acc[16];
#pragma unroll
    for (int j = 0; j < 16; j++) acc[j] = 0.f;
    for (int k = 0; k < D; k++) {
        float w = Wl[k * D + c];
#pragma unroll
        for (int j = 0; j < 16; j++) acc[j] += xl[(half + j * 2) * D + k] * w;
    }
    float b = bias[c];
#pragma unroll
    for (int j = 0; j < 16; j++) {
        int r = half + j * 2;
        if (r < rows) out[(size_t)(r0 + r) * D + c] = acc[j] + b;
    }
}

// ---------------- gate v7 FAST: plain-f32 scores + gap test; ambiguous -> redo list --
__global__ __launch_bounds__(256, 4) void k_gate(const float* __restrict__ nf,
                                                 const float* __restrict__ gW,
                                                 const float* __restrict__ gb,
                                                 float* __restrict__ gwout,
                                                 int* __restrict__ topi,
                                                 int* __restrict__ rcnt,
                                                 int* __restrict__ redo) {
    __shared__ float Wl[D * NE];       // 32 KB, layout [k][e]
    __shared__ float xsh[16 * D];      // 8 KB
    for (int i = threadIdx.x; i < D * NE / 4; i += 256)
        ((float4*)Wl)[i] = ((const float4*)gW)[i];
    int t_base = blockIdx.x * 16;
    for (int i = threadIdx.x; i < 16 * 32; i += 256) {
        int r = i >> 5, q = i & 31;
        ((float4*)(xsh + r * D))[q] =
            ((const float4*)(nf + (size_t)(t_base + r) * D))[q];
    }
    __syncthreads();

    int wave = threadIdx.x >> 6;
    int lane = threadIdx.x & 63;      // lane = expert
    int t0 = t_base + wave * 4;
    const float* xw = xsh + wave * 4 * D;

    float a0 = 0.f, a1 = 0.f, a2 = 0.f, a3 = 0.f;
#pragma unroll 4
    for (int k4 = 0; k4 < D; k4 += 4) {
        float x0[4], x1[4], x2[4], x3[4];
        *(float4*)x0 = *(const float4*)(xw + k4);
        *(float4*)x1 = *(const float4*)(xw + D + k4);
        *(float4*)x2 = *(const float4*)(xw + 2 * D + k4);
        *(float4*)x3 = *(const float4*)(xw + 3 * D + k4);
#pragma unroll
        for (int u = 0; u < 4; u++) {
            float w = Wl[(k4 + u) * NE + lane];
            a0 = fmaf(x0[u], w, a0);
            a1 = fmaf(x1[u], w, a1);
            a2 = fmaf(x2[u], w, a2);
            a3 = fmaf(x3[u], w, a3);
        }
    }
    float gbf = gb[lane];
    float af[4] = {a0 + gbf, a1 + gbf, a2 + gbf, a3 + gbf};

    const float TAU = 2e-4f;   // >> plain-f32 dot error (~5e-6 realistic)

#pragma unroll
    for (int j = 0; j < 4; j++) {
        float sf = (j == 0) ? af[0] : (j == 1) ? af[1] : (j == 2) ? af[2] : af[3];
        int t = t0 + j;

        float v1 = sf; int i1 = lane;
#pragma unroll
        for (int off = 32; off; off >>= 1) {
            float ov = __shfl_xor(v1, off);
            int   oi = __shfl_xor(i1, off);
            if (ov > v1 || (ov == v1 && oi < i1)) { v1 = ov; i1 = oi; }
        }
        float v2 = (lane == i1) ? -INFINITY : sf; int i2 = lane;
#pragma unroll
        for (int off = 32; off; off >>= 1) {
            float ov = __shfl_xor(v2, off);
            int   oi = __shfl_xor(i2, off);
            if (ov > v2 || (ov == v2 && oi < i2)) { v2 = ov; i2 = oi; }
        }
        float v3 = (lane == i1 || lane == i2) ? -INFINITY : sf;
#pragma unroll
        for (int off = 32; off; off >>= 1)
            v3 = fmaxf(v3, __shfl_xor(v3, off));

        if (lane == 0) {
            float dd = v2 - v1;
            float e2 = expf(dd);
            float g0 = 1.0f / (1.0f + e2);
            gwout[2 * t] = g0;
            gwout[2 * t + 1] = e2 * g0;
            topi[2 * t] = i1;
            topi[2 * t + 1] = i2;
            if ((v1 - v2 <= TAU) || (v2 - v3 <= TAU)) {
                int slot = atomicAdd(rcnt, 1);
                redo[slot] = t;
            }
        }
    }
}

// ---------------- gate FIX: comp-f32 rescore of ambiguous tokens (rare) ------------
__global__ __launch_bounds__(256) void k_gfix(const float* __restrict__ nf,
                                              const float* __restrict__ gW,
                                              const float* __restrict__ gb,
                                              const int* __restrict__ rcnt,
                                              const int* __restrict__ redo,
                                              float* __restrict__ gwout,
                                              int* __restrict__ topi) {
    int nredo = *rcnt;
    int lane = threadIdx.x & 63;
    int widx = blockIdx.x * 4 + (threadIdx.x >> 6);
    float gbf = gb[lane];
    for (int i = widx; i < nredo; i += gridDim.x * 4) {
        int t = redo[i];
        const float* xr = nf + (size_t)t * D;
        float s = 0.f, c = 0.f;
        for (int k = 0; k < D; k++)
            DOT2(s, c, xr[k], gW[k * NE + lane]);
        TSUM(s, c, gbf);
        float vv = s + c, rr = (s - vv) + c;

        float a1v = vv, a1r = rr; int i1 = lane;
#pragma unroll
        for (int off = 32; off; off >>= 1) {
            float ov = __shfl_xor(a1v, off);
            float orr = __shfl_xor(a1r, off);
            int   oi = __shfl_xor(i1, off);
            bool gt = (ov > a1v) || (ov == a1v && (orr > a1r || (orr == a1r && oi < i1)));
            if (gt) { a1v = ov; a1r = orr; i1 = oi; }
        }
        bool ex = (lane == i1);
        float a2v = ex ? -INFINITY : vv;
        float a2r = ex ? 0.f : rr;
        int i2 = lane;
#pragma unroll
        for (int off = 32; off; off >>= 1) {
            float ov = __shfl_xor(a2v, off);
            float orr = __shfl_xor(a2r, off);
            int   oi = __shfl_xor(i2, off);
            bool gt = (ov > a2v) || (ov == a2v && (orr > a2r || (orr == a2r && oi < i2)));
            if (gt) { a2v = ov; a2r = orr; i2 = oi; }
        }

        if (lane == 0) {
            float dd = (a2v - a1v) + (a2r - a1r);
            float e2 = expf(dd);
            float g0 = 1.0f / (1.0f + e2);
            gwout[2 * t] = g0;
            gwout[2 * t + 1] = e2 * g0;
            topi[2 * t] = i1;
            topi[2 * t + 1] = i2;
        }
    }
}

// ---------------- dispatch: parallel two-level counting scatter ----------------
__global__ __launch_bounds__(1024) void k_disp(const int* __restrict__ topi,
                                               int* __restrict__ cnt,
                                               int* __restrict__ plist) {
    __shared__ int lcnt[NE];
    __shared__ int lbase[NE];
    int tid = threadIdx.x;
    if (tid < NE) lcnt[tid] = 0;
    __syncthreads();
    int p = blockIdx.x * 1024 + tid;
    int e = 0, lr = 0;
    bool act = (p < NPAIR);
    if (act) {
        e = topi[p];
        lr = atomicAdd(&lcnt[e], 1);
    }
    __syncthreads();
    if (tid < NE) {
        int n = lcnt[tid];
        lbase[tid] = n ? atomicAdd(&cnt[tid], n) : 0;
    }
    __syncthreads();
    if (act) {
        int slot = lbase[e] + lr;
        if (slot < CAP) plist[e * CAP + slot] = p;
    }
}

// ---------------- weight convert: f32 -> bf16 fragments, LINEAR layout -------------
__global__ __launch_bounds__(256) void k_wconv(const float* __restrict__ W1,
                                               const float* __restrict__ W2,
                                               unsigned short* __restrict__ w1c,
                                               unsigned short* __restrict__ w2c) {
    int gid = blockIdx.x * 256 + threadIdx.x;
    const int NW1 = NE * 4 * 256 * 4;            // 262144
    if (gid < NW1) {
        int lhi = gid & 3, h = (gid >> 2) & 255, ks = (gid >> 10) & 3, e = gid >> 12;
        int d0 = ks * 32 + lhi * 8;
        unsigned short v[8] __attribute__((aligned(16)));
#pragma unroll
        for (int j = 0; j < 8; j++)
            v[j] = f2bf(W1[((size_t)e * D + d0 + j) * H + h]);
        *(int4*)(w1c + (size_t)gid * 8) = *(int4*)v;
    } else {
        int g = gid - NW1;
        int lhi = g & 3, d = (g >> 2) & 127, ks = (g >> 9) & 7, e = g >> 12;
        int h0 = ks * 32 + lhi * 8;
        unsigned short v[8] __attribute__((aligned(16)));
#pragma unroll
        for (int j = 0; j < 8; j++)
            v[j] = f2bf(W2[((size_t)e * H + h0 + j) * D + d]);
        *(int4*)(w2c + (size_t)g * 8) = *(int4*)v;
    }
}

// ---------------- MoE FFN v8: reg-W + YB bounce + fast gelu + 3 barriers/tile ------
// Top barrier removed: YB-ready(t) already fences all XA/HL reads of iter t, and
// iter t's YB read (ybuf store) completes before XA-ready(t+1).
__global__ __launch_bounds__(512, 4) void k_moe(const float* __restrict__ nf,
                                                const int* __restrict__ cnt,
                                                const int* __restrict__ plist,
                                                const unsigned short* __restrict__ w1c,
                                                const float* __restrict__ b1,
                                                const unsigned short* __restrict__ w2c,
                                                const float* __restrict__ b2,
                                                const float* __restrict__ gwbuf,
                                                unsigned short* __restrict__ ybuf) {
    __shared__ __align__(16) char smem[32768];
    const int XA = 0, HL = 8192, YB = 24576;
    int e = blockIdx.x & 63;         // same-expert blocks on same XCD (L2 W reuse)
    int q = blockIdx.x >> 6;
    int n = min(cnt[e], CAP);
    int ntile = (n + TILE_R - 1) / TILE_R;
    if (q >= ntile) return;
    int tid = threadIdx.x;

    int wv = tid >> 6, lane = tid & 63;
    int lhi = lane >> 4, llo = lane & 15;
    int sr = tid >> 4, ss = tid & 15;   // staging role: row, 16B-chunk
    f32x4 zero = {0.f, 0.f, 0.f, 0.f};

    // ---- load W fragments into registers (once per block; coalesced 1KB/wave) ----
    s16x8 w1f[4][2];
#pragma unroll
    for (int ks = 0; ks < 4; ks++)
#pragma unroll
        for (int nt = 0; nt < 2; nt++) {
            int h = wv * 32 + nt * 16 + llo;
            w1f[ks][nt] = *(const s16x8*)(w1c +
                ((size_t)e * 4096 + (ks * 256 + h) * 4 + lhi) * 8);
        }
    s16x8 w2f[8];
    {
        int d = wv * 16 + llo;
#pragma unroll
        for (int ks = 0; ks < 8; ks++)
            w2f[ks] = *(const s16x8*)(w2c +
                ((size_t)e * 4096 + (ks * 128 + d) * 4 + lhi) * 8);
    }

    float vals[8];
    auto loadt = [&](int rt2, float* v) {
        bool ok = false;
        if (rt2 < ntile) {
            int rows2 = min(TILE_R, n - rt2 * TILE_R);
            if (sr < rows2) {
                int p = plist[e * CAP + rt2 * TILE_R + sr];
                const float4* xr = (const float4*)(nf + (size_t)(p >> 1) * D + ss * 8);
                *(float4*)(v + 0) = xr[0];
                *(float4*)(v + 4) = xr[1];
                ok = true;
            }
        }
        if (!ok) {
#pragma unroll
            for (int k = 0; k < 8; k++) v[k] = 0.f;
        }
    };
    loadt(q, vals);   // prefetch first tile (overlaps W-frag loads)

    for (int rt = q; rt < ntile; rt += BQ) {
        int r0 = rt * TILE_R;
        int rows = min(TILE_R, n - r0);

        // ---- write XA from prefetched regs (bf16, swizzled) ----
        {
            unsigned short hb[8] __attribute__((aligned(16)));
#pragma unroll
            for (int k = 0; k < 8; k++) hb[k] = f2bf(vals[k]);
            *(int4*)(smem + XA + sr * 256 + ((ss * 16) ^ ((sr & 7) << 4))) = *(int4*)hb;
        }
        __syncthreads();   // XA ready

        loadt(rt + BQ, vals);   // issue next tile's loads; latency hidden under compute

        // ---- GEMM1: H[32x256] = X @ W1; wave wv owns h-cols [wv*32, +32) ----
        f32x4 acc1[2][2];
#pragma unroll
        for (int mt = 0; mt < 2; mt++)
#pragma unroll
            for (int nt = 0; nt < 2; nt++) acc1[mt][nt] = zero;
#pragma unroll
        for (int ks = 0; ks < 4; ks++) {
            int kb = ks * 64 + lhi * 16;
            s16x8 a0 = *(const s16x8*)(smem + XA + llo * 256        + (kb ^ ((llo & 7) << 4)));
            s16x8 a1 = *(const s16x8*)(smem + XA + (llo + 16) * 256 + (kb ^ ((llo & 7) << 4)));
#pragma unroll
            for (int nt = 0; nt < 2; nt++) {
                acc1[0][nt] = __builtin_amdgcn_mfma_f32_16x16x32_bf16(a0, w1f[ks][nt], acc1[0][nt], 0, 0, 0);
                acc1[1][nt] = __builtin_amdgcn_mfma_f32_16x16x32_bf16(a1, w1f[ks][nt], acc1[1][nt], 0, 0, 0);
            }
        }

        // ---- fast gelu -> HL (bf16, swizzled) ----
#pragma unroll
        for (int mt = 0; mt < 2; mt++)
#pragma unroll
            for (int nt = 0; nt < 2; nt++)
#pragma unroll
                for (int r = 0; r < 4; r++) {
                    int m = mt * 16 + lhi * 4 + r;
                    int hc = wv * 32 + nt * 16 + llo;
                    float hv = acc1[mt][nt][r] + b1[e * H + hc];
                    *(unsigned short*)(smem + HL + m * 512 + ((hc * 2) ^ ((m & 7) << 4))) =
                        f2bf(gelu_f(hv));
                }
        __syncthreads();   // HL ready

        // ---- GEMM2: Y[32x128] = H @ W2; wave wv owns d-cols [wv*16, +16) ----
        f32x4 acc2[2];
        acc2[0] = zero; acc2[1] = zero;
#pragma unroll
        for (int ks = 0; ks < 8; ks++) {
            int kb = ks * 64 + lhi * 16;
            s16x8 a0 = *(const s16x8*)(smem + HL + llo * 512        + (kb ^ ((llo & 7) << 4)));
            s16x8 a1 = *(const s16x8*)(smem + HL + (llo + 16) * 512 + (kb ^ ((llo & 7) << 4)));
            acc2[0] = __builtin_amdgcn_mfma_f32_16x16x32_bf16(a0, w2f[ks], acc2[0], 0, 0, 0);
            acc2[1] = __builtin_amdgcn_mfma_f32_16x16x32_bf16(a1, w2f[ks], acc2[1], 0, 0, 0);
        }

        // ---- stage y (acc2 + b2) into YB (bf16, swizzled) ----
        {
            int d = wv * 16 + llo;
            float bb = b2[e * D + d];
#pragma unroll
            for (int mt = 0; mt < 2; mt++)
#pragma unroll
                for (int r = 0; r < 4; r++) {
                    int m = mt * 16 + lhi * 4 + r;
                    *(unsigned short*)(smem + YB + m * 256 + ((d * 2) ^ ((m & 7) << 4))) =
                        f2bf(acc2[mt][r] + bb);
                }
        }
        __syncthreads();   // YB ready (also fences XA/HL reads for next iter)

        // ---- coalesced ybuf write: thread owns (row sr, 16B chunk ss) ----
        if (sr < rows) {
            int p = plist[e * CAP + r0 + sr];
            float gw = gwbuf[p];
            unsigned short yv[8] __attribute__((aligned(16)));
            *(int4*)yv = *(const int4*)(smem + YB + sr * 256 + ((ss * 16) ^ ((sr & 7) << 4)));
#pragma unroll
            for (int k = 0; k < 8; k++) yv[k] = f2bf(gw * bf2f(yv[k]));
            *(int4*)(ybuf + (size_t)p * D + ss * 8) = *(int4*)yv;
        }
    }
}

// ---------------- BatchNorm ----------------
__global__ __launch_bounds__(256) void k_bnpart(const float* __restrict__ nf,
                                                const unsigned short* __restrict__ ybuf,
                                                double* __restrict__ part) {
    int blk = blockIdx.x;
    int col = threadIdx.x & 127;
    int half = threadIdx.x >> 7;
    int r0 = blk * BN_ROWS;
    int r1 = min(r0 + BN_ROWS, N_NODES);
    double s = 0.0, ss = 0.0;
    for (int r = r0 + half; r < r1; r += 2) {
        float v32 = nf[(size_t)r * D + col]
                  + bf2f(ybuf[(size_t)(2 * r) * D + col])
                  + bf2f(ybuf[(size_t)(2 * r + 1) * D + col]);
        double v = (double)v32;
        s += v; ss += v * v;
    }
    __shared__ double sh[2][256];
    sh[0][threadIdx.x] = s; sh[1][threadIdx.x] = ss;
    __syncthreads();
    if (threadIdx.x < 128) {
        part[(size_t)blk * 256 + col]       = sh[0][col] + sh[0][col + 128];
        part[(size_t)blk * 256 + 128 + col] = sh[1][col] + sh[1][col + 128];
    }
}

__global__ void k_bnstats(const double* __restrict__ part,
                          const float* __restrict__ gamma,
                          float* __restrict__ stats) {
    int col = threadIdx.x;   // 128 threads
    double s = 0.0, ss = 0.0;
    for (int b = 0; b < BN_NBLK; b++) {
        s  += part[(size_t)b * 256 + col];
        ss += part[(size_t)b * 256 + 128 + col];
    }
    double mean = s / (double)N_NODES;
    double var = ss / (double)N_NODES - mean * mean;
    stats[col] = (float)mean;
    stats[128 + col] = gamma[col] * (float)(1.0 / sqrt(var + 1e-5));
}

__global__ __launch_bounds__(256) void k_bnapply(const unsigned short* __restrict__ ybuf,
                                                 const float* __restrict__ stats,
                                                 const float* __restrict__ beta,
                                                 float* __restrict__ out) {
    int i = blockIdx.x * blockDim.x + threadIdx.x;   // float4 index
    if (i >= N_NODES * (D / 4)) return;
    int t = i >> 5;
    int q = i & 31;
    int c0 = q * 4;
    float4 v  = ((float4*)out)[i];
    short4 y0v = *(const short4*)(ybuf + (size_t)(2 * t) * D + c0);
    short4 y1v = *(const short4*)(ybuf + (size_t)(2 * t + 1) * D + c0);
    float4 r;
    r.x = (v.x + bf2f((unsigned short)y0v.x) + bf2f((unsigned short)y1v.x) - stats[c0 + 0]) * stats[128 + c0 + 0] + beta[c0 + 0];
    r.y = (v.y + bf2f((unsigned short)y0v.y) + bf2f((unsigned short)y1v.y) - stats[c0 + 1]) * stats[128 + c0 + 1] + beta[c0 + 1];
    r.z = (v.z + bf2f((unsigned short)y0v.z) + bf2f((unsigned short)y1v.z) - stats[c0 + 2]) * stats[128 + c0 + 2] + beta[c0 + 2];
    r.w = (v.w + bf2f((unsigned short)y0v.w) + bf2f((unsigned short)y1v.w) - stats[c0 + 3]) * stats[128 + c0 + 3] + beta[c0 + 3];
    ((float4*)out)[i] = r;
}

// ---------------- launch ----------------
extern "C" void kernel_launch(void* const* d_in, const int* in_sizes, int n_in,
                              void* d_out, int out_size, void* d_ws, size_t ws_size,
                              hipStream_t stream) {
    const float* feats   = (const float*)d_in[0];
    const int*   esrc    = (const int*)d_in[1];
    const int*   edst    = (const int*)d_in[2];
    const float* W_conv  = (const float*)d_in[3];
    const float* b_conv  = (const float*)d_in[4];
    const float* gate_W  = (const float*)d_in[5];
    const float* gate_b  = (const float*)d_in[6];
    const float* W1      = (const float*)d_in[7];
    const float* b1      = (const float*)d_in[8];
    const float* W2      = (const float*)d_in[9];
    const float* b2      = (const float*)d_in[10];
    const float* bn_g    = (const float*)d_in[11];
    const float* bn_b    = (const float*)d_in[12];
    float* out = (float*)d_out;   // doubles as new_feats storage

    char* ws = (char*)d_ws;
    size_t off = 0;
    auto rup = [](size_t x) { return (x + 255) & ~(size_t)255; };
    int*    deg    = (int*)   (ws + off); off += rup((size_t)N_NODES * 4);
    int*    cursor = (int*)   (ws + off); off += rup((size_t)N_NODES * 4);
    int*    cnt    = (int*)   (ws + off); off += 256;
    int*    rcnt   = (int*)   (ws + off); off += 256;
    size_t zero_bytes = off;                 // deg + cursor + cnt + rcnt (~400 KB)
    float*  invs   = (float*) (ws + off); off += rup((size_t)N_NODES * 4);
    int*    rowptr = (int*)   (ws + off); off += rup((size_t)(N_NODES + 1) * 4);
    int*    csr    = (int*)   (ws + off); off += rup((size_t)N_EDGES * 4);
    float*  gwbuf  = (float*) (ws + off); off += rup((size_t)NPAIR * 4);
    int*    topi   = (int*)   (ws + off); off += rup((size_t)NPAIR * 4);
    int*    redo   = (int*)   (ws + off); off += rup((size_t)N_NODES * 4);
    int*    plist  = (int*)   (ws + off); off += rup((size_t)NE * CAP * 4);
    double* part   = (double*)(ws + off); off += rup((size_t)BN_NBLK * 256 * 8);
    float*  stats  = (float*) (ws + off); off += 1024;
    unsigned short* w1c = (unsigned short*)(ws + off); off += rup((size_t)NE * D * H * 2); // 4 MB
    unsigned short* w2c = (unsigned short*)(ws + off); off += rup((size_t)NE * D * H * 2); // 4 MB
    unsigned short* ybuf = (unsigned short*)(ws + off); off += rup((size_t)NPAIR * D * 2); // 25.6 MB
    float*  agg    = (float*)ybuf;   // lifetime-disjoint alias (agg dead before k_moe writes ybuf)
    (void)ws_size; (void)in_sizes; (void)n_in; (void)out_size;

    hipMemsetAsync(d_ws, 0, zero_bytes, stream);

    k_wconv<<<2 * NE * 4 * 256 * 4 / 256, 256, 0, stream>>>(W1, W2, w1c, w2c);
    k_deg<<<(N_EDGES + 255) / 256, 256, 0, stream>>>(edst, deg);
    k_invsqrt<<<(N_NODES + 255) / 256, 256, 0, stream>>>(deg, invs);
    k_scan<<<1, 1024, 0, stream>>>(deg, rowptr);
    k_scatter<<<(N_EDGES + 255) / 256, 256, 0, stream>>>(esrc, edst, rowptr, cursor, csr);
    k_gather<<<(N_NODES + 3) / 4, 256, 0, stream>>>(feats, rowptr, csr, invs, agg);
    k_conv<<<(N_NODES + TILE_R - 1) / TILE_R, 256, 0, stream>>>(agg, W_conv, b_conv, out);
    k_gate<<<N_NODES / 16, 256, 0, stream>>>(out, gate_W, gate_b, gwbuf, topi, rcnt, redo);
    k_gfix<<<128, 256, 0, stream>>>(out, gate_W, gate_b, rcnt, redo, gwbuf, topi);
    k_disp<<<(NPAIR + 1023) / 1024, 1024, 0, stream>>>(topi, cnt, plist);
    k_moe<<<NE * BQ, 512, 0, stream>>>(out, cnt, plist, w1c, b1, w2c, b2, gwbuf, ybuf);
    k_bnpart<<<BN_NBLK, 256, 0, stream>>>(out, ybuf, part);
    k_bnstats<<<1, 128, 0, stream>>>(part, bn_g, stats);
    k_bnapply<<<(N_NODES * (D / 4) + 255) / 256, 256, 0, stream>>>(ybuf, stats, bn_b, out);
}

// Round 18
// 417.730 us; speedup vs baseline: 1.5493x; 1.1041x over previous
//
#include <hip/hip_runtime.h>
#include <math.h>

#define N_NODES 50000
#define N_EDGES 500000
#define D 128
#define H 256
#define NE 64
#define TOPK 2
#define NPAIR (N_NODES * TOPK)
#define CAP 3126               // 2 * ceil(100000/64)
#define TILE_R 32
#define BQ 16                  // blocks per expert in k_moe (1024 blocks = 4/CU)
#define BN_NBLK 128
#define BN_ROWS ((N_NODES + BN_NBLK - 1) / BN_NBLK) // 391

typedef __attribute__((ext_vector_type(8))) short s16x8;
typedef __attribute__((ext_vector_type(4))) float f32x4;

__device__ __forceinline__ unsigned short f2bf(float f) {
    unsigned u = __float_as_uint(f);
    unsigned r = (u + 0x7fffu + ((u >> 16) & 1u)) >> 16;
    return (unsigned short)r;
}
__device__ __forceinline__ float bf2f(unsigned short u) {
    return __uint_as_float(((unsigned)u) << 16);
}

// gelu(x) = 0.5x(1+erf(x/sqrt2)); erf via A&S 7.1.26 (|err|<=1.5e-7 << bf16 quant)
__device__ __forceinline__ float gelu_f(float x) {
    float u = 0.70710678118654752f * x;
    float au = fabsf(u);
    float t = 1.0f / fmaf(0.3275911f, au, 1.0f);
    float poly = t * fmaf(t, fmaf(t, fmaf(t, fmaf(t, 1.061405429f, -1.453152027f),
                      1.421413741f), -0.284496736f), 0.254829592f);
    float e = __expf(-u * u);
    float erfa = 1.0f - poly * e;
    float erfu = copysignf(erfa, u);
    return 0.5f * x * (1.0f + erfu);
}

// Compensated f32: TwoProd (mul + fma residual) + branch-free TwoSum.
#define DOT2(s, c, xx, ww) {                      \
    float p_ = (xx) * (ww);                       \
    float e1_ = fmaf((xx), (ww), -p_);            \
    float t_ = (s) + p_;                          \
    float z_ = t_ - (s);                          \
    float e2_ = ((s) - (t_ - z_)) + (p_ - z_);    \
    (s) = t_;                                     \
    (c) += e1_ + e2_; }

#define TSUM(s, c, pp) {                          \
    float p_ = (pp);                              \
    float t_ = (s) + p_;                          \
    float z_ = t_ - (s);                          \
    float e2_ = ((s) - (t_ - z_)) + (p_ - z_);    \
    (s) = t_;                                     \
    (c) += e2_; }

// Kahan add: 4 ops; order-variation ~1e-7 rel (covered by gate TAU band)
#define KAH(s, c, pp) {                           \
    float y_ = (pp) - (c);                        \
    float t_ = (s) + y_;                          \
    (c) = (t_ - (s)) - y_;                        \
    (s) = t_; }

// ---------------- degree count ----------------
__global__ void k_deg(const int* __restrict__ dst, int* __restrict__ deg) {
    int i = blockIdx.x * blockDim.x + threadIdx.x;
    if (i < N_EDGES) atomicAdd(&deg[dst[i]], 1);
}

__global__ void k_invsqrt(const int* __restrict__ deg, float* __restrict__ invs) {
    int i = blockIdx.x * blockDim.x + threadIdx.x;
    if (i < N_NODES) {
        double d = (double)deg[i];
        if (d < 1.0) d = 1.0;
        invs[i] = (float)(1.0 / sqrt(d));
    }
}

// ---------------- exclusive scan of deg -> rowptr ----------------
__global__ __launch_bounds__(1024) void k_scan(const int* __restrict__ deg,
                                               int* __restrict__ rowptr) {
    __shared__ int sh[1024];
    int t = threadIdx.x;
    const int chunk = (N_NODES + 1023) / 1024;   // 49
    int lo = t * chunk;
    int hi = min(lo + chunk, N_NODES);
    int s = 0;
    for (int i = lo; i < hi; i++) s += deg[i];
    sh[t] = s;
    __syncthreads();
    for (int off = 1; off < 1024; off <<= 1) {
        int v = (t >= off) ? sh[t - off] : 0;
        __syncthreads();
        sh[t] += v;
        __syncthreads();
    }
    int run = (t == 0) ? 0 : sh[t - 1];
    for (int i = lo; i < hi; i++) { rowptr[i] = run; run += deg[i]; }
    if (t == 1023) rowptr[N_NODES] = run;
}

// ---------------- scatter edges into CSR ----------------
__global__ void k_scatter(const int* __restrict__ src, const int* __restrict__ dst,
                          const int* __restrict__ rowptr, int* __restrict__ cursor,
                          int* __restrict__ csr) {
    int e = blockIdx.x * blockDim.x + threadIdx.x;
    if (e >= N_EDGES) return;
    int d = dst[e];
    int pos = atomicAdd(&cursor[d], 1);
    csr[rowptr[d] + pos] = src[e];
}

// ---------------- per-node gather: Kahan f32, 4-edge unroll (4-way MLP) -----------
__global__ __launch_bounds__(256) void k_gather(const float* __restrict__ feats,
                                                const int* __restrict__ rowptr,
                                                const int* __restrict__ csr,
                                                const float* __restrict__ invs,
                                                float* __restrict__ agg) {
    int node = blockIdx.x * 4 + (threadIdx.x >> 6);
    if (node >= N_NODES) return;
    int lane = threadIdx.x & 63;
    int beg = rowptr[node], end = rowptr[node + 1];
    float wd = invs[node];
    float sx = 0.f, cx = 0.f, sy = 0.f, cy = 0.f;
    int i = beg;
    for (; i + 4 <= end; i += 4) {
        int s0 = csr[i], s1 = csr[i + 1], s2 = csr[i + 2], s3 = csr[i + 3];
        float n0 = invs[s0] * wd, n1 = invs[s1] * wd;
        float n2 = invs[s2] * wd, n3 = invs[s3] * wd;
        float2 f0 = ((const float2*)(feats + (size_t)s0 * D))[lane];
        float2 f1 = ((const float2*)(feats + (size_t)s1 * D))[lane];
        float2 f2 = ((const float2*)(feats + (size_t)s2 * D))[lane];
        float2 f3 = ((const float2*)(feats + (size_t)s3 * D))[lane];
        KAH(sx, cx, n0 * f0.x); KAH(sy, cy, n0 * f0.y);
        KAH(sx, cx, n1 * f1.x); KAH(sy, cy, n1 * f1.y);
        KAH(sx, cx, n2 * f2.x); KAH(sy, cy, n2 * f2.y);
        KAH(sx, cx, n3 * f3.x); KAH(sy, cy, n3 * f3.y);
    }
    for (; i < end; i++) {
        int s = csr[i];
        float nrm = invs[s] * wd;
        float2 f = ((const float2*)(feats + (size_t)s * D))[lane];
        KAH(sx, cx, nrm * f.x);
        KAH(sy, cy, nrm * f.y);
    }
    ((float2*)(agg + (size_t)node * D))[lane] = make_float2(sx, sy);
}

// ---------------- W_conv split: f32 -> (hi,lo) bf16 fragments ----------------------
// unit u = (ks*128 + c)*4 + lhi, k = ks*32 + lhi*8 + j; 2048 units of 16B each
__global__ __launch_bounds__(256) void k_wcsplit(const float* __restrict__ W,
                                                 unsigned short* __restrict__ whi,
                                                 unsigned short* __restrict__ wlo) {
    int u = blockIdx.x * 256 + threadIdx.x;   // 0..2047
    int lhi = u & 3, c = (u >> 2) & 127, ks = u >> 9;
    int k0 = ks * 32 + lhi * 8;
    unsigned short vh[8] __attribute__((aligned(16)));
    unsigned short vl[8] __attribute__((aligned(16)));
#pragma unroll
    for (int j = 0; j < 8; j++) {
        float x = W[(size_t)(k0 + j) * D + c];
        unsigned short h = f2bf(x);
        vh[j] = h;
        vl[j] = f2bf(x - bf2f(h));
    }
    *(int4*)(whi + (size_t)u * 8) = *(int4*)vh;
    *(int4*)(wlo + (size_t)u * 8) = *(int4*)vl;
}

// ---------------- conv GEMM v2: split-bf16 MFMA (err ~2e-6, f32-class) -------------
// out[32x128] = X[32x128] @ W[128x128] + b; X split hi/lo in LDS; W frags in regs.
// x*w ~= xh*wh + xh*wl + xl*wh (lo*lo dropped). YB f32 bounce -> coalesced store.
__global__ __launch_bounds__(512, 4) void k_conv(const float* __restrict__ agg,
                                                 const unsigned short* __restrict__ whi,
                                                 const unsigned short* __restrict__ wlo,
                                                 const float* __restrict__ bias,
                                                 float* __restrict__ out) {
    __shared__ __align__(16) char smem[32768];  // XH 8K | XL 8K | YB 16K
    const int XH = 0, XL = 8192, YB = 16384;
    int r0 = blockIdx.x * TILE_R;
    int rows = min(TILE_R, N_NODES - r0);
    int tid = threadIdx.x;
    int wv = tid >> 6, lane = tid & 63;
    int lhi = lane >> 4, llo = lane & 15;
    int sr = tid >> 4, ss = tid & 15;
    f32x4 zero = {0.f, 0.f, 0.f, 0.f};

    // W fragments (registers): wave wv owns out-cols [wv*16,+16), c = wv*16+llo
    int c = wv * 16 + llo;
    s16x8 whf[4], wlf[4];
#pragma unroll
    for (int ks = 0; ks < 4; ks++) {
        size_t u = ((size_t)(ks * 128 + c) * 4 + lhi) * 8;
        whf[ks] = *(const s16x8*)(whi + u);
        wlf[ks] = *(const s16x8*)(wlo + u);
    }

    // stage X hi/lo (row sr, 8 floats at ss*8)
    {
        float v[8];
        if (sr < rows) {
            const float4* xr = (const float4*)(agg + (size_t)(r0 + sr) * D + ss * 8);
            *(float4*)(v + 0) = xr[0];
            *(float4*)(v + 4) = xr[1];
        } else {
#pragma unroll
            for (int k = 0; k < 8; k++) v[k] = 0.f;
        }
        unsigned short hb[8] __attribute__((aligned(16)));
        unsigned short lb[8] __attribute__((aligned(16)));
#pragma unroll
        for (int k = 0; k < 8; k++) {
            unsigned short h = f2bf(v[k]);
            hb[k] = h;
            lb[k] = f2bf(v[k] - bf2f(h));
        }
        int swz = (sr & 7) << 4;
        *(int4*)(smem + XH + sr * 256 + ((ss * 16) ^ swz)) = *(int4*)hb;
        *(int4*)(smem + XL + sr * 256 + ((ss * 16) ^ swz)) = *(int4*)lb;
    }
    __syncthreads();

    // GEMM: acc[mt] over row-groups; 3 split-products per (ks, mt)
    f32x4 acc[2];
    acc[0] = zero; acc[1] = zero;
#pragma unroll
    for (int ks = 0; ks < 4; ks++) {
        int kb = ks * 64 + lhi * 16;
        int sw0 = (llo & 7) << 4;
        s16x8 ah0 = *(const s16x8*)(smem + XH + llo * 256        + (kb ^ sw0));
        s16x8 ah1 = *(const s16x8*)(smem + XH + (llo + 16) * 256 + (kb ^ sw0));
        s16x8 al0 = *(const s16x8*)(smem + XL + llo * 256        + (kb ^ sw0));
        s16x8 al1 = *(const s16x8*)(smem + XL + (llo + 16) * 256 + (kb ^ sw0));
        acc[0] = __builtin_amdgcn_mfma_f32_16x16x32_bf16(ah0, whf[ks], acc[0], 0, 0, 0);
        acc[0] = __builtin_amdgcn_mfma_f32_16x16x32_bf16(ah0, wlf[ks], acc[0], 0, 0, 0);
        acc[0] = __builtin_amdgcn_mfma_f32_16x16x32_bf16(al0, whf[ks], acc[0], 0, 0, 0);
        acc[1] = __builtin_amdgcn_mfma_f32_16x16x32_bf16(ah1, whf[ks], acc[1], 0, 0, 0);
        acc[1] = __builtin_amdgcn_mfma_f32_16x16x32_bf16(ah1, wlf[ks], acc[1], 0, 0, 0);
        acc[1] = __builtin_amdgcn_mfma_f32_16x16x32_bf16(al1, whf[ks], acc[1], 0, 0, 0);
    }

    // bias + YB (f32, swizzled)
    {
        float bb = bias[c];
#pragma unroll
        for (int mt = 0; mt < 2; mt++)
#pragma unroll
            for (int r = 0; r < 4; r++) {
                int m = mt * 16 + lhi * 4 + r;
                *(float*)(smem + YB + m * 512 + ((c * 4) ^ ((m & 7) << 4))) = acc[mt][r] + bb;
            }
    }
    __syncthreads();

    // coalesced out write: row sr, 32B chunk ss
    if (sr < rows) {
        int swz = (sr & 7) << 4;
        int4 a = *(const int4*)(smem + YB + sr * 512 + ((ss * 32) ^ swz));
        int4 b = *(const int4*)(smem + YB + sr * 512 + ((ss * 32 + 16) ^ swz));
        float4* op = (float4*)(out + (size_t)(r0 + sr) * D + ss * 8);
        op[0] = *(float4*)&a;
        op[1] = *(float4*)&b;
    }
}

// ---------------- gate v7 FAST: plain-f32 scores + gap test; ambiguous -> redo list --
__global__ __launch_bounds__(256, 4) void k_gate(const float* __restrict__ nf,
                                                 const float* __restrict__ gW,
                                                 const float* __restrict__ gb,
                                                 float* __restrict__ gwout,
                                                 int* __restrict__ topi,
                                                 int* __restrict__ rcnt,
                                                 int* __restrict__ redo) {
    __shared__ float Wl[D * NE];       // 32 KB, layout [k][e]
    __shared__ float xsh[16 * D];      // 8 KB
    for (int i = threadIdx.x; i < D * NE / 4; i += 256)
        ((float4*)Wl)[i] = ((const float4*)gW)[i];
    int t_base = blockIdx.x * 16;
    for (int i = threadIdx.x; i < 16 * 32; i += 256) {
        int r = i >> 5, q = i & 31;
        ((float4*)(xsh + r * D))[q] =
            ((const float4*)(nf + (size_t)(t_base + r) * D))[q];
    }
    __syncthreads();

    int wave = threadIdx.x >> 6;
    int lane = threadIdx.x & 63;      // lane = expert
    int t0 = t_base + wave * 4;
    const float* xw = xsh + wave * 4 * D;

    float a0 = 0.f, a1 = 0.f, a2 = 0.f, a3 = 0.f;
#pragma unroll 4
    for (int k4 = 0; k4 < D; k4 += 4) {
        float x0[4], x1[4], x2[4], x3[4];
        *(float4*)x0 = *(const float4*)(xw + k4);
        *(float4*)x1 = *(const float4*)(xw + D + k4);
        *(float4*)x2 = *(const float4*)(xw + 2 * D + k4);
        *(float4*)x3 = *(const float4*)(xw + 3 * D + k4);
#pragma unroll
        for (int u = 0; u < 4; u++) {
            float w = Wl[(k4 + u) * NE + lane];
            a0 = fmaf(x0[u], w, a0);
            a1 = fmaf(x1[u], w, a1);
            a2 = fmaf(x2[u], w, a2);
            a3 = fmaf(x3[u], w, a3);
        }
    }
    float gbf = gb[lane];
    float af[4] = {a0 + gbf, a1 + gbf, a2 + gbf, a3 + gbf};

    const float TAU = 2e-4f;   // >> plain-f32 dot error (~5e-6 realistic)

#pragma unroll
    for (int j = 0; j < 4; j++) {
        float sf = (j == 0) ? af[0] : (j == 1) ? af[1] : (j == 2) ? af[2] : af[3];
        int t = t0 + j;

        float v1 = sf; int i1 = lane;
#pragma unroll
        for (int off = 32; off; off >>= 1) {
            float ov = __shfl_xor(v1, off);
            int   oi = __shfl_xor(i1, off);
            if (ov > v1 || (ov == v1 && oi < i1)) { v1 = ov; i1 = oi; }
        }
        float v2 = (lane == i1) ? -INFINITY : sf; int i2 = lane;
#pragma unroll
        for (int off = 32; off; off >>= 1) {
            float ov = __shfl_xor(v2, off);
            int   oi = __shfl_xor(i2, off);
            if (ov > v2 || (ov == v2 && oi < i2)) { v2 = ov; i2 = oi; }
        }
        float v3 = (lane == i1 || lane == i2) ? -INFINITY : sf;
#pragma unroll
        for (int off = 32; off; off >>= 1)
            v3 = fmaxf(v3, __shfl_xor(v3, off));

        if (lane == 0) {
            float dd = v2 - v1;
            float e2 = expf(dd);
            float g0 = 1.0f / (1.0f + e2);
            gwout[2 * t] = g0;
            gwout[2 * t + 1] = e2 * g0;
            topi[2 * t] = i1;
            topi[2 * t + 1] = i2;
            if ((v1 - v2 <= TAU) || (v2 - v3 <= TAU)) {
                int slot = atomicAdd(rcnt, 1);
                redo[slot] = t;
            }
        }
    }
}

// ---------------- gate FIX: comp-f32 rescore of ambiguous tokens (rare) ------------
__global__ __launch_bounds__(256) void k_gfix(const float* __restrict__ nf,
                                              const float* __restrict__ gW,
                                              const float* __restrict__ gb,
                                              const int* __restrict__ rcnt,
                                              const int* __restrict__ redo,
                                              float* __restrict__ gwout,
                                              int* __restrict__ topi) {
    int nredo = *rcnt;
    int lane = threadIdx.x & 63;
    int widx = blockIdx.x * 4 + (threadIdx.x >> 6);
    float gbf = gb[lane];
    for (int i = widx; i < nredo; i += gridDim.x * 4) {
        int t = redo[i];
        const float* xr = nf + (size_t)t * D;
        float s = 0.f, c = 0.f;
        for (int k = 0; k < D; k++)
            DOT2(s, c, xr[k], gW[k * NE + lane]);
        TSUM(s, c, gbf);
        float vv = s + c, rr = (s - vv) + c;

        float a1v = vv, a1r = rr; int i1 = lane;
#pragma unroll
        for (int off = 32; off; off >>= 1) {
            float ov = __shfl_xor(a1v, off);
            float orr = __shfl_xor(a1r, off);
            int   oi = __shfl_xor(i1, off);
            bool gt = (ov > a1v) || (ov == a1v && (orr > a1r || (orr == a1r && oi < i1)));
            if (gt) { a1v = ov; a1r = orr; i1 = oi; }
        }
        bool ex = (lane == i1);
        float a2v = ex ? -INFINITY : vv;
        float a2r = ex ? 0.f : rr;
        int i2 = lane;
#pragma unroll
        for (int off = 32; off; off >>= 1) {
            float ov = __shfl_xor(a2v, off);
            float orr = __shfl_xor(a2r, off);
            int   oi = __shfl_xor(i2, off);
            bool gt = (ov > a2v) || (ov == a2v && (orr > a2r || (orr == a2r && oi < i2)));
            if (gt) { a2v = ov; a2r = orr; i2 = oi; }
        }

        if (lane == 0) {
            float dd = (a2v - a1v) + (a2r - a1r);
            float e2 = expf(dd);
            float g0 = 1.0f / (1.0f + e2);
            gwout[2 * t] = g0;
            gwout[2 * t + 1] = e2 * g0;
            topi[2 * t] = i1;
            topi[2 * t + 1] = i2;
        }
    }
}

// ---------------- dispatch: parallel two-level counting scatter ----------------
__global__ __launch_bounds__(1024) void k_disp(const int* __restrict__ topi,
                                               int* __restrict__ cnt,
                                               int* __restrict__ plist) {
    __shared__ int lcnt[NE];
    __shared__ int lbase[NE];
    int tid = threadIdx.x;
    if (tid < NE) lcnt[tid] = 0;
    __syncthreads();
    int p = blockIdx.x * 1024 + tid;
    int e = 0, lr = 0;
    bool act = (p < NPAIR);
    if (act) {
        e = topi[p];
        lr = atomicAdd(&lcnt[e], 1);
    }
    __syncthreads();
    if (tid < NE) {
        int n = lcnt[tid];
        lbase[tid] = n ? atomicAdd(&cnt[tid], n) : 0;
    }
    __syncthreads();
    if (act) {
        int slot = lbase[e] + lr;
        if (slot < CAP) plist[e * CAP + slot] = p;
    }
}

// ---------------- weight convert: f32 -> bf16 fragments, LINEAR layout -------------
__global__ __launch_bounds__(256) void k_wconv(const float* __restrict__ W1,
                                               const float* __restrict__ W2,
                                               unsigned short* __restrict__ w1c,
                                               unsigned short* __restrict__ w2c) {
    int gid = blockIdx.x * 256 + threadIdx.x;
    const int NW1 = NE * 4 * 256 * 4;            // 262144
    if (gid < NW1) {
        int lhi = gid & 3, h = (gid >> 2) & 255, ks = (gid >> 10) & 3, e = gid >> 12;
        int d0 = ks * 32 + lhi * 8;
        unsigned short v[8] __attribute__((aligned(16)));
#pragma unroll
        for (int j = 0; j < 8; j++)
            v[j] = f2bf(W1[((size_t)e * D + d0 + j) * H + h]);
        *(int4*)(w1c + (size_t)gid * 8) = *(int4*)v;
    } else {
        int g = gid - NW1;
        int lhi = g & 3, d = (g >> 2) & 127, ks = (g >> 9) & 7, e = g >> 12;
        int h0 = ks * 32 + lhi * 8;
        unsigned short v[8] __attribute__((aligned(16)));
#pragma unroll
        for (int j = 0; j < 8; j++)
            v[j] = f2bf(W2[((size_t)e * H + h0 + j) * D + d]);
        *(int4*)(w2c + (size_t)g * 8) = *(int4*)v;
    }
}

// ---------------- MoE FFN v8: reg-W + YB bounce + fast gelu + 3 barriers/tile ------
__global__ __launch_bounds__(512, 4) void k_moe(const float* __restrict__ nf,
                                                const int* __restrict__ cnt,
                                                const int* __restrict__ plist,
                                                const unsigned short* __restrict__ w1c,
                                                const float* __restrict__ b1,
                                                const unsigned short* __restrict__ w2c,
                                                const float* __restrict__ b2,
                                                const float* __restrict__ gwbuf,
                                                unsigned short* __restrict__ ybuf) {
    __shared__ __align__(16) char smem[32768];
    const int XA = 0, HL = 8192, YB = 24576;
    int e = blockIdx.x & 63;         // same-expert blocks on same XCD (L2 W reuse)
    int q = blockIdx.x >> 6;
    int n = min(cnt[e], CAP);
    int ntile = (n + TILE_R - 1) / TILE_R;
    if (q >= ntile) return;
    int tid = threadIdx.x;

    int wv = tid >> 6, lane = tid & 63;
    int lhi = lane >> 4, llo = lane & 15;
    int sr = tid >> 4, ss = tid & 15;   // staging role: row, 16B-chunk
    f32x4 zero = {0.f, 0.f, 0.f, 0.f};

    // ---- load W fragments into registers (once per block; coalesced 1KB/wave) ----
    s16x8 w1f[4][2];
#pragma unroll
    for (int ks = 0; ks < 4; ks++)
#pragma unroll
        for (int nt = 0; nt < 2; nt++) {
            int h = wv * 32 + nt * 16 + llo;
            w1f[ks][nt] = *(const s16x8*)(w1c +
                ((size_t)e * 4096 + (ks * 256 + h) * 4 + lhi) * 8);
        }
    s16x8 w2f[8];
    {
        int d = wv * 16 + llo;
#pragma unroll
        for (int ks = 0; ks < 8; ks++)
            w2f[ks] = *(const s16x8*)(w2c +
                ((size_t)e * 4096 + (ks * 128 + d) * 4 + lhi) * 8);
    }

    float vals[8];
    auto loadt = [&](int rt2, float* v) {
        bool ok = false;
        if (rt2 < ntile) {
            int rows2 = min(TILE_R, n - rt2 * TILE_R);
            if (sr < rows2) {
                int p = plist[e * CAP + rt2 * TILE_R + sr];
                const float4* xr = (const float4*)(nf + (size_t)(p >> 1) * D + ss * 8);
                *(float4*)(v + 0) = xr[0];
                *(float4*)(v + 4) = xr[1];
                ok = true;
            }
        }
        if (!ok) {
#pragma unroll
            for (int k = 0; k < 8; k++) v[k] = 0.f;
        }
    };
    loadt(q, vals);   // prefetch first tile (overlaps W-frag loads)

    for (int rt = q; rt < ntile; rt += BQ) {
        int r0 = rt * TILE_R;
        int rows = min(TILE_R, n - r0);

        // ---- write XA from prefetched regs (bf16, swizzled) ----
        {
            unsigned short hb[8] __attribute__((aligned(16)));
#pragma unroll
            for (int k = 0; k < 8; k++) hb[k] = f2bf(vals[k]);
            *(int4*)(smem + XA + sr * 256 + ((ss * 16) ^ ((sr & 7) << 4))) = *(int4*)hb;
        }
        __syncthreads();   // XA ready

        loadt(rt + BQ, vals);   // issue next tile's loads; latency hidden under compute

        // ---- GEMM1: H[32x256] = X @ W1; wave wv owns h-cols [wv*32, +32) ----
        f32x4 acc1[2][2];
#pragma unroll
        for (int mt = 0; mt < 2; mt++)
#pragma unroll
            for (int nt = 0; nt < 2; nt++) acc1[mt][nt] = zero;
#pragma unroll
        for (int ks = 0; ks < 4; ks++) {
            int kb = ks * 64 + lhi * 16;
            s16x8 a0 = *(const s16x8*)(smem + XA + llo * 256        + (kb ^ ((llo & 7) << 4)));
            s16x8 a1 = *(const s16x8*)(smem + XA + (llo + 16) * 256 + (kb ^ ((llo & 7) << 4)));
#pragma unroll
            for (int nt = 0; nt < 2; nt++) {
                acc1[0][nt] = __builtin_amdgcn_mfma_f32_16x16x32_bf16(a0, w1f[ks][nt], acc1[0][nt], 0, 0, 0);
                acc1[1][nt] = __builtin_amdgcn_mfma_f32_16x16x32_bf16(a1, w1f[ks][nt], acc1[1][nt], 0, 0, 0);
            }
        }

        // ---- fast gelu -> HL (bf16, swizzled) ----
#pragma unroll
        for (int mt = 0; mt < 2; mt++)
#pragma unroll
            for (int nt = 0; nt < 2; nt++)
#pragma unroll
                for (int r = 0; r < 4; r++) {
                    int m = mt * 16 + lhi * 4 + r;
                    int hc = wv * 32 + nt * 16 + llo;
                    float hv = acc1[mt][nt][r] + b1[e * H + hc];
                    *(unsigned short*)(smem + HL + m * 512 + ((hc * 2) ^ ((m & 7) << 4))) =
                        f2bf(gelu_f(hv));
                }
        __syncthreads();   // HL ready

        // ---- GEMM2: Y[32x128] = H @ W2; wave wv owns d-cols [wv*16, +16) ----
        f32x4 acc2[2];
        acc2[0] = zero; acc2[1] = zero;
#pragma unroll
        for (int ks = 0; ks < 8; ks++) {
            int kb = ks * 64 + lhi * 16;
            s16x8 a0 = *(const s16x8*)(smem + HL + llo * 512        + (kb ^ ((llo & 7) << 4)));
            s16x8 a1 = *(const s16x8*)(smem + HL + (llo + 16) * 512 + (kb ^ ((llo & 7) << 4)));
            acc2[0] = __builtin_amdgcn_mfma_f32_16x16x32_bf16(a0, w2f[ks], acc2[0], 0, 0, 0);
            acc2[1] = __builtin_amdgcn_mfma_f32_16x16x32_bf16(a1, w2f[ks], acc2[1], 0, 0, 0);
        }

        // ---- stage y (acc2 + b2) into YB (bf16, swizzled) ----
        {
            int d = wv * 16 + llo;
            float bb = b2[e * D + d];
#pragma unroll
            for (int mt = 0; mt < 2; mt++)
#pragma unroll
                for (int r = 0; r < 4; r++) {
                    int m = mt * 16 + lhi * 4 + r;
                    *(unsigned short*)(smem + YB + m * 256 + ((d * 2) ^ ((m & 7) << 4))) =
                        f2bf(acc2[mt][r] + bb);
                }
        }
        __syncthreads();   // YB ready (also fences XA/HL reads for next iter)

        // ---- coalesced ybuf write: thread owns (row sr, 16B chunk ss) ----
        if (sr < rows) {
            int p = plist[e * CAP + r0 + sr];
            float gw = gwbuf[p];
            unsigned short yv[8] __attribute__((aligned(16)));
            *(int4*)yv = *(const int4*)(smem + YB + sr * 256 + ((ss * 16) ^ ((sr & 7) << 4)));
#pragma unroll
            for (int k = 0; k < 8; k++) yv[k] = f2bf(gw * bf2f(yv[k]));
            *(int4*)(ybuf + (size_t)p * D + ss * 8) = *(int4*)yv;
        }
    }
}

// ---------------- BatchNorm: bnpart also writes z = nf + y0 + y1 into nf (in place) --
__global__ __launch_bounds__(256) void k_bnpart(float* __restrict__ nf,
                                                const unsigned short* __restrict__ ybuf,
                                                double* __restrict__ part) {
    int blk = blockIdx.x;
    int col = threadIdx.x & 127;
    int half = threadIdx.x >> 7;
    int r0 = blk * BN_ROWS;
    int r1 = min(r0 + BN_ROWS, N_NODES);
    double s = 0.0, ss = 0.0;
    for (int r = r0 + half; r < r1; r += 2) {
        float v32 = nf[(size_t)r * D + col]
                  + bf2f(ybuf[(size_t)(2 * r) * D + col])
                  + bf2f(ybuf[(size_t)(2 * r + 1) * D + col]);
        nf[(size_t)r * D + col] = v32;        // z for bnapply (nf dead after this)
        double v = (double)v32;
        s += v; ss += v * v;
    }
    __shared__ double sh[2][256];
    sh[0][threadIdx.x] = s; sh[1][threadIdx.x] = ss;
    __syncthreads();
    if (threadIdx.x < 128) {
        part[(size_t)blk * 256 + col]       = sh[0][col] + sh[0][col + 128];
        part[(size_t)blk * 256 + 128 + col] = sh[1][col] + sh[1][col + 128];
    }
}

__global__ void k_bnstats(const double* __restrict__ part,
                          const float* __restrict__ gamma,
                          float* __restrict__ stats) {
    int col = threadIdx.x;   // 128 threads
    double s = 0.0, ss = 0.0;
    for (int b = 0; b < BN_NBLK; b++) {
        s  += part[(size_t)b * 256 + col];
        ss += part[(size_t)b * 256 + 128 + col];
    }
    double mean = s / (double)N_NODES;
    double var = ss / (double)N_NODES - mean * mean;
    stats[col] = (float)mean;
    stats[128 + col] = gamma[col] * (float)(1.0 / sqrt(var + 1e-5));
}

// ---------------- bnapply v2: in-place on z (out), float4 ----------------
__global__ __launch_bounds__(256) void k_bnapply(const float* __restrict__ stats,
                                                 const float* __restrict__ beta,
                                                 float* __restrict__ out) {
    int i = blockIdx.x * blockDim.x + threadIdx.x;   // float4 index
    if (i >= N_NODES * (D / 4)) return;
    int q = i & 31;
    int c0 = q * 4;
    float4 z = ((const float4*)out)[i];
    float4 r;
    r.x = (z.x - stats[c0 + 0]) * stats[128 + c0 + 0] + beta[c0 + 0];
    r.y = (z.y - stats[c0 + 1]) * stats[128 + c0 + 1] + beta[c0 + 1];
    r.z = (z.z - stats[c0 + 2]) * stats[128 + c0 + 2] + beta[c0 + 2];
    r.w = (z.w - stats[c0 + 3]) * stats[128 + c0 + 3] + beta[c0 + 3];
    ((float4*)out)[i] = r;
}

// ---------------- launch ----------------
extern "C" void kernel_launch(void* const* d_in, const int* in_sizes, int n_in,
                              void* d_out, int out_size, void* d_ws, size_t ws_size,
                              hipStream_t stream) {
    const float* feats   = (const float*)d_in[0];
    const int*   esrc    = (const int*)d_in[1];
    const int*   edst    = (const int*)d_in[2];
    const float* W_conv  = (const float*)d_in[3];
    const float* b_conv  = (const float*)d_in[4];
    const float* gate_W  = (const float*)d_in[5];
    const float* gate_b  = (const float*)d_in[6];
    const float* W1      = (const float*)d_in[7];
    const float* b1      = (const float*)d_in[8];
    const float* W2      = (const float*)d_in[9];
    const float* b2      = (const float*)d_in[10];
    const float* bn_g    = (const float*)d_in[11];
    const float* bn_b    = (const float*)d_in[12];
    float* out = (float*)d_out;   // doubles as new_feats / z storage

    char* ws = (char*)d_ws;
    size_t off = 0;
    auto rup = [](size_t x) { return (x + 255) & ~(size_t)255; };
    int*    deg    = (int*)   (ws + off); off += rup((size_t)N_NODES * 4);
    int*    cursor = (int*)   (ws + off); off += rup((size_t)N_NODES * 4);
    int*    cnt    = (int*)   (ws + off); off += 256;
    int*    rcnt   = (int*)   (ws + off); off += 256;
    size_t zero_bytes = off;                 // deg + cursor + cnt + rcnt (~400 KB)
    float*  invs   = (float*) (ws + off); off += rup((size_t)N_NODES * 4);
    int*    rowptr = (int*)   (ws + off); off += rup((size_t)(N_NODES + 1) * 4);
    int*    csr    = (int*)   (ws + off); off += rup((size_t)N_EDGES * 4);
    float*  gwbuf  = (float*) (ws + off); off += rup((size_t)NPAIR * 4);
    int*    topi   = (int*)   (ws + off); off += rup((size_t)NPAIR * 4);
    int*    redo   = (int*)   (ws + off); off += rup((size_t)N_NODES * 4);
    int*    plist  = (int*)   (ws + off); off += rup((size_t)NE * CAP * 4);
    double* part   = (double*)(ws + off); off += rup((size_t)BN_NBLK * 256 * 8);
    float*  stats  = (float*) (ws + off); off += 1024;
    unsigned short* w1c  = (unsigned short*)(ws + off); off += rup((size_t)NE * D * H * 2); // 4 MB
    unsigned short* w2c  = (unsigned short*)(ws + off); off += rup((size_t)NE * D * H * 2); // 4 MB
    unsigned short* wchi = (unsigned short*)(ws + off); off += rup((size_t)D * D * 2);      // 32 KB
    unsigned short* wclo = (unsigned short*)(ws + off); off += rup((size_t)D * D * 2);      // 32 KB
    unsigned short* ybuf = (unsigned short*)(ws + off); off += rup((size_t)NPAIR * D * 2);  // 25.6 MB
    float*  agg    = (float*)ybuf;   // lifetime-disjoint alias (agg dead before k_moe writes ybuf)
    (void)ws_size; (void)in_sizes; (void)n_in; (void)out_size;

    hipMemsetAsync(d_ws, 0, zero_bytes, stream);

    k_wconv<<<2 * NE * 4 * 256 * 4 / 256, 256, 0, stream>>>(W1, W2, w1c, w2c);
    k_wcsplit<<<8, 256, 0, stream>>>(W_conv, wchi, wclo);
    k_deg<<<(N_EDGES + 255) / 256, 256, 0, stream>>>(edst, deg);
    k_invsqrt<<<(N_NODES + 255) / 256, 256, 0, stream>>>(deg, invs);
    k_scan<<<1, 1024, 0, stream>>>(deg, rowptr);
    k_scatter<<<(N_EDGES + 255) / 256, 256, 0, stream>>>(esrc, edst, rowptr, cursor, csr);
    k_gather<<<(N_NODES + 3) / 4, 256, 0, stream>>>(feats, rowptr, csr, invs, agg);
    k_conv<<<(N_NODES + TILE_R - 1) / TILE_R, 512, 0, stream>>>(agg, wchi, wclo, b_conv, out);
    k_gate<<<N_NODES / 16, 256, 0, stream>>>(out, gate_W, gate_b, gwbuf, topi, rcnt, redo);
    k_gfix<<<128, 256, 0, stream>>>(out, gate_W, gate_b, rcnt, redo, gwbuf, topi);
    k_disp<<<(NPAIR + 1023) / 1024, 1024, 0, stream>>>(topi, cnt, plist);
    k_moe<<<NE * BQ, 512, 0, stream>>>(out, cnt, plist, w1c, b1, w2c, b2, gwbuf, ybuf);
    k_bnpart<<<BN_NBLK, 256, 0, stream>>>(out, ybuf, part);
    k_bnstats<<<1, 128, 0, stream>>>(part, bn_g, stats);
    k_bnapply<<<(N_NODES * (D / 4) + 255) / 256, 256, 0, stream>>>(stats, bn_b, out);
}

// Round 19
// 402.738 us; speedup vs baseline: 1.6069x; 1.0372x over previous
//
#include <hip/hip_runtime.h>
#include <math.h>

#define N_NODES 50000
#define N_EDGES 500000
#define D 128
#define H 256
#define NE 64
#define TOPK 2
#define NPAIR (N_NODES * TOPK)
#define CAP 3126               // 2 * ceil(100000/64)
#define TILE_R 32
#define BQ 16                  // blocks per expert in k_moe (1024 blocks = 4/CU)
#define BN_NBLK 128
#define BN_ROWS ((N_NODES + BN_NBLK - 1) / BN_NBLK) // 391

typedef __attribute__((ext_vector_type(8))) short s16x8;
typedef __attribute__((ext_vector_type(4))) float f32x4;

__device__ __forceinline__ unsigned short f2bf(float f) {
    unsigned u = __float_as_uint(f);
    unsigned r = (u + 0x7fffu + ((u >> 16) & 1u)) >> 16;
    return (unsigned short)r;
}
__device__ __forceinline__ float bf2f(unsigned short u) {
    return __uint_as_float(((unsigned)u) << 16);
}

// gelu(x) = 0.5x(1+erf(x/sqrt2)); erf via A&S 7.1.26 (|err|<=1.5e-7 << bf16 quant)
__device__ __forceinline__ float gelu_f(float x) {
    float u = 0.70710678118654752f * x;
    float au = fabsf(u);
    float t = 1.0f / fmaf(0.3275911f, au, 1.0f);
    float poly = t * fmaf(t, fmaf(t, fmaf(t, fmaf(t, 1.061405429f, -1.453152027f),
                      1.421413741f), -0.284496736f), 0.254829592f);
    float e = __expf(-u * u);
    float erfa = 1.0f - poly * e;
    float erfu = copysignf(erfa, u);
    return 0.5f * x * (1.0f + erfu);
}

// Compensated f32: TwoProd (mul + fma residual) + branch-free TwoSum.
#define DOT2(s, c, xx, ww) {                      \
    float p_ = (xx) * (ww);                       \
    float e1_ = fmaf((xx), (ww), -p_);            \
    float t_ = (s) + p_;                          \
    float z_ = t_ - (s);                          \
    float e2_ = ((s) - (t_ - z_)) + (p_ - z_);    \
    (s) = t_;                                     \
    (c) += e1_ + e2_; }

#define TSUM(s, c, pp) {                          \
    float p_ = (pp);                              \
    float t_ = (s) + p_;                          \
    float z_ = t_ - (s);                          \
    float e2_ = ((s) - (t_ - z_)) + (p_ - z_);    \
    (s) = t_;                                     \
    (c) += e2_; }

// Kahan add: 4 ops; order-variation ~1e-7 rel (covered by gate TAU band)
#define KAH(s, c, pp) {                           \
    float y_ = (pp) - (c);                        \
    float t_ = (s) + y_;                          \
    (c) = (t_ - (s)) - y_;                        \
    (s) = t_; }

// ---------------- degree count ----------------
__global__ void k_deg(const int* __restrict__ dst, int* __restrict__ deg) {
    int i = blockIdx.x * blockDim.x + threadIdx.x;
    if (i < N_EDGES) atomicAdd(&deg[dst[i]], 1);
}

__global__ void k_invsqrt(const int* __restrict__ deg, float* __restrict__ invs) {
    int i = blockIdx.x * blockDim.x + threadIdx.x;
    if (i < N_NODES) {
        double d = (double)deg[i];
        if (d < 1.0) d = 1.0;
        invs[i] = (float)(1.0 / sqrt(d));
    }
}

// ---------------- exclusive scan of deg -> rowptr ----------------
__global__ __launch_bounds__(1024) void k_scan(const int* __restrict__ deg,
                                               int* __restrict__ rowptr) {
    __shared__ int sh[1024];
    int t = threadIdx.x;
    const int chunk = (N_NODES + 1023) / 1024;   // 49
    int lo = t * chunk;
    int hi = min(lo + chunk, N_NODES);
    int s = 0;
    for (int i = lo; i < hi; i++) s += deg[i];
    sh[t] = s;
    __syncthreads();
    for (int off = 1; off < 1024; off <<= 1) {
        int v = (t >= off) ? sh[t - off] : 0;
        __syncthreads();
        sh[t] += v;
        __syncthreads();
    }
    int run = (t == 0) ? 0 : sh[t - 1];
    for (int i = lo; i < hi; i++) { rowptr[i] = run; run += deg[i]; }
    if (t == 1023) rowptr[N_NODES] = run;
}

// ---------------- scatter edges into CSR ----------------
__global__ void k_scatter(const int* __restrict__ src, const int* __restrict__ dst,
                          const int* __restrict__ rowptr, int* __restrict__ cursor,
                          int* __restrict__ csr) {
    int e = blockIdx.x * blockDim.x + threadIdx.x;
    if (e >= N_EDGES) return;
    int d = dst[e];
    int pos = atomicAdd(&cursor[d], 1);
    csr[rowptr[d] + pos] = src[e];
}

// ---------------- per-node gather: Kahan f32, 4-edge unroll (4-way MLP) -----------
__global__ __launch_bounds__(256) void k_gather(const float* __restrict__ feats,
                                                const int* __restrict__ rowptr,
                                                const int* __restrict__ csr,
                                                const float* __restrict__ invs,
                                                float* __restrict__ agg) {
    int node = blockIdx.x * 4 + (threadIdx.x >> 6);
    if (node >= N_NODES) return;
    int lane = threadIdx.x & 63;
    int beg = rowptr[node], end = rowptr[node + 1];
    float wd = invs[node];
    float sx = 0.f, cx = 0.f, sy = 0.f, cy = 0.f;
    int i = beg;
    for (; i + 4 <= end; i += 4) {
        int s0 = csr[i], s1 = csr[i + 1], s2 = csr[i + 2], s3 = csr[i + 3];
        float n0 = invs[s0] * wd, n1 = invs[s1] * wd;
        float n2 = invs[s2] * wd, n3 = invs[s3] * wd;
        float2 f0 = ((const float2*)(feats + (size_t)s0 * D))[lane];
        float2 f1 = ((const float2*)(feats + (size_t)s1 * D))[lane];
        float2 f2 = ((const float2*)(feats + (size_t)s2 * D))[lane];
        float2 f3 = ((const float2*)(feats + (size_t)s3 * D))[lane];
        KAH(sx, cx, n0 * f0.x); KAH(sy, cy, n0 * f0.y);
        KAH(sx, cx, n1 * f1.x); KAH(sy, cy, n1 * f1.y);
        KAH(sx, cx, n2 * f2.x); KAH(sy, cy, n2 * f2.y);
        KAH(sx, cx, n3 * f3.x); KAH(sy, cy, n3 * f3.y);
    }
    for (; i < end; i++) {
        int s = csr[i];
        float nrm = invs[s] * wd;
        float2 f = ((const float2*)(feats + (size_t)s * D))[lane];
        KAH(sx, cx, nrm * f.x);
        KAH(sy, cy, nrm * f.y);
    }
    ((float2*)(agg + (size_t)node * D))[lane] = make_float2(sx, sy);
}

// ---------------- W_conv split: f32 -> (hi,lo) bf16 fragments ----------------------
__global__ __launch_bounds__(256) void k_wcsplit(const float* __restrict__ W,
                                                 unsigned short* __restrict__ whi,
                                                 unsigned short* __restrict__ wlo) {
    int u = blockIdx.x * 256 + threadIdx.x;   // 0..2047
    int lhi = u & 3, c = (u >> 2) & 127, ks = u >> 9;
    int k0 = ks * 32 + lhi * 8;
    unsigned short vh[8] __attribute__((aligned(16)));
    unsigned short vl[8] __attribute__((aligned(16)));
#pragma unroll
    for (int j = 0; j < 8; j++) {
        float x = W[(size_t)(k0 + j) * D + c];
        unsigned short h = f2bf(x);
        vh[j] = h;
        vl[j] = f2bf(x - bf2f(h));
    }
    *(int4*)(whi + (size_t)u * 8) = *(int4*)vh;
    *(int4*)(wlo + (size_t)u * 8) = *(int4*)vl;
}

// ---------------- gate_W split: f32 [128][64] -> (hi,lo) fragments -----------------
// unit u = (ks*64 + e)*4 + lhi = ks*256 + e*4 + lhi, k = ks*32+lhi*8+j
__global__ __launch_bounds__(256) void k_wgsplit(const float* __restrict__ gW,
                                                 unsigned short* __restrict__ ghi,
                                                 unsigned short* __restrict__ glo) {
    int u = blockIdx.x * 256 + threadIdx.x;   // 0..1023
    int lhi = u & 3, e = (u >> 2) & 63, ks = u >> 8;
    int k0 = ks * 32 + lhi * 8;
    unsigned short vh[8] __attribute__((aligned(16)));
    unsigned short vl[8] __attribute__((aligned(16)));
#pragma unroll
    for (int j = 0; j < 8; j++) {
        float x = gW[(size_t)(k0 + j) * NE + e];
        unsigned short h = f2bf(x);
        vh[j] = h;
        vl[j] = f2bf(x - bf2f(h));
    }
    *(int4*)(ghi + (size_t)u * 8) = *(int4*)vh;
    *(int4*)(glo + (size_t)u * 8) = *(int4*)vl;
}

// ---------------- fused conv GEMM + gate (split-bf16 MFMA, f32-class error) --------
// Phase A: out[32x128] = X @ Wc + b (as r17 k_conv).
// Phase B: out-tile split hi/lo into XH/XL (X dead); scores[32x64] = out @ gW via
//          waves 0-3; +gb -> SC (LDS). err ~2e-6 << TAU -> gap-test semantics intact.
// Phase C: all 8 waves: top-2/top-3 + gap test; ambiguous -> redo list (k_gfix).
__global__ __launch_bounds__(512, 4) void k_convgate(
        const float* __restrict__ agg,
        const unsigned short* __restrict__ whi, const unsigned short* __restrict__ wlo,
        const float* __restrict__ bias,
        const unsigned short* __restrict__ ghi, const unsigned short* __restrict__ glo,
        const float* __restrict__ gb,
        float* __restrict__ out, float* __restrict__ gwout, int* __restrict__ topi,
        int* __restrict__ rcnt, int* __restrict__ redo) {
    __shared__ __align__(16) char smem[32768];  // XH 8K | XL 8K | YB 16K (SC = YB+0, 8K, after out store)
    const int XH = 0, XL = 8192, YB = 16384, SC = 16384;
    int r0 = blockIdx.x * TILE_R;
    int rows = min(TILE_R, N_NODES - r0);
    int tid = threadIdx.x;
    int wv = tid >> 6, lane = tid & 63;
    int lhi = lane >> 4, llo = lane & 15;
    int sr = tid >> 4, ss = tid & 15;
    f32x4 zero = {0.f, 0.f, 0.f, 0.f};

    // conv W fragments: wave wv owns out-cols c = wv*16+llo
    int c = wv * 16 + llo;
    s16x8 whf[4], wlf[4];
#pragma unroll
    for (int ks = 0; ks < 4; ks++) {
        size_t u = ((size_t)(ks * 128 + c) * 4 + lhi) * 8;
        whf[ks] = *(const s16x8*)(whi + u);
        wlf[ks] = *(const s16x8*)(wlo + u);
    }
    // gate W fragments (waves 0-3 only): expert e = wv*16+llo
    s16x8 gwh[4], gwl[4];
    if (wv < 4) {
#pragma unroll
        for (int ks = 0; ks < 4; ks++) {
            size_t u = ((size_t)(ks * 64 + c) * 4 + lhi) * 8;
            gwh[ks] = *(const s16x8*)(ghi + u);
            gwl[ks] = *(const s16x8*)(glo + u);
        }
    }

    // stage X hi/lo
    {
        float v[8];
        if (sr < rows) {
            const float4* xr = (const float4*)(agg + (size_t)(r0 + sr) * D + ss * 8);
            *(float4*)(v + 0) = xr[0];
            *(float4*)(v + 4) = xr[1];
        } else {
#pragma unroll
            for (int k = 0; k < 8; k++) v[k] = 0.f;
        }
        unsigned short hb[8] __attribute__((aligned(16)));
        unsigned short lb[8] __attribute__((aligned(16)));
#pragma unroll
        for (int k = 0; k < 8; k++) {
            unsigned short h = f2bf(v[k]);
            hb[k] = h;
            lb[k] = f2bf(v[k] - bf2f(h));
        }
        int swz = (sr & 7) << 4;
        *(int4*)(smem + XH + sr * 256 + ((ss * 16) ^ swz)) = *(int4*)hb;
        *(int4*)(smem + XL + sr * 256 + ((ss * 16) ^ swz)) = *(int4*)lb;
    }
    __syncthreads();   // (1) X staged

    // conv GEMM
    f32x4 acc[2];
    acc[0] = zero; acc[1] = zero;
#pragma unroll
    for (int ks = 0; ks < 4; ks++) {
        int kb = ks * 64 + lhi * 16;
        int sw0 = (llo & 7) << 4;
        s16x8 ah0 = *(const s16x8*)(smem + XH + llo * 256        + (kb ^ sw0));
        s16x8 ah1 = *(const s16x8*)(smem + XH + (llo + 16) * 256 + (kb ^ sw0));
        s16x8 al0 = *(const s16x8*)(smem + XL + llo * 256        + (kb ^ sw0));
        s16x8 al1 = *(const s16x8*)(smem + XL + (llo + 16) * 256 + (kb ^ sw0));
        acc[0] = __builtin_amdgcn_mfma_f32_16x16x32_bf16(ah0, whf[ks], acc[0], 0, 0, 0);
        acc[0] = __builtin_amdgcn_mfma_f32_16x16x32_bf16(ah0, wlf[ks], acc[0], 0, 0, 0);
        acc[0] = __builtin_amdgcn_mfma_f32_16x16x32_bf16(al0, whf[ks], acc[0], 0, 0, 0);
        acc[1] = __builtin_amdgcn_mfma_f32_16x16x32_bf16(ah1, whf[ks], acc[1], 0, 0, 0);
        acc[1] = __builtin_amdgcn_mfma_f32_16x16x32_bf16(ah1, wlf[ks], acc[1], 0, 0, 0);
        acc[1] = __builtin_amdgcn_mfma_f32_16x16x32_bf16(al1, whf[ks], acc[1], 0, 0, 0);
    }
    __syncthreads();   // (2) all XH/XL reads done -> safe to overwrite

    // out-tile -> YB (f32) and hi/lo split -> XH/XL (element (m,c))
    {
        float bb = bias[c];
#pragma unroll
        for (int mt = 0; mt < 2; mt++)
#pragma unroll
            for (int r = 0; r < 4; r++) {
                int m = mt * 16 + lhi * 4 + r;
                float ov = acc[mt][r] + bb;
                int swz = (m & 7) << 4;
                *(float*)(smem + YB + m * 512 + ((c * 4) ^ swz)) = ov;
                unsigned short h = f2bf(ov);
                *(unsigned short*)(smem + XH + m * 256 + ((c * 2) ^ swz)) = h;
                *(unsigned short*)(smem + XL + m * 256 + ((c * 2) ^ swz)) = f2bf(ov - bf2f(h));
            }
    }
    __syncthreads();   // (3) YB + out-hi/lo ready

    // store out (coalesced) ; gate GEMM (waves 0-3)
    if (sr < rows) {
        int swz = (sr & 7) << 4;
        int4 a = *(const int4*)(smem + YB + sr * 512 + ((ss * 32) ^ swz));
        int4 b = *(const int4*)(smem + YB + sr * 512 + ((ss * 32 + 16) ^ swz));
        float4* op = (float4*)(out + (size_t)(r0 + sr) * D + ss * 8);
        op[0] = *(float4*)&a;
        op[1] = *(float4*)&b;
    }
    f32x4 accg[2];
    accg[0] = zero; accg[1] = zero;
    if (wv < 4) {
#pragma unroll
        for (int ks = 0; ks < 4; ks++) {
            int kb = ks * 64 + lhi * 16;
            int sw0 = (llo & 7) << 4;
            s16x8 ah0 = *(const s16x8*)(smem + XH + llo * 256        + (kb ^ sw0));
            s16x8 ah1 = *(const s16x8*)(smem + XH + (llo + 16) * 256 + (kb ^ sw0));
            s16x8 al0 = *(const s16x8*)(smem + XL + llo * 256        + (kb ^ sw0));
            s16x8 al1 = *(const s16x8*)(smem + XL + (llo + 16) * 256 + (kb ^ sw0));
            accg[0] = __builtin_amdgcn_mfma_f32_16x16x32_bf16(ah0, gwh[ks], accg[0], 0, 0, 0);
            accg[0] = __builtin_amdgcn_mfma_f32_16x16x32_bf16(ah0, gwl[ks], accg[0], 0, 0, 0);
            accg[0] = __builtin_amdgcn_mfma_f32_16x16x32_bf16(al0, gwh[ks], accg[0], 0, 0, 0);
            accg[1] = __builtin_amdgcn_mfma_f32_16x16x32_bf16(ah1, gwh[ks], accg[1], 0, 0, 0);
            accg[1] = __builtin_amdgcn_mfma_f32_16x16x32_bf16(ah1, gwl[ks], accg[1], 0, 0, 0);
            accg[1] = __builtin_amdgcn_mfma_f32_16x16x32_bf16(al1, gwh[ks], accg[1], 0, 0, 0);
        }
    }
    __syncthreads();   // (4) YB reads (out store) done -> SC region free

    if (wv < 4) {
        float gbe = gb[c];
#pragma unroll
        for (int mt = 0; mt < 2; mt++)
#pragma unroll
            for (int r = 0; r < 4; r++) {
                int m = mt * 16 + lhi * 4 + r;
                *(float*)(smem + SC + m * 256 + c * 4) = accg[mt][r] + gbe;
            }
    }
    __syncthreads();   // (5) SC ready

    // top-2 / top-3 + gap test: wave wv owns tokens [wv*4, +4), lane = expert
    const float TAU = 2e-4f;
#pragma unroll
    for (int j = 0; j < 4; j++) {
        int tt = wv * 4 + j;
        if (tt >= rows) break;
        int t = r0 + tt;
        float sf = *(const float*)(smem + SC + tt * 256 + lane * 4);

        float v1 = sf; int i1 = lane;
#pragma unroll
        for (int off = 32; off; off >>= 1) {
            float ov = __shfl_xor(v1, off);
            int   oi = __shfl_xor(i1, off);
            if (ov > v1 || (ov == v1 && oi < i1)) { v1 = ov; i1 = oi; }
        }
        float v2 = (lane == i1) ? -INFINITY : sf; int i2 = lane;
#pragma unroll
        for (int off = 32; off; off >>= 1) {
            float ov = __shfl_xor(v2, off);
            int   oi = __shfl_xor(i2, off);
            if (ov > v2 || (ov == v2 && oi < i2)) { v2 = ov; i2 = oi; }
        }
        float v3 = (lane == i1 || lane == i2) ? -INFINITY : sf;
#pragma unroll
        for (int off = 32; off; off >>= 1)
            v3 = fmaxf(v3, __shfl_xor(v3, off));

        if (lane == 0) {
            float dd = v2 - v1;
            float e2 = expf(dd);
            float g0 = 1.0f / (1.0f + e2);
            gwout[2 * t] = g0;
            gwout[2 * t + 1] = e2 * g0;
            topi[2 * t] = i1;
            topi[2 * t + 1] = i2;
            if ((v1 - v2 <= TAU) || (v2 - v3 <= TAU)) {
                int slot = atomicAdd(rcnt, 1);
                redo[slot] = t;
            }
        }
    }
}

// ---------------- gate FIX: comp-f32 rescore of ambiguous tokens (rare) ------------
__global__ __launch_bounds__(256) void k_gfix(const float* __restrict__ nf,
                                              const float* __restrict__ gW,
                                              const float* __restrict__ gb,
                                              const int* __restrict__ rcnt,
                                              const int* __restrict__ redo,
                                              float* __restrict__ gwout,
                                              int* __restrict__ topi) {
    int nredo = *rcnt;
    int lane = threadIdx.x & 63;
    int widx = blockIdx.x * 4 + (threadIdx.x >> 6);
    float gbf = gb[lane];
    for (int i = widx; i < nredo; i += gridDim.x * 4) {
        int t = redo[i];
        const float* xr = nf + (size_t)t * D;
        float s = 0.f, c = 0.f;
        for (int k = 0; k < D; k++)
            DOT2(s, c, xr[k], gW[k * NE + lane]);
        TSUM(s, c, gbf);
        float vv = s + c, rr = (s - vv) + c;

        float a1v = vv, a1r = rr; int i1 = lane;
#pragma unroll
        for (int off = 32; off; off >>= 1) {
            float ov = __shfl_xor(a1v, off);
            float orr = __shfl_xor(a1r, off);
            int   oi = __shfl_xor(i1, off);
            bool gt = (ov > a1v) || (ov == a1v && (orr > a1r || (orr == a1r && oi < i1)));
            if (gt) { a1v = ov; a1r = orr; i1 = oi; }
        }
        bool ex = (lane == i1);
        float a2v = ex ? -INFINITY : vv;
        float a2r = ex ? 0.f : rr;
        int i2 = lane;
#pragma unroll
        for (int off = 32; off; off >>= 1) {
            float ov = __shfl_xor(a2v, off);
            float orr = __shfl_xor(a2r, off);
            int   oi = __shfl_xor(i2, off);
            bool gt = (ov > a2v) || (ov == a2v && (orr > a2r || (orr == a2r && oi < i2)));
            if (gt) { a2v = ov; a2r = orr; i2 = oi; }
        }

        if (lane == 0) {
            float dd = (a2v - a1v) + (a2r - a1r);
            float e2 = expf(dd);
            float g0 = 1.0f / (1.0f + e2);
            gwout[2 * t] = g0;
            gwout[2 * t + 1] = e2 * g0;
            topi[2 * t] = i1;
            topi[2 * t + 1] = i2;
        }
    }
}

// ---------------- dispatch: parallel two-level counting scatter ----------------
__global__ __launch_bounds__(1024) void k_disp(const int* __restrict__ topi,
                                               int* __restrict__ cnt,
                                               int* __restrict__ plist) {
    __shared__ int lcnt[NE];
    __shared__ int lbase[NE];
    int tid = threadIdx.x;
    if (tid < NE) lcnt[tid] = 0;
    __syncthreads();
    int p = blockIdx.x * 1024 + tid;
    int e = 0, lr = 0;
    bool act = (p < NPAIR);
    if (act) {
        e = topi[p];
        lr = atomicAdd(&lcnt[e], 1);
    }
    __syncthreads();
    if (tid < NE) {
        int n = lcnt[tid];
        lbase[tid] = n ? atomicAdd(&cnt[tid], n) : 0;
    }
    __syncthreads();
    if (act) {
        int slot = lbase[e] + lr;
        if (slot < CAP) plist[e * CAP + slot] = p;
    }
}

// ---------------- weight convert: f32 -> bf16 fragments, LINEAR layout -------------
__global__ __launch_bounds__(256) void k_wconv(const float* __restrict__ W1,
                                               const float* __restrict__ W2,
                                               unsigned short* __restrict__ w1c,
                                               unsigned short* __restrict__ w2c) {
    int gid = blockIdx.x * 256 + threadIdx.x;
    const int NW1 = NE * 4 * 256 * 4;            // 262144
    if (gid < NW1) {
        int lhi = gid & 3, h = (gid >> 2) & 255, ks = (gid >> 10) & 3, e = gid >> 12;
        int d0 = ks * 32 + lhi * 8;
        unsigned short v[8] __attribute__((aligned(16)));
#pragma unroll
        for (int j = 0; j < 8; j++)
            v[j] = f2bf(W1[((size_t)e * D + d0 + j) * H + h]);
        *(int4*)(w1c + (size_t)gid * 8) = *(int4*)v;
    } else {
        int g = gid - NW1;
        int lhi = g & 3, d = (g >> 2) & 127, ks = (g >> 9) & 7, e = g >> 12;
        int h0 = ks * 32 + lhi * 8;
        unsigned short v[8] __attribute__((aligned(16)));
#pragma unroll
        for (int j = 0; j < 8; j++)
            v[j] = f2bf(W2[((size_t)e * H + h0 + j) * D + d]);
        *(int4*)(w2c + (size_t)g * 8) = *(int4*)v;
    }
}

// ---------------- MoE FFN v8: reg-W + YB bounce + fast gelu + 3 barriers/tile ------
__global__ __launch_bounds__(512, 4) void k_moe(const float* __restrict__ nf,
                                                const int* __restrict__ cnt,
                                                const int* __restrict__ plist,
                                                const unsigned short* __restrict__ w1c,
                                                const float* __restrict__ b1,
                                                const unsigned short* __restrict__ w2c,
                                                const float* __restrict__ b2,
                                                const float* __restrict__ gwbuf,
                                                unsigned short* __restrict__ ybuf) {
    __shared__ __align__(16) char smem[32768];
    const int XA = 0, HL = 8192, YB = 24576;
    int e = blockIdx.x & 63;         // same-expert blocks on same XCD (L2 W reuse)
    int q = blockIdx.x >> 6;
    int n = min(cnt[e], CAP);
    int ntile = (n + TILE_R - 1) / TILE_R;
    if (q >= ntile) return;
    int tid = threadIdx.x;

    int wv = tid >> 6, lane = tid & 63;
    int lhi = lane >> 4, llo = lane & 15;
    int sr = tid >> 4, ss = tid & 15;   // staging role: row, 16B-chunk
    f32x4 zero = {0.f, 0.f, 0.f, 0.f};

    // ---- load W fragments into registers (once per block; coalesced 1KB/wave) ----
    s16x8 w1f[4][2];
#pragma unroll
    for (int ks = 0; ks < 4; ks++)
#pragma unroll
        for (int nt = 0; nt < 2; nt++) {
            int h = wv * 32 + nt * 16 + llo;
            w1f[ks][nt] = *(const s16x8*)(w1c +
                ((size_t)e * 4096 + (ks * 256 + h) * 4 + lhi) * 8);
        }
    s16x8 w2f[8];
    {
        int d = wv * 16 + llo;
#pragma unroll
        for (int ks = 0; ks < 8; ks++)
            w2f[ks] = *(const s16x8*)(w2c +
                ((size_t)e * 4096 + (ks * 128 + d) * 4 + lhi) * 8);
    }

    float vals[8];
    auto loadt = [&](int rt2, float* v) {
        bool ok = false;
        if (rt2 < ntile) {
            int rows2 = min(TILE_R, n - rt2 * TILE_R);
            if (sr < rows2) {
                int p = plist[e * CAP + rt2 * TILE_R + sr];
                const float4* xr = (const float4*)(nf + (size_t)(p >> 1) * D + ss * 8);
                *(float4*)(v + 0) = xr[0];
                *(float4*)(v + 4) = xr[1];
                ok = true;
            }
        }
        if (!ok) {
#pragma unroll
            for (int k = 0; k < 8; k++) v[k] = 0.f;
        }
    };
    loadt(q, vals);   // prefetch first tile (overlaps W-frag loads)

    for (int rt = q; rt < ntile; rt += BQ) {
        int r0 = rt * TILE_R;
        int rows = min(TILE_R, n - r0);

        // ---- write XA from prefetched regs (bf16, swizzled) ----
        {
            unsigned short hb[8] __attribute__((aligned(16)));
#pragma unroll
            for (int k = 0; k < 8; k++) hb[k] = f2bf(vals[k]);
            *(int4*)(smem + XA + sr * 256 + ((ss * 16) ^ ((sr & 7) << 4))) = *(int4*)hb;
        }
        __syncthreads();   // XA ready

        loadt(rt + BQ, vals);   // issue next tile's loads; latency hidden under compute

        // ---- GEMM1: H[32x256] = X @ W1; wave wv owns h-cols [wv*32, +32) ----
        f32x4 acc1[2][2];
#pragma unroll
        for (int mt = 0; mt < 2; mt++)
#pragma unroll
            for (int nt = 0; nt < 2; nt++) acc1[mt][nt] = zero;
#pragma unroll
        for (int ks = 0; ks < 4; ks++) {
            int kb = ks * 64 + lhi * 16;
            s16x8 a0 = *(const s16x8*)(smem + XA + llo * 256        + (kb ^ ((llo & 7) << 4)));
            s16x8 a1 = *(const s16x8*)(smem + XA + (llo + 16) * 256 + (kb ^ ((llo & 7) << 4)));
#pragma unroll
            for (int nt = 0; nt < 2; nt++) {
                acc1[0][nt] = __builtin_amdgcn_mfma_f32_16x16x32_bf16(a0, w1f[ks][nt], acc1[0][nt], 0, 0, 0);
                acc1[1][nt] = __builtin_amdgcn_mfma_f32_16x16x32_bf16(a1, w1f[ks][nt], acc1[1][nt], 0, 0, 0);
            }
        }

        // ---- fast gelu -> HL (bf16, swizzled) ----
#pragma unroll
        for (int mt = 0; mt < 2; mt++)
#pragma unroll
            for (int nt = 0; nt < 2; nt++)
#pragma unroll
                for (int r = 0; r < 4; r++) {
                    int m = mt * 16 + lhi * 4 + r;
                    int hc = wv * 32 + nt * 16 + llo;
                    float hv = acc1[mt][nt][r] + b1[e * H + hc];
                    *(unsigned short*)(smem + HL + m * 512 + ((hc * 2) ^ ((m & 7) << 4))) =
                        f2bf(gelu_f(hv));
                }
        __syncthreads();   // HL ready

        // ---- GEMM2: Y[32x128] = H @ W2; wave wv owns d-cols [wv*16, +16) ----
        f32x4 acc2[2];
        acc2[0] = zero; acc2[1] = zero;
#pragma unroll
        for (int ks = 0; ks < 8; ks++) {
            int kb = ks * 64 + lhi * 16;
            s16x8 a0 = *(const s16x8*)(smem + HL + llo * 512        + (kb ^ ((llo & 7) << 4)));
            s16x8 a1 = *(const s16x8*)(smem + HL + (llo + 16) * 512 + (kb ^ ((llo & 7) << 4)));
            acc2[0] = __builtin_amdgcn_mfma_f32_16x16x32_bf16(a0, w2f[ks], acc2[0], 0, 0, 0);
            acc2[1] = __builtin_amdgcn_mfma_f32_16x16x32_bf16(a1, w2f[ks], acc2[1], 0, 0, 0);
        }

        // ---- stage y (acc2 + b2) into YB (bf16, swizzled) ----
        {
            int d = wv * 16 + llo;
            float bb = b2[e * D + d];
#pragma unroll
            for (int mt = 0; mt < 2; mt++)
#pragma unroll
                for (int r = 0; r < 4; r++) {
                    int m = mt * 16 + lhi * 4 + r;
                    *(unsigned short*)(smem + YB + m * 256 + ((d * 2) ^ ((m & 7) << 4))) =
                        f2bf(acc2[mt][r] + bb);
                }
        }
        __syncthreads();   // YB ready (also fences XA/HL reads for next iter)

        // ---- coalesced ybuf write: thread owns (row sr, 16B chunk ss) ----
        if (sr < rows) {
            int p = plist[e * CAP + r0 + sr];
            float gw = gwbuf[p];
            unsigned short yv[8] __attribute__((aligned(16)));
            *(int4*)yv = *(const int4*)(smem + YB + sr * 256 + ((ss * 16) ^ ((sr & 7) << 4)));
#pragma unroll
            for (int k = 0; k < 8; k++) yv[k] = f2bf(gw * bf2f(yv[k]));
            *(int4*)(ybuf + (size_t)p * D + ss * 8) = *(int4*)yv;
        }
    }
}

// ---------------- BatchNorm: bnpart also writes z = nf + y0 + y1 into nf (in place) --
__global__ __launch_bounds__(256) void k_bnpart(float* __restrict__ nf,
                                                const unsigned short* __restrict__ ybuf,
                                                double* __restrict__ part) {
    int blk = blockIdx.x;
    int col = threadIdx.x & 127;
    int half = threadIdx.x >> 7;
    int r0 = blk * BN_ROWS;
    int r1 = min(r0 + BN_ROWS, N_NODES);
    double s = 0.0, ss = 0.0;
    for (int r = r0 + half; r < r1; r += 2) {
        float v32 = nf[(size_t)r * D + col]
                  + bf2f(ybuf[(size_t)(2 * r) * D + col])
                  + bf2f(ybuf[(size_t)(2 * r + 1) * D + col]);
        nf[(size_t)r * D + col] = v32;        // z for bnapply (nf dead after this)
        double v = (double)v32;
        s += v; ss += v * v;
    }
    __shared__ double sh[2][256];
    sh[0][threadIdx.x] = s; sh[1][threadIdx.x] = ss;
    __syncthreads();
    if (threadIdx.x < 128) {
        part[(size_t)blk * 256 + col]       = sh[0][col] + sh[0][col + 128];
        part[(size_t)blk * 256 + 128 + col] = sh[1][col] + sh[1][col + 128];
    }
}

__global__ void k_bnstats(const double* __restrict__ part,
                          const float* __restrict__ gamma,
                          float* __restrict__ stats) {
    int col = threadIdx.x;   // 128 threads
    double s = 0.0, ss = 0.0;
    for (int b = 0; b < BN_NBLK; b++) {
        s  += part[(size_t)b * 256 + col];
        ss += part[(size_t)b * 256 + 128 + col];
    }
    double mean = s / (double)N_NODES;
    double var = ss / (double)N_NODES - mean * mean;
    stats[col] = (float)mean;
    stats[128 + col] = gamma[col] * (float)(1.0 / sqrt(var + 1e-5));
}

// ---------------- bnapply v2: in-place on z (out), float4 ----------------
__global__ __launch_bounds__(256) void k_bnapply(const float* __restrict__ stats,
                                                 const float* __restrict__ beta,
                                                 float* __restrict__ out) {
    int i = blockIdx.x * blockDim.x + threadIdx.x;   // float4 index
    if (i >= N_NODES * (D / 4)) return;
    int q = i & 31;
    int c0 = q * 4;
    float4 z = ((const float4*)out)[i];
    float4 r;
    r.x = (z.x - stats[c0 + 0]) * stats[128 + c0 + 0] + beta[c0 + 0];
    r.y = (z.y - stats[c0 + 1]) * stats[128 + c0 + 1] + beta[c0 + 1];
    r.z = (z.z - stats[c0 + 2]) * stats[128 + c0 + 2] + beta[c0 + 2];
    r.w = (z.w - stats[c0 + 3]) * stats[128 + c0 + 3] + beta[c0 + 3];
    ((float4*)out)[i] = r;
}

// ---------------- launch ----------------
extern "C" void kernel_launch(void* const* d_in, const int* in_sizes, int n_in,
                              void* d_out, int out_size, void* d_ws, size_t ws_size,
                              hipStream_t stream) {
    const float* feats   = (const float*)d_in[0];
    const int*   esrc    = (const int*)d_in[1];
    const int*   edst    = (const int*)d_in[2];
    const float* W_conv  = (const float*)d_in[3];
    const float* b_conv  = (const float*)d_in[4];
    const float* gate_W  = (const float*)d_in[5];
    const float* gate_b  = (const float*)d_in[6];
    const float* W1      = (const float*)d_in[7];
    const float* b1      = (const float*)d_in[8];
    const float* W2      = (const float*)d_in[9];
    const float* b2      = (const float*)d_in[10];
    const float* bn_g    = (const float*)d_in[11];
    const float* bn_b    = (const float*)d_in[12];
    float* out = (float*)d_out;   // doubles as new_feats / z storage

    char* ws = (char*)d_ws;
    size_t off = 0;
    auto rup = [](size_t x) { return (x + 255) & ~(size_t)255; };
    int*    deg    = (int*)   (ws + off); off += rup((size_t)N_NODES * 4);
    int*    cursor = (int*)   (ws + off); off += rup((size_t)N_NODES * 4);
    int*    cnt    = (int*)   (ws + off); off += 256;
    int*    rcnt   = (int*)   (ws + off); off += 256;
    size_t zero_bytes = off;                 // deg + cursor + cnt + rcnt (~400 KB)
    float*  invs   = (float*) (ws + off); off += rup((size_t)N_NODES * 4);
    int*    rowptr = (int*)   (ws + off); off += rup((size_t)(N_NODES + 1) * 4);
    int*    csr    = (int*)   (ws + off); off += rup((size_t)N_EDGES * 4);
    float*  gwbuf  = (float*) (ws + off); off += rup((size_t)NPAIR * 4);
    int*    topi   = (int*)   (ws + off); off += rup((size_t)NPAIR * 4);
    int*    redo   = (int*)   (ws + off); off += rup((size_t)N_NODES * 4);
    int*    plist  = (int*)   (ws + off); off += rup((size_t)NE * CAP * 4);
    double* part   = (double*)(ws + off); off += rup((size_t)BN_NBLK * 256 * 8);
    float*  stats  = (float*) (ws + off); off += 1024;
    unsigned short* w1c  = (unsigned short*)(ws + off); off += rup((size_t)NE * D * H * 2); // 4 MB
    unsigned short* w2c  = (unsigned short*)(ws + off); off += rup((size_t)NE * D * H * 2); // 4 MB
    unsigned short* wchi = (unsigned short*)(ws + off); off += rup((size_t)D * D * 2);      // 32 KB
    unsigned short* wclo = (unsigned short*)(ws + off); off += rup((size_t)D * D * 2);      // 32 KB
    unsigned short* wghi = (unsigned short*)(ws + off); off += rup((size_t)D * NE * 2);     // 16 KB
    unsigned short* wglo = (unsigned short*)(ws + off); off += rup((size_t)D * NE * 2);     // 16 KB
    unsigned short* ybuf = (unsigned short*)(ws + off); off += rup((size_t)NPAIR * D * 2);  // 25.6 MB
    float*  agg    = (float*)ybuf;   // lifetime-disjoint alias (agg dead before k_moe writes ybuf)
    (void)ws_size; (void)in_sizes; (void)n_in; (void)out_size;

    hipMemsetAsync(d_ws, 0, zero_bytes, stream);

    k_wconv<<<2 * NE * 4 * 256 * 4 / 256, 256, 0, stream>>>(W1, W2, w1c, w2c);
    k_wcsplit<<<8, 256, 0, stream>>>(W_conv, wchi, wclo);
    k_wgsplit<<<4, 256, 0, stream>>>(gate_W, wghi, wglo);
    k_deg<<<(N_EDGES + 255) / 256, 256, 0, stream>>>(edst, deg);
    k_invsqrt<<<(N_NODES + 255) / 256, 256, 0, stream>>>(deg, invs);
    k_scan<<<1, 1024, 0, stream>>>(deg, rowptr);
    k_scatter<<<(N_EDGES + 255) / 256, 256, 0, stream>>>(esrc, edst, rowptr, cursor, csr);
    k_gather<<<(N_NODES + 3) / 4, 256, 0, stream>>>(feats, rowptr, csr, invs, agg);
    k_convgate<<<(N_NODES + TILE_R - 1) / TILE_R, 512, 0, stream>>>(
        agg, wchi, wclo, b_conv, wghi, wglo, gate_b, out, gwbuf, topi, rcnt, redo);
    k_gfix<<<128, 256, 0, stream>>>(out, gate_W, gate_b, rcnt, redo, gwbuf, topi);
    k_disp<<<(NPAIR + 1023) / 1024, 1024, 0, stream>>>(topi, cnt, plist);
    k_moe<<<NE * BQ, 512, 0, stream>>>(out, cnt, plist, w1c, b1, w2c, b2, gwbuf, ybuf);
    k_bnpart<<<BN_NBLK, 256, 0, stream>>>(out, ybuf, part);
    k_bnstats<<<1, 128, 0, stream>>>(part, bn_g, stats);
    k_bnapply<<<(N_NODES * (D / 4) + 255) / 256, 256, 0, stream>>>(stats, bn_b, out);
}